// Round 8
// baseline (204.104 us; speedup 1.0000x reference)
//
#include <hip/hip_runtime.h>
#include <hip/hip_bf16.h>
#include <hip/hip_fp16.h>

// Problem constants
#define BB 8
#define HH 56
#define WW 56
#define CC 384
#define NHD 6
#define DD 64
#define HK 28
#define WK 28
#define NQ (HH*WW)       // 3136
#define NKV (HK*WK)      // 784
#define NTOK (BB*NQ)     // 25088
#define NTOKKV (BB*NKV)  // 6272
#define BN_EPS 1e-5f
#define LOG2E 1.44269504f

typedef _Float16 f16;
typedef _Float16 f16x4 __attribute__((ext_vector_type(4)));
typedef _Float16 f16x8 __attribute__((ext_vector_type(8)));
typedef float f32x4 __attribute__((ext_vector_type(4)));

__device__ __forceinline__ float fast_exp2(float x) {
#if __has_builtin(__builtin_amdgcn_exp2f)
  return __builtin_amdgcn_exp2f(x);   // v_exp_f32 (2^x)
#else
  return __expf(x * 0.69314718056f);
#endif
}

// ---------------- depthwise conv + BN, stride 1 (q path), f16 out ----------------
// 2 adjacent x-pixels per thread: shares 2/4 input cols, all weights, all BN math.
__global__ __launch_bounds__(256) void dw_bn_s1(
    const float* __restrict__ in, const float* __restrict__ w,
    const float* __restrict__ bns, const float* __restrict__ bnb,
    const float* __restrict__ bnm, const float* __restrict__ bnv,
    f16* __restrict__ out) {
  int idx = blockIdx.x * 256 + threadIdx.x;      // < (NTOK/2)*96 = 1204224
  int pp = idx / 96;
  int c = (idx % 96) * 4;
  int b = pp / (HH * WK);                        // 56*28 pixel-pairs per image
  int rem = pp % (HH * WK);
  int y = rem / WK, xh = rem % WK;
  int x0 = xh * 2;
  float a0x = 0, a0y = 0, a0z = 0, a0w = 0;
  float a1x = 0, a1y = 0, a1z = 0, a1w = 0;
#pragma unroll
  for (int kh = 0; kh < 3; ++kh) {
    int iy = y + kh - 1;
    if ((unsigned)iy >= (unsigned)HH) continue;
    const float* rp = in + ((size_t)(b * HH + iy) * WW) * CC + c;
    const float4 z4 = {0.f, 0.f, 0.f, 0.f};
    const float4 v0 = (x0 > 0) ? *(const float4*)(rp + (size_t)(x0 - 1) * CC) : z4;
    const float4 v1 = *(const float4*)(rp + (size_t)x0 * CC);
    const float4 v2 = *(const float4*)(rp + (size_t)(x0 + 1) * CC);
    const float4 v3 = (x0 < 54) ? *(const float4*)(rp + (size_t)(x0 + 2) * CC) : z4;
    const float4 w0 = *(const float4*)(w + (kh * 3 + 0) * CC + c);
    const float4 w1 = *(const float4*)(w + (kh * 3 + 1) * CC + c);
    const float4 w2 = *(const float4*)(w + (kh * 3 + 2) * CC + c);
    a0x = fmaf(v0.x, w0.x, fmaf(v1.x, w1.x, fmaf(v2.x, w2.x, a0x)));
    a0y = fmaf(v0.y, w0.y, fmaf(v1.y, w1.y, fmaf(v2.y, w2.y, a0y)));
    a0z = fmaf(v0.z, w0.z, fmaf(v1.z, w1.z, fmaf(v2.z, w2.z, a0z)));
    a0w = fmaf(v0.w, w0.w, fmaf(v1.w, w1.w, fmaf(v2.w, w2.w, a0w)));
    a1x = fmaf(v1.x, w0.x, fmaf(v2.x, w1.x, fmaf(v3.x, w2.x, a1x)));
    a1y = fmaf(v1.y, w0.y, fmaf(v2.y, w1.y, fmaf(v3.y, w2.y, a1y)));
    a1z = fmaf(v1.z, w0.z, fmaf(v2.z, w1.z, fmaf(v3.z, w2.z, a1z)));
    a1w = fmaf(v1.w, w0.w, fmaf(v2.w, w1.w, fmaf(v3.w, w2.w, a1w)));
  }
  const float4 s = *(const float4*)(bns + c);
  const float4 bi = *(const float4*)(bnb + c);
  const float4 m = *(const float4*)(bnm + c);
  const float4 va = *(const float4*)(bnv + c);
  f16x4 r0, r1;
  float g;
  g = s.x * rsqrtf(va.x + BN_EPS); r0[0] = (f16)fmaf(a0x - m.x, g, bi.x); r1[0] = (f16)fmaf(a1x - m.x, g, bi.x);
  g = s.y * rsqrtf(va.y + BN_EPS); r0[1] = (f16)fmaf(a0y - m.y, g, bi.y); r1[1] = (f16)fmaf(a1y - m.y, g, bi.y);
  g = s.z * rsqrtf(va.z + BN_EPS); r0[2] = (f16)fmaf(a0z - m.z, g, bi.z); r1[2] = (f16)fmaf(a1z - m.z, g, bi.z);
  g = s.w * rsqrtf(va.w + BN_EPS); r0[3] = (f16)fmaf(a0w - m.w, g, bi.w); r1[3] = (f16)fmaf(a1w - m.w, g, bi.w);
  const size_t pix0 = (size_t)b * NQ + y * WW + x0;
  *(f16x4*)(out + pix0 * CC + c) = r0;
  *(f16x4*)(out + (pix0 + 1) * CC + c) = r1;
}

// -------- fused depthwise conv + BN, stride 2, k and v from same input, f16 out --------
__global__ __launch_bounds__(256) void dw_bn_s2_kv(
    const float* __restrict__ in,
    const float* __restrict__ wk_, const float* __restrict__ kbs, const float* __restrict__ kbb,
    const float* __restrict__ kbm, const float* __restrict__ kbv,
    const float* __restrict__ wv_, const float* __restrict__ vbs, const float* __restrict__ vbb,
    const float* __restrict__ vbm, const float* __restrict__ vbv,
    f16* __restrict__ outk, f16* __restrict__ outv) {
  int idx = blockIdx.x * 256 + threadIdx.x;      // < NTOKKV*96
  int pix = idx / 96;
  int c = (idx % 96) * 4;
  int b = pix / (HK * WK);
  int p = pix % (HK * WK);
  int oy = p / WK, ox = p % WK;
  float kx = 0, ky = 0, kz = 0, kw4 = 0;
  float vx = 0, vy = 0, vz = 0, vw4 = 0;
#pragma unroll
  for (int kh = 0; kh < 3; ++kh) {
    int iy = oy * 2 + kh;
    if (iy >= HH) continue;
#pragma unroll
    for (int kwi = 0; kwi < 3; ++kwi) {
      int ix = ox * 2 + kwi;
      if (ix >= WW) continue;
      const float4 v = *(const float4*)(in + (((size_t)(b * HH + iy) * WW + ix) * CC + c));
      const float4 a = *(const float4*)(wk_ + ((kh * 3 + kwi) * CC + c));
      const float4 bq = *(const float4*)(wv_ + ((kh * 3 + kwi) * CC + c));
      kx = fmaf(v.x, a.x, kx); ky = fmaf(v.y, a.y, ky);
      kz = fmaf(v.z, a.z, kz); kw4 = fmaf(v.w, a.w, kw4);
      vx = fmaf(v.x, bq.x, vx); vy = fmaf(v.y, bq.y, vy);
      vz = fmaf(v.z, bq.z, vz); vw4 = fmaf(v.w, bq.w, vw4);
    }
  }
  {
    const float4 s = *(const float4*)(kbs + c);
    const float4 bi = *(const float4*)(kbb + c);
    const float4 m = *(const float4*)(kbm + c);
    const float4 va = *(const float4*)(kbv + c);
    f16x4 r; float g;
    g = s.x * rsqrtf(va.x + BN_EPS); r[0] = (f16)fmaf(kx - m.x, g, bi.x);
    g = s.y * rsqrtf(va.y + BN_EPS); r[1] = (f16)fmaf(ky - m.y, g, bi.y);
    g = s.z * rsqrtf(va.z + BN_EPS); r[2] = (f16)fmaf(kz - m.z, g, bi.z);
    g = s.w * rsqrtf(va.w + BN_EPS); r[3] = (f16)fmaf(kw4 - m.w, g, bi.w);
    *(f16x4*)(outk + (size_t)pix * CC + c) = r;
  }
  {
    const float4 s = *(const float4*)(vbs + c);
    const float4 bi = *(const float4*)(vbb + c);
    const float4 m = *(const float4*)(vbm + c);
    const float4 va = *(const float4*)(vbv + c);
    f16x4 r; float g;
    g = s.x * rsqrtf(va.x + BN_EPS); r[0] = (f16)fmaf(vx - m.x, g, bi.x);
    g = s.y * rsqrtf(va.y + BN_EPS); r[1] = (f16)fmaf(vy - m.y, g, bi.y);
    g = s.z * rsqrtf(va.z + BN_EPS); r[2] = (f16)fmaf(vz - m.z, g, bi.z);
    g = s.w * rsqrtf(va.w + BN_EPS); r[3] = (f16)fmaf(vw4 - m.w, g, bi.w);
    *(f16x4*)(outv + (size_t)pix * CC + c) = r;
  }
}

// ---- transpose-convert 4 weight matrices: fp32 [384(k)][384(n)] -> f16 [n][k] ----
__global__ __launch_bounds__(256) void convert_w(
    const float* __restrict__ w0, const float* __restrict__ w1,
    const float* __restrict__ w2, const float* __restrict__ w3,
    f16* __restrict__ o0, f16* __restrict__ o1,
    f16* __restrict__ o2, f16* __restrict__ o3) {
  const float* src = blockIdx.z == 0 ? w0 : blockIdx.z == 1 ? w1 : blockIdx.z == 2 ? w2 : w3;
  f16* dst = blockIdx.z == 0 ? o0 : blockIdx.z == 1 ? o1 : blockIdx.z == 2 ? o2 : o3;
  __shared__ float t[32][33];
  const int k0 = blockIdx.x * 32, n0 = blockIdx.y * 32;
  const int x = threadIdx.x & 31, y = threadIdx.x >> 5;
#pragma unroll
  for (int i = 0; i < 4; ++i) t[y + i * 8][x] = src[(size_t)(k0 + y + i * 8) * 384 + n0 + x];
  __syncthreads();
#pragma unroll
  for (int i = 0; i < 4; ++i)
    dst[(size_t)(n0 + y + i * 8) * 384 + k0 + x] = (f16)t[x][y + i * 8];
}

// ------------- f16 MFMA GEMM body (128x128 tile, 4 waves, 4x4 frags) -------------
template <int OF16>
__device__ __forceinline__ void gemm_body(
    const f16* __restrict__ A, const f16* __restrict__ Bt,
    float* __restrict__ Cf, f16* __restrict__ Ch, float scale,
    int row0, int col0) {
  __shared__ f16 As[128 * 32];   // [row][k], 64 B per row
  __shared__ f16 Bs[128 * 32];   // [col][k], 64 B per col
  const int tid = threadIdx.x;
  const int wave = tid >> 6, lane = tid & 63;
  const int c = lane & 15, g = lane >> 4;
  const int wr = wave >> 1, wc = wave & 1;     // 2x2 waves, each 64x64

  f32x4 acc[4][4] = {};

  for (int k0 = 0; k0 < 384; k0 += 32) {
    __syncthreads();
#pragma unroll
    for (int ph = 0; ph < 2; ++ph) {
      const int i = ph * 256 + wave * 64 + lane;   // chunk index: row = i>>2, ch = i&3
      const f16* sa = A + (size_t)(row0 + (i >> 2)) * 384 + k0 + (i & 3) * 8;
      __builtin_amdgcn_global_load_lds(
          (const __attribute__((address_space(1))) void*)sa,
          (__attribute__((address_space(3))) void*)(As + ph * 2048 + wave * 512), 16, 0, 0);
      const f16* sb = Bt + (size_t)(col0 + (i >> 2)) * 384 + k0 + (i & 3) * 8;
      __builtin_amdgcn_global_load_lds(
          (const __attribute__((address_space(1))) void*)sb,
          (__attribute__((address_space(3))) void*)(Bs + ph * 2048 + wave * 512), 16, 0, 0);
    }
    __syncthreads();

    f16x8 bf[4];
#pragma unroll
    for (int n = 0; n < 4; ++n)
      bf[n] = *(const f16x8*)(Bs + (size_t)(wc * 64 + n * 16 + c) * 32 + g * 8);
#pragma unroll
    for (int m = 0; m < 4; ++m) {
      f16x8 af = *(const f16x8*)(As + (size_t)(wr * 64 + m * 16 + c) * 32 + g * 8);
#pragma unroll
      for (int n = 0; n < 4; ++n)
        acc[m][n] = __builtin_amdgcn_mfma_f32_16x16x32_f16(af, bf[n], acc[m][n], 0, 0, 0);
    }
  }

#pragma unroll
  for (int m = 0; m < 4; ++m)
#pragma unroll
    for (int n = 0; n < 4; ++n)
#pragma unroll
      for (int r = 0; r < 4; ++r) {
        const size_t row = row0 + wr * 64 + m * 16 + g * 4 + r;
        const size_t col = col0 + wc * 64 + n * 16 + c;
        if (OF16) Ch[row * 384 + col] = (f16)(acc[m][n][r] * scale);
        else      Cf[row * 384 + col] = acc[m][n][r] * scale;
      }
}

template <int OF16>
__global__ __launch_bounds__(256) void gemm_mfma(
    const f16* __restrict__ A, const f16* __restrict__ Bt,
    float* __restrict__ Cf, f16* __restrict__ Ch, float scale) {
  gemm_body<OF16>(A, Bt, Cf, Ch, scale, blockIdx.x * 128, blockIdx.y * 128);
}

// k and v pointwise GEMMs in one launch (blockIdx.z picks)
__global__ __launch_bounds__(256) void gemm_kv(
    const f16* __restrict__ A0, const f16* __restrict__ B0, f16* __restrict__ C0,
    const f16* __restrict__ A1, const f16* __restrict__ B1, f16* __restrict__ C1) {
  if (blockIdx.z == 0)
    gemm_body<1>(A0, B0, nullptr, C0, 1.0f, blockIdx.x * 128, blockIdx.y * 128);
  else
    gemm_body<1>(A1, B1, nullptr, C1, 1.0f, blockIdx.x * 128, blockIdx.y * 128);
}

// ------------- per-batch transpose: in [b*784+kv][384] -> out [b*384+c][784] -------------
__global__ __launch_bounds__(256) void transpose_f16(
    const f16* __restrict__ in, f16* __restrict__ out) {
  __shared__ f16 t[32][33];
  const int b = blockIdx.z;
  const int kv0 = blockIdx.x * 32, c0 = blockIdx.y * 32;
  const int x = threadIdx.x & 31, y = threadIdx.x >> 5;  // 32 x 8
#pragma unroll
  for (int i = 0; i < 4; ++i) {
    int row = y + i * 8;
    int kv = kv0 + row;
    if (kv < NKV) t[row][x] = in[((size_t)b * NKV + kv) * 384 + c0 + x];
  }
  __syncthreads();
#pragma unroll
  for (int i = 0; i < 4; ++i) {
    int row = y + i * 8;
    if (kv0 + x < NKV)
      out[((size_t)b * 384 + c0 + row) * NKV + kv0 + x] = t[x][row];
  }
}

// ------------- f16 MFMA flash attention, swapped-QK^T, K dbuf, V direct-from-L2 -------------
// grid = B*NH*49; block 256 (4 waves x 16 q rows). KVT=64, NT=13.
// Q pre-scaled by 0.125*log2(e); softmax = native exp2.
// S^T = mfma(A=K, B=Q): lane (c,g) holds S[kv = t0+ct*16+g*4+r][q = c].
// V^T [d][kv] read directly from global per-MFMA (L2-resident: 100KB/bh shared
// by 49 blocks) -> LDS 24KB -> 5+ blocks/CU.
#define NT 13
__global__ __launch_bounds__(256, 5) void attn_mfma(
    const f16* __restrict__ qp, const f16* __restrict__ kp,
    const f16* __restrict__ vt, f16* __restrict__ op) {
  __shared__ f16 Ks[2][64 * 64];   // [buf][kv][d], 128B rows, chunk ch at ch^(kv&7)
  __shared__ f16 Ps[4][16 * 64];   // per-wave [q][kv], 128B rows, ch^(q&7)
  const int bid = blockIdx.x;
  const int qt = bid % 49;
  const int bh = bid / 49;
  const int h = bh % NHD, b = bh / NHD;
  const int tid = threadIdx.x;
  const int wave = tid >> 6, lane = tid & 63;
  const int c = lane & 15, g = lane >> 4;

  const size_t qrow = (size_t)b * NQ + qt * 64 + wave * 16 + c;
  f16x8 qa[2];
  qa[0] = *(const f16x8*)(qp + qrow * 384 + h * 64 + g * 8);
  qa[1] = *(const f16x8*)(qp + qrow * 384 + h * 64 + 32 + g * 8);

  const int tid8 = tid >> 3, tch = tid & 7;
  const int lch = tch ^ (tid8 & 7);            // logical chunk fetched

  const f16* kbase = kp + ((size_t)b * NKV) * 384 + h * 64;
  const f16* vbase = vt + ((size_t)(b * 384 + h * 64)) * NKV;

  float mrun = -1e30f, lsum = 0.f;   // for q = c (redundant across g)
  f32x4 o[4] = {};                    // O[q=g*4+r][d=dt*16+c]
  f16* prow = &Ps[wave][0];

#define STAGEK(T0, BUF) do {                                                             \
    int kv0 = (T0) + tid8; if (kv0 > NKV - 1) kv0 = NKV - 1;                             \
    int kv1 = (T0) + 32 + tid8; if (kv1 > NKV - 1) kv1 = NKV - 1;                        \
    __builtin_amdgcn_global_load_lds(                                                    \
        (const __attribute__((address_space(1))) void*)(kbase + (size_t)kv0 * 384 + lch * 8), \
        (__attribute__((address_space(3))) void*)(&Ks[BUF][0] + wave * 512), 16, 0, 0);  \
    __builtin_amdgcn_global_load_lds(                                                    \
        (const __attribute__((address_space(1))) void*)(kbase + (size_t)kv1 * 384 + lch * 8), \
        (__attribute__((address_space(3))) void*)(&Ks[BUF][0] + 2048 + wave * 512), 16, 0, 0);\
  } while (0)

  STAGEK(0, 0);
  int cur = 0;

  for (int ti = 0; ti < NT; ++ti) {
    const int t0 = ti * 64;
    __syncthreads();     // buf[cur] staged (each wave's vmcnt drained at barrier)
    if (ti + 1 < NT) STAGEK(t0 + 64, cur ^ 1);   // prefetch next K tile during compute
    const f16* ksb = &Ks[cur][0];

    // S^T tiles: s[ct] = K[t0+ct*16..+16) . Q^T, accumulated over kh
    f32x4 s[4] = {};
#pragma unroll
    for (int kh = 0; kh < 2; ++kh) {
#pragma unroll
      for (int ct = 0; ct < 4; ++ct) {
        const int row = ct * 16 + c;
        const int sch = (kh * 4 + g) ^ (row & 7);
        f16x8 kb = *(const f16x8*)(ksb + row * 64 + sch * 8);
        s[ct] = __builtin_amdgcn_mfma_f32_16x16x32_f16(kb, qa[kh], s[ct], 0, 0, 0);
      }
    }
    // tail mask
    if (t0 + 64 > NKV) {
#pragma unroll
      for (int ct = 0; ct < 4; ++ct)
#pragma unroll
        for (int r = 0; r < 4; ++r)
          if (t0 + ct * 16 + g * 4 + r >= NKV) s[ct][r] = -1e30f;
    }

    // tile max for q=c
    float mt = s[0][0];
#pragma unroll
    for (int ct = 0; ct < 4; ++ct)
#pragma unroll
      for (int r = 0; r < 4; ++r) mt = fmaxf(mt, s[ct][r]);
    mt = fmaxf(mt, __shfl_xor(mt, 16));
    mt = fmaxf(mt, __shfl_xor(mt, 32));

    // defer-max (log2 units; P bounded by 2^8)
    unsigned long long need = __ballot(mt > mrun + 8.0f);
    if (need) {
      const float mnew = fmaxf(mrun, mt);
      const float corr = fast_exp2(mrun - mnew);
      mrun = mnew;
      lsum *= corr;
#pragma unroll
      for (int r = 0; r < 4; ++r) {
        const float co = __shfl(corr, g * 4 + r);
#pragma unroll
        for (int dt = 0; dt < 4; ++dt) o[dt][r] *= co;
      }
    }

    // P = exp2(S - mrun); pack f16, store to per-wave LDS; accumulate sum
    float ps = 0.f;
#pragma unroll
    for (int ct = 0; ct < 4; ++ct) {
      f16x4 pk;
#pragma unroll
      for (int r = 0; r < 4; ++r) {
        const float p = fast_exp2(s[ct][r] - mrun);
        ps += p;
        pk[r] = (f16)p;
      }
      const int sch = (ct * 2 + (g >> 1)) ^ (c & 7);
      *(f16x4*)(prow + c * 64 + sch * 8 + (g & 1) * 4) = pk;
    }
    ps += __shfl_xor(ps, 16);
    ps += __shfl_xor(ps, 32);
    lsum += ps;

    // PV: o[dt] += P[q][kv] * V[kv][d]; V^T B-frag straight from global (L2)
#pragma unroll
    for (int ks = 0; ks < 2; ++ks) {
      const int sp = (ks * 4 + g) ^ (c & 7);
      f16x8 pa = *(const f16x8*)(prow + c * 64 + sp * 8);
#pragma unroll
      for (int dt = 0; dt < 4; ++dt) {
        f16x8 vb = *(const f16x8*)(vbase + (size_t)(dt * 16 + c) * NKV + t0 + ks * 32 + g * 8);
        o[dt] = __builtin_amdgcn_mfma_f32_16x16x32_f16(pa, vb, o[dt], 0, 0, 0);
      }
    }
    cur ^= 1;
  }
#undef STAGEK

  // epilogue: inv per q=c -> shuffle to q=g*4+r layout
  const float inv = 1.0f / lsum;
  f16* obase = op + ((size_t)(b * NQ + qt * 64 + wave * 16)) * 384 + h * 64;
#pragma unroll
  for (int r = 0; r < 4; ++r) {
    const float iv = __shfl(inv, g * 4 + r);
#pragma unroll
    for (int dt = 0; dt < 4; ++dt)
      obase[(size_t)(g * 4 + r) * 384 + dt * 16 + c] = (f16)(o[dt][r] * iv);
  }
}

extern "C" void kernel_launch(void* const* d_in, const int* in_sizes, int n_in,
                              void* d_out, int out_size, void* d_ws, size_t ws_size,
                              hipStream_t stream) {
  const float* inputs_q  = (const float*)d_in[0];
  const float* inputs_kv = (const float*)d_in[1];
  const float* out_kern  = (const float*)d_in[2];
  const float* q_dwk = (const float*)d_in[3];
  const float* q_bs  = (const float*)d_in[4];
  const float* q_bb  = (const float*)d_in[5];
  const float* q_bm  = (const float*)d_in[6];
  const float* q_bv  = (const float*)d_in[7];
  const float* q_pwk = (const float*)d_in[8];
  const float* k_dwk = (const float*)d_in[9];
  const float* k_bs  = (const float*)d_in[10];
  const float* k_bb  = (const float*)d_in[11];
  const float* k_bm  = (const float*)d_in[12];
  const float* k_bv  = (const float*)d_in[13];
  const float* k_pwk = (const float*)d_in[14];
  const float* v_dwk = (const float*)d_in[15];
  const float* v_bs  = (const float*)d_in[16];
  const float* v_bb  = (const float*)d_in[17];
  const float* v_bm  = (const float*)d_in[18];
  const float* v_bv  = (const float*)d_in[19];
  const float* v_pwk = (const float*)d_in[20];

  char* wsb = (char*)d_ws;
  f16* qdw = (f16*)(wsb + 0);             // 25088*384 f16
  f16* kdw = (f16*)(wsb + 19267584);      // 6272*384 f16
  f16* vdw = (f16*)(wsb + 24084480);      // 6272*384 f16
  f16* qf  = (f16*)(wsb + 28901376);      // 25088*384 f16
  f16* kf  = (f16*)(wsb + 48168960);      // 6272*384 f16
  f16* vf  = (f16*)(wsb + 52985856);      // 6272*384 f16
  f16* vtp = (f16*)(wsb + 57802752);      // 8*384*784 f16
  f16* of  = (f16*)(wsb + 62619648);      // 25088*384 f16
  f16* wqt = (f16*)(wsb + 81887232);      // 384*384 f16 x4
  f16* wkt = (f16*)(wsb + 82182144);
  f16* wvt = (f16*)(wsb + 82477056);
  f16* wot = (f16*)(wsb + 82771968);

  // 0. weight transpose-convert
  convert_w<<<dim3(12, 12, 4), 256, 0, stream>>>(
      q_pwk, k_pwk, v_pwk, out_kern, wqt, wkt, wvt, wot);
  // 1. depthwise + BN -> f16
  dw_bn_s1<<<4704, 256, 0, stream>>>(inputs_q, q_dwk, q_bs, q_bb, q_bm, q_bv, qdw);
  dw_bn_s2_kv<<<2352, 256, 0, stream>>>(inputs_kv,
      k_dwk, k_bs, k_bb, k_bm, k_bv,
      v_dwk, v_bs, v_bb, v_bm, v_bv,
      kdw, vdw);
  // 2. pointwise GEMMs (q folded with 1/8 * log2e for exp2 softmax)
  gemm_mfma<1><<<dim3(196, 3), 256, 0, stream>>>(qdw, wqt, nullptr, qf, 0.125f * LOG2E);
  gemm_kv<<<dim3(49, 3, 2), 256, 0, stream>>>(kdw, wkt, kf, vdw, wvt, vf);
  // 3. V transpose per batch
  transpose_f16<<<dim3(25, 12, 8), 256, 0, stream>>>(vf, vtp);
  // 4. MFMA attention (K dbuf, V direct) -> f16 O
  attn_mfma<<<BB * NHD * 49, 256, 0, stream>>>(qf, kf, vtp, of);
  // 5. output projection (MFMA, fp32 out)
  gemm_mfma<0><<<dim3(196, 3), 256, 0, stream>>>(of, wot, (float*)d_out, nullptr, 1.0f);
}

// Round 10
// 177.713 us; speedup vs baseline: 1.1485x; 1.1485x over previous
//
#include <hip/hip_runtime.h>
#include <hip/hip_bf16.h>
#include <hip/hip_fp16.h>

// Problem constants
#define BB 8
#define HH 56
#define WW 56
#define CC 384
#define NHD 6
#define DD 64
#define HK 28
#define WK 28
#define NQ (HH*WW)       // 3136
#define NKV (HK*WK)      // 784
#define NTOK (BB*NQ)     // 25088
#define NTOKKV (BB*NKV)  // 6272
#define BN_EPS 1e-5f
#define LOG2E 1.44269504f

typedef _Float16 f16;
typedef _Float16 f16x2 __attribute__((ext_vector_type(2)));
typedef _Float16 f16x4 __attribute__((ext_vector_type(4)));
typedef _Float16 f16x8 __attribute__((ext_vector_type(8)));
typedef float f32x4 __attribute__((ext_vector_type(4)));

__device__ __forceinline__ float fast_exp2(float x) {
#if __has_builtin(__builtin_amdgcn_exp2f)
  return __builtin_amdgcn_exp2f(x);   // v_exp_f32 (2^x)
#else
  return __expf(x * 0.69314718056f);
#endif
}

__device__ __forceinline__ f16x4 pack4(float p0, float p1, float p2, float p3) {
#if __has_builtin(__builtin_amdgcn_cvt_pkrtz)
  f16x2 a = __builtin_bit_cast(f16x2, __builtin_amdgcn_cvt_pkrtz(p0, p1));
  f16x2 b = __builtin_bit_cast(f16x2, __builtin_amdgcn_cvt_pkrtz(p2, p3));
  return __builtin_shufflevector(a, b, 0, 1, 2, 3);
#else
  f16x4 r; r[0] = (f16)p0; r[1] = (f16)p1; r[2] = (f16)p2; r[3] = (f16)p3;
  return r;
#endif
}

// ---------------- depthwise conv + BN, stride 1 (q path), f16 out ----------------
// 2 adjacent x-pixels per thread: shares 2/4 input cols, all weights, all BN math.
__global__ __launch_bounds__(256) void dw_bn_s1(
    const float* __restrict__ in, const float* __restrict__ w,
    const float* __restrict__ bns, const float* __restrict__ bnb,
    const float* __restrict__ bnm, const float* __restrict__ bnv,
    f16* __restrict__ out) {
  int idx = blockIdx.x * 256 + threadIdx.x;      // < (NTOK/2)*96 = 1204224
  int pp = idx / 96;
  int c = (idx % 96) * 4;
  int b = pp / (HH * WK);                        // 56*28 pixel-pairs per image
  int rem = pp % (HH * WK);
  int y = rem / WK, xh = rem % WK;
  int x0 = xh * 2;
  float a0x = 0, a0y = 0, a0z = 0, a0w = 0;
  float a1x = 0, a1y = 0, a1z = 0, a1w = 0;
#pragma unroll
  for (int kh = 0; kh < 3; ++kh) {
    int iy = y + kh - 1;
    if ((unsigned)iy >= (unsigned)HH) continue;
    const float* rp = in + ((size_t)(b * HH + iy) * WW) * CC + c;
    const float4 z4 = {0.f, 0.f, 0.f, 0.f};
    const float4 v0 = (x0 > 0) ? *(const float4*)(rp + (size_t)(x0 - 1) * CC) : z4;
    const float4 v1 = *(const float4*)(rp + (size_t)x0 * CC);
    const float4 v2 = *(const float4*)(rp + (size_t)(x0 + 1) * CC);
    const float4 v3 = (x0 < 54) ? *(const float4*)(rp + (size_t)(x0 + 2) * CC) : z4;
    const float4 w0 = *(const float4*)(w + (kh * 3 + 0) * CC + c);
    const float4 w1 = *(const float4*)(w + (kh * 3 + 1) * CC + c);
    const float4 w2 = *(const float4*)(w + (kh * 3 + 2) * CC + c);
    a0x = fmaf(v0.x, w0.x, fmaf(v1.x, w1.x, fmaf(v2.x, w2.x, a0x)));
    a0y = fmaf(v0.y, w0.y, fmaf(v1.y, w1.y, fmaf(v2.y, w2.y, a0y)));
    a0z = fmaf(v0.z, w0.z, fmaf(v1.z, w1.z, fmaf(v2.z, w2.z, a0z)));
    a0w = fmaf(v0.w, w0.w, fmaf(v1.w, w1.w, fmaf(v2.w, w2.w, a0w)));
    a1x = fmaf(v1.x, w0.x, fmaf(v2.x, w1.x, fmaf(v3.x, w2.x, a1x)));
    a1y = fmaf(v1.y, w0.y, fmaf(v2.y, w1.y, fmaf(v3.y, w2.y, a1y)));
    a1z = fmaf(v1.z, w0.z, fmaf(v2.z, w1.z, fmaf(v3.z, w2.z, a1z)));
    a1w = fmaf(v1.w, w0.w, fmaf(v2.w, w1.w, fmaf(v3.w, w2.w, a1w)));
  }
  const float4 s = *(const float4*)(bns + c);
  const float4 bi = *(const float4*)(bnb + c);
  const float4 m = *(const float4*)(bnm + c);
  const float4 va = *(const float4*)(bnv + c);
  f16x4 r0, r1;
  float g;
  g = s.x * rsqrtf(va.x + BN_EPS); r0[0] = (f16)fmaf(a0x - m.x, g, bi.x); r1[0] = (f16)fmaf(a1x - m.x, g, bi.x);
  g = s.y * rsqrtf(va.y + BN_EPS); r0[1] = (f16)fmaf(a0y - m.y, g, bi.y); r1[1] = (f16)fmaf(a1y - m.y, g, bi.y);
  g = s.z * rsqrtf(va.z + BN_EPS); r0[2] = (f16)fmaf(a0z - m.z, g, bi.z); r1[2] = (f16)fmaf(a1z - m.z, g, bi.z);
  g = s.w * rsqrtf(va.w + BN_EPS); r0[3] = (f16)fmaf(a0w - m.w, g, bi.w); r1[3] = (f16)fmaf(a1w - m.w, g, bi.w);
  const size_t pix0 = (size_t)b * NQ + y * WW + x0;
  *(f16x4*)(out + pix0 * CC + c) = r0;
  *(f16x4*)(out + (pix0 + 1) * CC + c) = r1;
}

// -------- fused depthwise conv + BN, stride 2, k and v from same input, f16 out --------
__global__ __launch_bounds__(256) void dw_bn_s2_kv(
    const float* __restrict__ in,
    const float* __restrict__ wk_, const float* __restrict__ kbs, const float* __restrict__ kbb,
    const float* __restrict__ kbm, const float* __restrict__ kbv,
    const float* __restrict__ wv_, const float* __restrict__ vbs, const float* __restrict__ vbb,
    const float* __restrict__ vbm, const float* __restrict__ vbv,
    f16* __restrict__ outk, f16* __restrict__ outv) {
  int idx = blockIdx.x * 256 + threadIdx.x;      // < NTOKKV*96
  int pix = idx / 96;
  int c = (idx % 96) * 4;
  int b = pix / (HK * WK);
  int p = pix % (HK * WK);
  int oy = p / WK, ox = p % WK;
  float kx = 0, ky = 0, kz = 0, kw4 = 0;
  float vx = 0, vy = 0, vz = 0, vw4 = 0;
#pragma unroll
  for (int kh = 0; kh < 3; ++kh) {
    int iy = oy * 2 + kh;
    if (iy >= HH) continue;
#pragma unroll
    for (int kwi = 0; kwi < 3; ++kwi) {
      int ix = ox * 2 + kwi;
      if (ix >= WW) continue;
      const float4 v = *(const float4*)(in + (((size_t)(b * HH + iy) * WW + ix) * CC + c));
      const float4 a = *(const float4*)(wk_ + ((kh * 3 + kwi) * CC + c));
      const float4 bq = *(const float4*)(wv_ + ((kh * 3 + kwi) * CC + c));
      kx = fmaf(v.x, a.x, kx); ky = fmaf(v.y, a.y, ky);
      kz = fmaf(v.z, a.z, kz); kw4 = fmaf(v.w, a.w, kw4);
      vx = fmaf(v.x, bq.x, vx); vy = fmaf(v.y, bq.y, vy);
      vz = fmaf(v.z, bq.z, vz); vw4 = fmaf(v.w, bq.w, vw4);
    }
  }
  {
    const float4 s = *(const float4*)(kbs + c);
    const float4 bi = *(const float4*)(kbb + c);
    const float4 m = *(const float4*)(kbm + c);
    const float4 va = *(const float4*)(kbv + c);
    f16x4 r; float g;
    g = s.x * rsqrtf(va.x + BN_EPS); r[0] = (f16)fmaf(kx - m.x, g, bi.x);
    g = s.y * rsqrtf(va.y + BN_EPS); r[1] = (f16)fmaf(ky - m.y, g, bi.y);
    g = s.z * rsqrtf(va.z + BN_EPS); r[2] = (f16)fmaf(kz - m.z, g, bi.z);
    g = s.w * rsqrtf(va.w + BN_EPS); r[3] = (f16)fmaf(kw4 - m.w, g, bi.w);
    *(f16x4*)(outk + (size_t)pix * CC + c) = r;
  }
  {
    const float4 s = *(const float4*)(vbs + c);
    const float4 bi = *(const float4*)(vbb + c);
    const float4 m = *(const float4*)(vbm + c);
    const float4 va = *(const float4*)(vbv + c);
    f16x4 r; float g;
    g = s.x * rsqrtf(va.x + BN_EPS); r[0] = (f16)fmaf(vx - m.x, g, bi.x);
    g = s.y * rsqrtf(va.y + BN_EPS); r[1] = (f16)fmaf(vy - m.y, g, bi.y);
    g = s.z * rsqrtf(va.z + BN_EPS); r[2] = (f16)fmaf(vz - m.z, g, bi.z);
    g = s.w * rsqrtf(va.w + BN_EPS); r[3] = (f16)fmaf(vw4 - m.w, g, bi.w);
    *(f16x4*)(outv + (size_t)pix * CC + c) = r;
  }
}

// ---- transpose-convert 4 weight matrices: fp32 [384(k)][384(n)] -> f16 [n][k] ----
__global__ __launch_bounds__(256) void convert_w(
    const float* __restrict__ w0, const float* __restrict__ w1,
    const float* __restrict__ w2, const float* __restrict__ w3,
    f16* __restrict__ o0, f16* __restrict__ o1,
    f16* __restrict__ o2, f16* __restrict__ o3) {
  const float* src = blockIdx.z == 0 ? w0 : blockIdx.z == 1 ? w1 : blockIdx.z == 2 ? w2 : w3;
  f16* dst = blockIdx.z == 0 ? o0 : blockIdx.z == 1 ? o1 : blockIdx.z == 2 ? o2 : o3;
  __shared__ float t[32][33];
  const int k0 = blockIdx.x * 32, n0 = blockIdx.y * 32;
  const int x = threadIdx.x & 31, y = threadIdx.x >> 5;
#pragma unroll
  for (int i = 0; i < 4; ++i) t[y + i * 8][x] = src[(size_t)(k0 + y + i * 8) * 384 + n0 + x];
  __syncthreads();
#pragma unroll
  for (int i = 0; i < 4; ++i)
    dst[(size_t)(n0 + y + i * 8) * 384 + k0 + x] = (f16)t[x][y + i * 8];
}

// ------------- f16 MFMA GEMM body (128x128 tile, 4 waves, 4x4 frags) -------------
template <int OF16>
__device__ __forceinline__ void gemm_body(
    const f16* __restrict__ A, const f16* __restrict__ Bt,
    float* __restrict__ Cf, f16* __restrict__ Ch, float scale,
    int row0, int col0) {
  __shared__ f16 As[128 * 32];   // [row][k], 64 B per row
  __shared__ f16 Bs[128 * 32];   // [col][k], 64 B per col
  const int tid = threadIdx.x;
  const int wave = tid >> 6, lane = tid & 63;
  const int c = lane & 15, g = lane >> 4;
  const int wr = wave >> 1, wc = wave & 1;     // 2x2 waves, each 64x64

  f32x4 acc[4][4] = {};

  for (int k0 = 0; k0 < 384; k0 += 32) {
    __syncthreads();
#pragma unroll
    for (int ph = 0; ph < 2; ++ph) {
      const int i = ph * 256 + wave * 64 + lane;   // chunk index: row = i>>2, ch = i&3
      const f16* sa = A + (size_t)(row0 + (i >> 2)) * 384 + k0 + (i & 3) * 8;
      __builtin_amdgcn_global_load_lds(
          (const __attribute__((address_space(1))) void*)sa,
          (__attribute__((address_space(3))) void*)(As + ph * 2048 + wave * 512), 16, 0, 0);
      const f16* sb = Bt + (size_t)(col0 + (i >> 2)) * 384 + k0 + (i & 3) * 8;
      __builtin_amdgcn_global_load_lds(
          (const __attribute__((address_space(1))) void*)sb,
          (__attribute__((address_space(3))) void*)(Bs + ph * 2048 + wave * 512), 16, 0, 0);
    }
    __syncthreads();

    f16x8 bf[4];
#pragma unroll
    for (int n = 0; n < 4; ++n)
      bf[n] = *(const f16x8*)(Bs + (size_t)(wc * 64 + n * 16 + c) * 32 + g * 8);
#pragma unroll
    for (int m = 0; m < 4; ++m) {
      f16x8 af = *(const f16x8*)(As + (size_t)(wr * 64 + m * 16 + c) * 32 + g * 8);
#pragma unroll
      for (int n = 0; n < 4; ++n)
        acc[m][n] = __builtin_amdgcn_mfma_f32_16x16x32_f16(af, bf[n], acc[m][n], 0, 0, 0);
    }
  }

#pragma unroll
  for (int m = 0; m < 4; ++m)
#pragma unroll
    for (int n = 0; n < 4; ++n)
#pragma unroll
      for (int r = 0; r < 4; ++r) {
        const size_t row = row0 + wr * 64 + m * 16 + g * 4 + r;
        const size_t col = col0 + wc * 64 + n * 16 + c;
        if (OF16) Ch[row * 384 + col] = (f16)(acc[m][n][r] * scale);
        else      Cf[row * 384 + col] = acc[m][n][r] * scale;
      }
}

template <int OF16>
__global__ __launch_bounds__(256) void gemm_mfma(
    const f16* __restrict__ A, const f16* __restrict__ Bt,
    float* __restrict__ Cf, f16* __restrict__ Ch, float scale) {
  gemm_body<OF16>(A, Bt, Cf, Ch, scale, blockIdx.x * 128, blockIdx.y * 128);
}

// k and v pointwise GEMMs in one launch (blockIdx.z picks)
__global__ __launch_bounds__(256) void gemm_kv(
    const f16* __restrict__ A0, const f16* __restrict__ B0, f16* __restrict__ C0,
    const f16* __restrict__ A1, const f16* __restrict__ B1, f16* __restrict__ C1) {
  if (blockIdx.z == 0)
    gemm_body<1>(A0, B0, nullptr, C0, 1.0f, blockIdx.x * 128, blockIdx.y * 128);
  else
    gemm_body<1>(A1, B1, nullptr, C1, 1.0f, blockIdx.x * 128, blockIdx.y * 128);
}

// ------------- per-batch transpose: in [b*784+kv][384] -> out [b*384+c][784] -------------
__global__ __launch_bounds__(256) void transpose_f16(
    const f16* __restrict__ in, f16* __restrict__ out) {
  __shared__ f16 t[32][33];
  const int b = blockIdx.z;
  const int kv0 = blockIdx.x * 32, c0 = blockIdx.y * 32;
  const int x = threadIdx.x & 31, y = threadIdx.x >> 5;  // 32 x 8
#pragma unroll
  for (int i = 0; i < 4; ++i) {
    int row = y + i * 8;
    int kv = kv0 + row;
    if (kv < NKV) t[row][x] = in[((size_t)b * NKV + kv) * 384 + c0 + x];
  }
  __syncthreads();
#pragma unroll
  for (int i = 0; i < 4; ++i) {
    int row = y + i * 8;
    if (kv0 + x < NKV)
      out[((size_t)b * 384 + c0 + row) * NKV + kv0 + x] = t[x][row];
  }
}

// ------------- f16 MFMA flash attention, swapped-QK^T (R6 staging + MFMA-lsum) -------------
// grid = B*NH*49; block 256 (4 waves x 16 q rows). KVT=64.
// Q pre-scaled by 0.125*log2(e); softmax = native exp2.
// S^T = mfma(A=K, B=Q): lane (c,g) holds S[kv = t0+ct*16+g*4+r][q = c].
// lsum computed on the MFMA pipe: o_sum = mfma(P, ones) -> row layout q=g*4+r
// (same as O) -> no per-tile lane-sum shuffles, no epilogue shuffle.
__global__ __launch_bounds__(256) void attn_mfma(
    const f16* __restrict__ qp, const f16* __restrict__ kp,
    const f16* __restrict__ vt, f16* __restrict__ op) {
  __shared__ f16 Ks[64 * 64];      // [kv][d], 128B rows, chunk ch stored at ch^(kv&7)
  __shared__ f16 Vs[64 * 64];      // [d][kv], 128B rows, chunk ch stored at ch^(d&7)
  __shared__ f16 Ps[4][16 * 64];   // per-wave [q][kv], 128B rows, ch^(q&7)
  const int bid = blockIdx.x;
  const int qt = bid % 49;
  const int bh = bid / 49;
  const int h = bh % NHD, b = bh / NHD;
  const int tid = threadIdx.x;
  const int wave = tid >> 6, lane = tid & 63;
  const int c = lane & 15, g = lane >> 4;

  const size_t qrow = (size_t)b * NQ + qt * 64 + wave * 16 + c;
  f16x8 qa[2];
  qa[0] = *(const f16x8*)(qp + qrow * 384 + h * 64 + g * 8);
  qa[1] = *(const f16x8*)(qp + qrow * 384 + h * 64 + 32 + g * 8);

  f16x8 vones;
#pragma unroll
  for (int j = 0; j < 8; ++j) vones[j] = (f16)1.0f;

  const int tid8 = tid >> 3, tch = tid & 7;
  const int lch = tch ^ (tid8 & 7);            // logical chunk fetched

  const f16* kbase = kp + ((size_t)b * NKV) * 384 + h * 64;
  const f16* vbase = vt + ((size_t)(b * 384 + h * 64)) * NKV;

  float mrun = -1e30f;                // for q = c (redundant across g)
  f32x4 o[4] = {};                    // O[q=g*4+r][d=dt*16+c]
  f32x4 osum = {};                    // lsum[q=g*4+r] (all cols equal)
  f16* prow = &Ps[wave][0];

  for (int t0 = 0; t0 < NKV; t0 += 64) {
    __syncthreads();
    {
      int kv0 = t0 + tid8; if (kv0 > NKV - 1) kv0 = NKV - 1;
      int kv1 = t0 + 32 + tid8; if (kv1 > NKV - 1) kv1 = NKV - 1;
      __builtin_amdgcn_global_load_lds(
          (const __attribute__((address_space(1))) void*)(kbase + (size_t)kv0 * 384 + lch * 8),
          (__attribute__((address_space(3))) void*)(Ks + wave * 512), 16, 0, 0);
      __builtin_amdgcn_global_load_lds(
          (const __attribute__((address_space(1))) void*)(kbase + (size_t)kv1 * 384 + lch * 8),
          (__attribute__((address_space(3))) void*)(Ks + 2048 + wave * 512), 16, 0, 0);
      int col = t0 + lch * 8; if (col > NKV - 8) col = NKV - 8;
      __builtin_amdgcn_global_load_lds(
          (const __attribute__((address_space(1))) void*)(vbase + (size_t)tid8 * NKV + col),
          (__attribute__((address_space(3))) void*)(Vs + wave * 512), 16, 0, 0);
      __builtin_amdgcn_global_load_lds(
          (const __attribute__((address_space(1))) void*)(vbase + (size_t)(32 + tid8) * NKV + col),
          (__attribute__((address_space(3))) void*)(Vs + 2048 + wave * 512), 16, 0, 0);
    }
    __syncthreads();

    // S^T tiles: s[ct] = K[t0+ct*16..+16) . Q^T, accumulated over kh
    f32x4 s[4] = {};
#pragma unroll
    for (int kh = 0; kh < 2; ++kh) {
#pragma unroll
      for (int ct = 0; ct < 4; ++ct) {
        const int row = ct * 16 + c;
        const int sch = (kh * 4 + g) ^ (row & 7);
        f16x8 kb = *(const f16x8*)(Ks + row * 64 + sch * 8);
        s[ct] = __builtin_amdgcn_mfma_f32_16x16x32_f16(kb, qa[kh], s[ct], 0, 0, 0);
      }
    }
    // tail mask
    if (t0 + 64 > NKV) {
#pragma unroll
      for (int ct = 0; ct < 4; ++ct)
#pragma unroll
        for (int r = 0; r < 4; ++r)
          if (t0 + ct * 16 + g * 4 + r >= NKV) s[ct][r] = -1e30f;
    }

    // tile max for q=c
    float mt = fmaxf(fmaxf(fmaxf(s[0][0], s[0][1]), fmaxf(s[0][2], s[0][3])),
                     fmaxf(fmaxf(s[1][0], s[1][1]), fmaxf(s[1][2], s[1][3])));
    mt = fmaxf(mt, fmaxf(fmaxf(fmaxf(s[2][0], s[2][1]), fmaxf(s[2][2], s[2][3])),
                         fmaxf(fmaxf(s[3][0], s[3][1]), fmaxf(s[3][2], s[3][3]))));
    mt = fmaxf(mt, __shfl_xor(mt, 16));
    mt = fmaxf(mt, __shfl_xor(mt, 32));

    // defer-max (log2 units; P bounded by 2^8)
    unsigned long long need = __ballot(mt > mrun + 8.0f);
    if (need) {
      const float mnew = fmaxf(mrun, mt);
      const float corr = fast_exp2(mrun - mnew);
      mrun = mnew;
#pragma unroll
      for (int r = 0; r < 4; ++r) {
        const float co = __shfl(corr, g * 4 + r);
#pragma unroll
        for (int dt = 0; dt < 4; ++dt) o[dt][r] *= co;
        osum[r] *= co;
      }
    }

    // P = exp2(S - mrun); pack f16 (pkrtz), store to per-wave LDS
#pragma unroll
    for (int ct = 0; ct < 4; ++ct) {
      const float p0 = fast_exp2(s[ct][0] - mrun);
      const float p1 = fast_exp2(s[ct][1] - mrun);
      const float p2 = fast_exp2(s[ct][2] - mrun);
      const float p3 = fast_exp2(s[ct][3] - mrun);
      const int sch = (ct * 2 + (g >> 1)) ^ (c & 7);
      *(f16x4*)(prow + c * 64 + sch * 8 + (g & 1) * 4) = pack4(p0, p1, p2, p3);
    }

    // PV + lsum: o[dt] += P * V; osum += P * 1 (two k-slices of 32)
#pragma unroll
    for (int ks = 0; ks < 2; ++ks) {
      const int sp = (ks * 4 + g) ^ (c & 7);
      f16x8 pa = *(const f16x8*)(prow + c * 64 + sp * 8);
#pragma unroll
      for (int dt = 0; dt < 4; ++dt) {
        const int d = dt * 16 + c;
        f16x8 vb = *(const f16x8*)(Vs + d * 64 + sp * 8);  // (ks*4+g)^(d&7) == sp
        o[dt] = __builtin_amdgcn_mfma_f32_16x16x32_f16(pa, vb, o[dt], 0, 0, 0);
      }
      osum = __builtin_amdgcn_mfma_f32_16x16x32_f16(pa, vones, osum, 0, 0, 0);
    }
  }

  // epilogue: osum already in q=g*4+r row layout -> no shuffles
  f16* obase = op + ((size_t)(b * NQ + qt * 64 + wave * 16)) * 384 + h * 64;
#pragma unroll
  for (int r = 0; r < 4; ++r) {
    const float iv = 1.0f / osum[r];
#pragma unroll
    for (int dt = 0; dt < 4; ++dt)
      obase[(size_t)(g * 4 + r) * 384 + dt * 16 + c] = (f16)(o[dt][r] * iv);
  }
}

extern "C" void kernel_launch(void* const* d_in, const int* in_sizes, int n_in,
                              void* d_out, int out_size, void* d_ws, size_t ws_size,
                              hipStream_t stream) {
  const float* inputs_q  = (const float*)d_in[0];
  const float* inputs_kv = (const float*)d_in[1];
  const float* out_kern  = (const float*)d_in[2];
  const float* q_dwk = (const float*)d_in[3];
  const float* q_bs  = (const float*)d_in[4];
  const float* q_bb  = (const float*)d_in[5];
  const float* q_bm  = (const float*)d_in[6];
  const float* q_bv  = (const float*)d_in[7];
  const float* q_pwk = (const float*)d_in[8];
  const float* k_dwk = (const float*)d_in[9];
  const float* k_bs  = (const float*)d_in[10];
  const float* k_bb  = (const float*)d_in[11];
  const float* k_bm  = (const float*)d_in[12];
  const float* k_bv  = (const float*)d_in[13];
  const float* k_pwk = (const float*)d_in[14];
  const float* v_dwk = (const float*)d_in[15];
  const float* v_bs  = (const float*)d_in[16];
  const float* v_bb  = (const float*)d_in[17];
  const float* v_bm  = (const float*)d_in[18];
  const float* v_bv  = (const float*)d_in[19];
  const float* v_pwk = (const float*)d_in[20];

  char* wsb = (char*)d_ws;
  f16* qdw = (f16*)(wsb + 0);             // 25088*384 f16
  f16* kdw = (f16*)(wsb + 19267584);      // 6272*384 f16
  f16* vdw = (f16*)(wsb + 24084480);      // 6272*384 f16
  f16* qf  = (f16*)(wsb + 28901376);      // 25088*384 f16
  f16* kf  = (f16*)(wsb + 48168960);      // 6272*384 f16
  f16* vf  = (f16*)(wsb + 52985856);      // 6272*384 f16
  f16* vtp = (f16*)(wsb + 57802752);      // 8*384*784 f16
  f16* of  = (f16*)(wsb + 62619648);      // 25088*384 f16
  f16* wqt = (f16*)(wsb + 81887232);      // 384*384 f16 x4
  f16* wkt = (f16*)(wsb + 82182144);
  f16* wvt = (f16*)(wsb + 82477056);
  f16* wot = (f16*)(wsb + 82771968);

  // 0. weight transpose-convert
  convert_w<<<dim3(12, 12, 4), 256, 0, stream>>>(
      q_pwk, k_pwk, v_pwk, out_kern, wqt, wkt, wvt, wot);
  // 1. depthwise + BN -> f16
  dw_bn_s1<<<4704, 256, 0, stream>>>(inputs_q, q_dwk, q_bs, q_bb, q_bm, q_bv, qdw);
  dw_bn_s2_kv<<<2352, 256, 0, stream>>>(inputs_kv,
      k_dwk, k_bs, k_bb, k_bm, k_bv,
      v_dwk, v_bs, v_bb, v_bm, v_bv,
      kdw, vdw);
  // 2. pointwise GEMMs (q folded with 1/8 * log2e for exp2 softmax)
  gemm_mfma<1><<<dim3(196, 3), 256, 0, stream>>>(qdw, wqt, nullptr, qf, 0.125f * LOG2E);
  gemm_kv<<<dim3(49, 3, 2), 256, 0, stream>>>(kdw, wkt, kf, vdw, wvt, vf);
  // 3. V transpose per batch
  transpose_f16<<<dim3(25, 12, 8), 256, 0, stream>>>(vf, vtp);
  // 4. MFMA attention (V in LDS, MFMA-lsum) -> f16 O
  attn_mfma<<<BB * NHD * 49, 256, 0, stream>>>(qf, kf, vtp, of);
  // 5. output projection (MFMA, fp32 out)
  gemm_mfma<0><<<dim3(196, 3), 256, 0, stream>>>(of, wot, (float*)d_out, nullptr, 1.0f);
}

// Round 11
// 164.773 us; speedup vs baseline: 1.2387x; 1.0785x over previous
//
#include <hip/hip_runtime.h>
#include <hip/hip_bf16.h>
#include <hip/hip_fp16.h>

// Problem constants
#define BB 8
#define HH 56
#define WW 56
#define CC 384
#define NHD 6
#define DD 64
#define HK 28
#define WK 28
#define NQ (HH*WW)       // 3136
#define NKV (HK*WK)      // 784
#define NTOK (BB*NQ)     // 25088
#define NTOKKV (BB*NKV)  // 6272
#define BN_EPS 1e-5f
#define LOG2E 1.44269504f

typedef _Float16 f16;
typedef _Float16 f16x2 __attribute__((ext_vector_type(2)));
typedef _Float16 f16x4 __attribute__((ext_vector_type(4)));
typedef _Float16 f16x8 __attribute__((ext_vector_type(8)));
typedef float f32x4 __attribute__((ext_vector_type(4)));

__device__ __forceinline__ float fast_exp2(float x) {
#if __has_builtin(__builtin_amdgcn_exp2f)
  return __builtin_amdgcn_exp2f(x);   // v_exp_f32 (2^x)
#else
  return __expf(x * 0.69314718056f);
#endif
}

__device__ __forceinline__ f16x4 pack4(float p0, float p1, float p2, float p3) {
#if __has_builtin(__builtin_amdgcn_cvt_pkrtz)
  f16x2 a = __builtin_bit_cast(f16x2, __builtin_amdgcn_cvt_pkrtz(p0, p1));
  f16x2 b = __builtin_bit_cast(f16x2, __builtin_amdgcn_cvt_pkrtz(p2, p3));
  return __builtin_shufflevector(a, b, 0, 1, 2, 3);
#else
  f16x4 r; r[0] = (f16)p0; r[1] = (f16)p1; r[2] = (f16)p2; r[3] = (f16)p3;
  return r;
#endif
}

// ---------------- dw conv + BN bodies (called from fused preprocess) ----------------
__device__ __forceinline__ void dw_s1_body(
    int blk, int tid, const float* __restrict__ in, const float* __restrict__ w,
    const float* __restrict__ bns, const float* __restrict__ bnb,
    const float* __restrict__ bnm, const float* __restrict__ bnv,
    f16* __restrict__ out) {
  int idx = blk * 256 + tid;                     // < (NTOK/2)*96 = 1204224
  int pp = idx / 96;
  int c = (idx % 96) * 4;
  int b = pp / (HH * WK);
  int rem = pp % (HH * WK);
  int y = rem / WK, xh = rem % WK;
  int x0 = xh * 2;
  float a0x = 0, a0y = 0, a0z = 0, a0w = 0;
  float a1x = 0, a1y = 0, a1z = 0, a1w = 0;
#pragma unroll
  for (int kh = 0; kh < 3; ++kh) {
    int iy = y + kh - 1;
    if ((unsigned)iy >= (unsigned)HH) continue;
    const float* rp = in + ((size_t)(b * HH + iy) * WW) * CC + c;
    const float4 z4 = {0.f, 0.f, 0.f, 0.f};
    const float4 v0 = (x0 > 0) ? *(const float4*)(rp + (size_t)(x0 - 1) * CC) : z4;
    const float4 v1 = *(const float4*)(rp + (size_t)x0 * CC);
    const float4 v2 = *(const float4*)(rp + (size_t)(x0 + 1) * CC);
    const float4 v3 = (x0 < 54) ? *(const float4*)(rp + (size_t)(x0 + 2) * CC) : z4;
    const float4 w0 = *(const float4*)(w + (kh * 3 + 0) * CC + c);
    const float4 w1 = *(const float4*)(w + (kh * 3 + 1) * CC + c);
    const float4 w2 = *(const float4*)(w + (kh * 3 + 2) * CC + c);
    a0x = fmaf(v0.x, w0.x, fmaf(v1.x, w1.x, fmaf(v2.x, w2.x, a0x)));
    a0y = fmaf(v0.y, w0.y, fmaf(v1.y, w1.y, fmaf(v2.y, w2.y, a0y)));
    a0z = fmaf(v0.z, w0.z, fmaf(v1.z, w1.z, fmaf(v2.z, w2.z, a0z)));
    a0w = fmaf(v0.w, w0.w, fmaf(v1.w, w1.w, fmaf(v2.w, w2.w, a0w)));
    a1x = fmaf(v1.x, w0.x, fmaf(v2.x, w1.x, fmaf(v3.x, w2.x, a1x)));
    a1y = fmaf(v1.y, w0.y, fmaf(v2.y, w1.y, fmaf(v3.y, w2.y, a1y)));
    a1z = fmaf(v1.z, w0.z, fmaf(v2.z, w1.z, fmaf(v3.z, w2.z, a1z)));
    a1w = fmaf(v1.w, w0.w, fmaf(v2.w, w1.w, fmaf(v3.w, w2.w, a1w)));
  }
  const float4 s = *(const float4*)(bns + c);
  const float4 bi = *(const float4*)(bnb + c);
  const float4 m = *(const float4*)(bnm + c);
  const float4 va = *(const float4*)(bnv + c);
  f16x4 r0, r1;
  float g;
  g = s.x * rsqrtf(va.x + BN_EPS); r0[0] = (f16)fmaf(a0x - m.x, g, bi.x); r1[0] = (f16)fmaf(a1x - m.x, g, bi.x);
  g = s.y * rsqrtf(va.y + BN_EPS); r0[1] = (f16)fmaf(a0y - m.y, g, bi.y); r1[1] = (f16)fmaf(a1y - m.y, g, bi.y);
  g = s.z * rsqrtf(va.z + BN_EPS); r0[2] = (f16)fmaf(a0z - m.z, g, bi.z); r1[2] = (f16)fmaf(a1z - m.z, g, bi.z);
  g = s.w * rsqrtf(va.w + BN_EPS); r0[3] = (f16)fmaf(a0w - m.w, g, bi.w); r1[3] = (f16)fmaf(a1w - m.w, g, bi.w);
  const size_t pix0 = (size_t)b * NQ + y * WW + x0;
  *(f16x4*)(out + pix0 * CC + c) = r0;
  *(f16x4*)(out + (pix0 + 1) * CC + c) = r1;
}

__device__ __forceinline__ void dw_s2_body(
    int blk, int tid, const float* __restrict__ in,
    const float* __restrict__ wk_, const float* __restrict__ kbs, const float* __restrict__ kbb,
    const float* __restrict__ kbm, const float* __restrict__ kbv,
    const float* __restrict__ wv_, const float* __restrict__ vbs, const float* __restrict__ vbb,
    const float* __restrict__ vbm, const float* __restrict__ vbv,
    f16* __restrict__ outk, f16* __restrict__ outv) {
  int idx = blk * 256 + tid;                     // < NTOKKV*96
  int pix = idx / 96;
  int c = (idx % 96) * 4;
  int b = pix / (HK * WK);
  int p = pix % (HK * WK);
  int oy = p / WK, ox = p % WK;
  float kx = 0, ky = 0, kz = 0, kw4 = 0;
  float vx = 0, vy = 0, vz = 0, vw4 = 0;
#pragma unroll
  for (int kh = 0; kh < 3; ++kh) {
    int iy = oy * 2 + kh;
    if (iy >= HH) continue;
#pragma unroll
    for (int kwi = 0; kwi < 3; ++kwi) {
      int ix = ox * 2 + kwi;
      if (ix >= WW) continue;
      const float4 v = *(const float4*)(in + (((size_t)(b * HH + iy) * WW + ix) * CC + c));
      const float4 a = *(const float4*)(wk_ + ((kh * 3 + kwi) * CC + c));
      const float4 bq = *(const float4*)(wv_ + ((kh * 3 + kwi) * CC + c));
      kx = fmaf(v.x, a.x, kx); ky = fmaf(v.y, a.y, ky);
      kz = fmaf(v.z, a.z, kz); kw4 = fmaf(v.w, a.w, kw4);
      vx = fmaf(v.x, bq.x, vx); vy = fmaf(v.y, bq.y, vy);
      vz = fmaf(v.z, bq.z, vz); vw4 = fmaf(v.w, bq.w, vw4);
    }
  }
  {
    const float4 s = *(const float4*)(kbs + c);
    const float4 bi = *(const float4*)(kbb + c);
    const float4 m = *(const float4*)(kbm + c);
    const float4 va = *(const float4*)(kbv + c);
    f16x4 r; float g;
    g = s.x * rsqrtf(va.x + BN_EPS); r[0] = (f16)fmaf(kx - m.x, g, bi.x);
    g = s.y * rsqrtf(va.y + BN_EPS); r[1] = (f16)fmaf(ky - m.y, g, bi.y);
    g = s.z * rsqrtf(va.z + BN_EPS); r[2] = (f16)fmaf(kz - m.z, g, bi.z);
    g = s.w * rsqrtf(va.w + BN_EPS); r[3] = (f16)fmaf(kw4 - m.w, g, bi.w);
    *(f16x4*)(outk + (size_t)pix * CC + c) = r;
  }
  {
    const float4 s = *(const float4*)(vbs + c);
    const float4 bi = *(const float4*)(vbb + c);
    const float4 m = *(const float4*)(vbm + c);
    const float4 va = *(const float4*)(vbv + c);
    f16x4 r; float g;
    g = s.x * rsqrtf(va.x + BN_EPS); r[0] = (f16)fmaf(vx - m.x, g, bi.x);
    g = s.y * rsqrtf(va.y + BN_EPS); r[1] = (f16)fmaf(vy - m.y, g, bi.y);
    g = s.z * rsqrtf(va.z + BN_EPS); r[2] = (f16)fmaf(vz - m.z, g, bi.z);
    g = s.w * rsqrtf(va.w + BN_EPS); r[3] = (f16)fmaf(vw4 - m.w, g, bi.w);
    *(f16x4*)(outv + (size_t)pix * CC + c) = r;
  }
}

// ---- fused preprocess: dw_s1 (4704 blocks) + dw_s2_kv (2352) + convert_w (576) ----
__global__ __launch_bounds__(256) void preprocess(
    const float* __restrict__ inputs_q, const float* __restrict__ inputs_kv,
    const float* __restrict__ q_dwk, const float* __restrict__ q_bs,
    const float* __restrict__ q_bb, const float* __restrict__ q_bm,
    const float* __restrict__ q_bv,
    const float* __restrict__ k_dwk, const float* __restrict__ k_bs,
    const float* __restrict__ k_bb, const float* __restrict__ k_bm,
    const float* __restrict__ k_bv,
    const float* __restrict__ v_dwk, const float* __restrict__ v_bs,
    const float* __restrict__ v_bb, const float* __restrict__ v_bm,
    const float* __restrict__ v_bv,
    const float* __restrict__ w0, const float* __restrict__ w1,
    const float* __restrict__ w2, const float* __restrict__ w3,
    f16* __restrict__ o0, f16* __restrict__ o1,
    f16* __restrict__ o2, f16* __restrict__ o3,
    f16* __restrict__ qdw, f16* __restrict__ kdw, f16* __restrict__ vdw) {
  __shared__ float t[32][33];
  const int blk = blockIdx.x;
  const int tid = threadIdx.x;
  if (blk < 4704) {
    dw_s1_body(blk, tid, inputs_q, q_dwk, q_bs, q_bb, q_bm, q_bv, qdw);
  } else if (blk < 7056) {
    dw_s2_body(blk - 4704, tid, inputs_kv,
               k_dwk, k_bs, k_bb, k_bm, k_bv,
               v_dwk, v_bs, v_bb, v_bm, v_bv, kdw, vdw);
  } else {
    const int r = blk - 7056;                 // 0..575  (12 x 12 x 4)
    const int z = r / 144, rem = r % 144;
    const int bx = rem % 12, by = rem / 12;
    const float* src = z == 0 ? w0 : z == 1 ? w1 : z == 2 ? w2 : w3;
    f16* dst = z == 0 ? o0 : z == 1 ? o1 : z == 2 ? o2 : o3;
    const int k0 = bx * 32, n0 = by * 32;
    const int x = tid & 31, y = tid >> 5;
#pragma unroll
    for (int i = 0; i < 4; ++i) t[y + i * 8][x] = src[(size_t)(k0 + y + i * 8) * 384 + n0 + x];
    __syncthreads();
#pragma unroll
    for (int i = 0; i < 4; ++i)
      dst[(size_t)(n0 + y + i * 8) * 384 + k0 + x] = (f16)t[x][y + i * 8];
  }
}

// ------------- f16 MFMA GEMM body (128x128 tile, 4 waves, 4x4 frags) -------------
// MODE 0: fp32 row-major; MODE 1: f16 row-major; MODE 2: f16 V^T (vtp [b*384+d][784])
template <int MODE>
__device__ __forceinline__ void gemm_body(
    const f16* __restrict__ A, const f16* __restrict__ Bt,
    float* __restrict__ Cf, f16* __restrict__ Ch, float scale,
    int row0, int col0) {
  __shared__ f16 As[128 * 32];   // [row][k], 64 B per row
  __shared__ f16 Bs[128 * 32];   // [col][k], 64 B per col
  const int tid = threadIdx.x;
  const int wave = tid >> 6, lane = tid & 63;
  const int c = lane & 15, g = lane >> 4;
  const int wr = wave >> 1, wc = wave & 1;     // 2x2 waves, each 64x64

  f32x4 acc[4][4] = {};

  for (int k0 = 0; k0 < 384; k0 += 32) {
    __syncthreads();
#pragma unroll
    for (int ph = 0; ph < 2; ++ph) {
      const int i = ph * 256 + wave * 64 + lane;   // chunk index: row = i>>2, ch = i&3
      const f16* sa = A + (size_t)(row0 + (i >> 2)) * 384 + k0 + (i & 3) * 8;
      __builtin_amdgcn_global_load_lds(
          (const __attribute__((address_space(1))) void*)sa,
          (__attribute__((address_space(3))) void*)(As + ph * 2048 + wave * 512), 16, 0, 0);
      const f16* sb = Bt + (size_t)(col0 + (i >> 2)) * 384 + k0 + (i & 3) * 8;
      __builtin_amdgcn_global_load_lds(
          (const __attribute__((address_space(1))) void*)sb,
          (__attribute__((address_space(3))) void*)(Bs + ph * 2048 + wave * 512), 16, 0, 0);
    }
    __syncthreads();

    f16x8 bf[4];
#pragma unroll
    for (int n = 0; n < 4; ++n)
      bf[n] = *(const f16x8*)(Bs + (size_t)(wc * 64 + n * 16 + c) * 32 + g * 8);
#pragma unroll
    for (int m = 0; m < 4; ++m) {
      f16x8 af = *(const f16x8*)(As + (size_t)(wr * 64 + m * 16 + c) * 32 + g * 8);
#pragma unroll
      for (int n = 0; n < 4; ++n)
        acc[m][n] = __builtin_amdgcn_mfma_f32_16x16x32_f16(af, bf[n], acc[m][n], 0, 0, 0);
    }
  }

  if (MODE == 2) {
    // transposed V store: acc[m][n][r] = V[token = row0+wr*64+m*16+g*4+r][d = col0+wc*64+n*16+c]
#pragma unroll
    for (int m = 0; m < 4; ++m)
#pragma unroll
      for (int n = 0; n < 4; ++n) {
        const int gr = row0 + wr * 64 + m * 16 + g * 4;
        const int col = col0 + wc * 64 + n * 16 + c;
        const int bb = gr / NKV;
        const int kv = gr - bb * NKV;           // 4-pack cannot cross batch (784%4==0, gr%4==0)
        f16x4 pk;
#pragma unroll
        for (int r = 0; r < 4; ++r) pk[r] = (f16)(acc[m][n][r] * scale);
        *(f16x4*)(Ch + ((size_t)bb * 384 + col) * NKV + kv) = pk;
      }
  } else {
#pragma unroll
    for (int m = 0; m < 4; ++m)
#pragma unroll
      for (int n = 0; n < 4; ++n)
#pragma unroll
        for (int r = 0; r < 4; ++r) {
          const size_t row = row0 + wr * 64 + m * 16 + g * 4 + r;
          const size_t col = col0 + wc * 64 + n * 16 + c;
          if (MODE == 1) Ch[row * 384 + col] = (f16)(acc[m][n][r] * scale);
          else           Cf[row * 384 + col] = acc[m][n][r] * scale;
        }
  }
}

// fused q/k/v pointwise GEMMs: 882 flat blocks = q(196x3) + k(49x3) + v(49x3)
__global__ __launch_bounds__(256) void gemm_qkv(
    const f16* __restrict__ qdw, const f16* __restrict__ wqt, f16* __restrict__ qf, float qscale,
    const f16* __restrict__ kdw, const f16* __restrict__ wkt, f16* __restrict__ kf,
    const f16* __restrict__ vdw, const f16* __restrict__ wvt, f16* __restrict__ vtp) {
  const int blk = blockIdx.x;
  if (blk < 588) {
    gemm_body<1>(qdw, wqt, nullptr, qf, qscale, (blk % 196) * 128, (blk / 196) * 128);
  } else if (blk < 735) {
    const int r = blk - 588;
    gemm_body<1>(kdw, wkt, nullptr, kf, 1.0f, (r % 49) * 128, (r / 49) * 128);
  } else {
    const int r = blk - 735;
    gemm_body<2>(vdw, wvt, nullptr, vtp, 1.0f, (r % 49) * 128, (r / 49) * 128);
  }
}

template <int MODE>
__global__ __launch_bounds__(256) void gemm_mfma(
    const f16* __restrict__ A, const f16* __restrict__ Bt,
    float* __restrict__ Cf, f16* __restrict__ Ch, float scale) {
  gemm_body<MODE>(A, Bt, Cf, Ch, scale, blockIdx.x * 128, blockIdx.y * 128);
}

// ------------- attention softmax helper (per q-fragment) -------------
__device__ __forceinline__ void softmax_tile(
    f32x4 (&s)[4], float& mrun, f32x4 (&o)[4], f32x4& osum,
    f16* __restrict__ pq, int c, int g) {
  float mt = s[0][0];
#pragma unroll
  for (int ct = 0; ct < 4; ++ct)
#pragma unroll
    for (int r = 0; r < 4; ++r) mt = fmaxf(mt, s[ct][r]);
  mt = fmaxf(mt, __shfl_xor(mt, 16));
  mt = fmaxf(mt, __shfl_xor(mt, 32));
  if (__ballot(mt > mrun + 8.0f)) {     // defer-max: P bounded by 2^8
    const float mnew = fmaxf(mrun, mt);
    const float corr = fast_exp2(mrun - mnew);
    mrun = mnew;
#pragma unroll
    for (int r = 0; r < 4; ++r) {
      const float co = __shfl(corr, g * 4 + r);
#pragma unroll
      for (int dt = 0; dt < 4; ++dt) o[dt][r] *= co;
      osum[r] *= co;
    }
  }
#pragma unroll
  for (int ct = 0; ct < 4; ++ct) {
    const float p0 = fast_exp2(s[ct][0] - mrun);
    const float p1 = fast_exp2(s[ct][1] - mrun);
    const float p2 = fast_exp2(s[ct][2] - mrun);
    const float p3 = fast_exp2(s[ct][3] - mrun);
    const int sch = (ct * 2 + (g >> 1)) ^ (c & 7);
    *(f16x4*)(pq + c * 64 + sch * 8 + (g & 1) * 4) = pack4(p0, p1, p2, p3);
  }
}

// ------------- f16 MFMA flash attention, QBLK=128 (2 q-frags/wave), swapped QK^T -------------
// grid = B*NH*25; block 256 (4 waves x 32 q rows). KVT=64. qt=24 has only 64 valid rows.
// kb (K A-frag) and vb (V B-frag) LDS reads SHARED across both q-fragments.
__global__ __launch_bounds__(256) void attn_mfma(
    const f16* __restrict__ qp, const f16* __restrict__ kp,
    const f16* __restrict__ vt, f16* __restrict__ op) {
  __shared__ f16 Ks[64 * 64];      // [kv][d], chunk ch at ch^(kv&7)
  __shared__ f16 Vs[64 * 64];      // [d][kv], chunk ch at ch^(d&7)
  __shared__ f16 Ps[4][32 * 64];   // per-wave [q(32 rows)][kv], ch^(row&7)
  const int bid = blockIdx.x;
  const int qt = bid % 25;
  const int bh = bid / 25;
  const int h = bh % NHD, b = bh / NHD;
  const int tid = threadIdx.x;
  const int wave = tid >> 6, lane = tid & 63;
  const int c = lane & 15, g = lane >> 4;

  const int qr0 = qt * 128 + wave * 16 + c;           // always < NQ
  int qr1 = qt * 128 + 64 + wave * 16 + c;
  if (qr1 > NQ - 1) qr1 = NQ - 1;                     // tail block: clamp (no store)
  const f16* qpb = qp + (size_t)b * NQ * 384 + h * 64;
  f16x8 qa[2][2];                                     // [qf][kh]
  qa[0][0] = *(const f16x8*)(qpb + (size_t)qr0 * 384 + g * 8);
  qa[0][1] = *(const f16x8*)(qpb + (size_t)qr0 * 384 + 32 + g * 8);
  qa[1][0] = *(const f16x8*)(qpb + (size_t)qr1 * 384 + g * 8);
  qa[1][1] = *(const f16x8*)(qpb + (size_t)qr1 * 384 + 32 + g * 8);

  f16x8 vones;
#pragma unroll
  for (int j = 0; j < 8; ++j) vones[j] = (f16)1.0f;

  const int tid8 = tid >> 3, tch = tid & 7;
  const int lch = tch ^ (tid8 & 7);

  const f16* kbase = kp + (size_t)b * NKV * 384 + h * 64;
  const f16* vbase = vt + ((size_t)(b * 384 + h * 64)) * NKV;

  float mrun0 = -1e30f, mrun1 = -1e30f;
  f32x4 o0[4] = {}, o1[4] = {};
  f32x4 osum0 = {}, osum1 = {};
  f16* prow = &Ps[wave][0];

  for (int t0 = 0; t0 < NKV; t0 += 64) {
    __syncthreads();
    {
      int kv0 = t0 + tid8; if (kv0 > NKV - 1) kv0 = NKV - 1;
      int kv1 = t0 + 32 + tid8; if (kv1 > NKV - 1) kv1 = NKV - 1;
      __builtin_amdgcn_global_load_lds(
          (const __attribute__((address_space(1))) void*)(kbase + (size_t)kv0 * 384 + lch * 8),
          (__attribute__((address_space(3))) void*)(Ks + wave * 512), 16, 0, 0);
      __builtin_amdgcn_global_load_lds(
          (const __attribute__((address_space(1))) void*)(kbase + (size_t)kv1 * 384 + lch * 8),
          (__attribute__((address_space(3))) void*)(Ks + 2048 + wave * 512), 16, 0, 0);
      int col = t0 + lch * 8; if (col > NKV - 8) col = NKV - 8;
      __builtin_amdgcn_global_load_lds(
          (const __attribute__((address_space(1))) void*)(vbase + (size_t)tid8 * NKV + col),
          (__attribute__((address_space(3))) void*)(Vs + wave * 512), 16, 0, 0);
      __builtin_amdgcn_global_load_lds(
          (const __attribute__((address_space(1))) void*)(vbase + (size_t)(32 + tid8) * NKV + col),
          (__attribute__((address_space(3))) void*)(Vs + 2048 + wave * 512), 16, 0, 0);
    }
    __syncthreads();

    // S^T: kb shared across both q-fragments
    f32x4 s0[4] = {}, s1[4] = {};
#pragma unroll
    for (int kh = 0; kh < 2; ++kh) {
#pragma unroll
      for (int ct = 0; ct < 4; ++ct) {
        const int row = ct * 16 + c;
        const int sch = (kh * 4 + g) ^ (row & 7);
        f16x8 kb = *(const f16x8*)(Ks + row * 64 + sch * 8);
        s0[ct] = __builtin_amdgcn_mfma_f32_16x16x32_f16(kb, qa[0][kh], s0[ct], 0, 0, 0);
        s1[ct] = __builtin_amdgcn_mfma_f32_16x16x32_f16(kb, qa[1][kh], s1[ct], 0, 0, 0);
      }
    }
    if (t0 + 64 > NKV) {
#pragma unroll
      for (int ct = 0; ct < 4; ++ct)
#pragma unroll
        for (int r = 0; r < 4; ++r)
          if (t0 + ct * 16 + g * 4 + r >= NKV) { s0[ct][r] = -1e30f; s1[ct][r] = -1e30f; }
    }

    softmax_tile(s0, mrun0, o0, osum0, prow, c, g);            // rows c
    softmax_tile(s1, mrun1, o1, osum1, prow + 16 * 64, c, g);  // rows 16+c

    // PV: vb shared across both q-fragments
#pragma unroll
    for (int ks = 0; ks < 2; ++ks) {
      const int sp = (ks * 4 + g) ^ (c & 7);
      f16x8 pa0 = *(const f16x8*)(prow + c * 64 + sp * 8);
      f16x8 pa1 = *(const f16x8*)(prow + (16 + c) * 64 + sp * 8);
#pragma unroll
      for (int dt = 0; dt < 4; ++dt) {
        const int d = dt * 16 + c;
        f16x8 vb = *(const f16x8*)(Vs + d * 64 + sp * 8);
        o0[dt] = __builtin_amdgcn_mfma_f32_16x16x32_f16(pa0, vb, o0[dt], 0, 0, 0);
        o1[dt] = __builtin_amdgcn_mfma_f32_16x16x32_f16(pa1, vb, o1[dt], 0, 0, 0);
      }
      osum0 = __builtin_amdgcn_mfma_f32_16x16x32_f16(pa0, vones, osum0, 0, 0, 0);
      osum1 = __builtin_amdgcn_mfma_f32_16x16x32_f16(pa1, vones, osum1, 0, 0, 0);
    }
  }

  // epilogue (osum in q=g*4+r row layout)
  f16* ob0 = op + ((size_t)(b * NQ + qt * 128 + wave * 16)) * 384 + h * 64;
#pragma unroll
  for (int r = 0; r < 4; ++r) {
    const float iv = 1.0f / osum0[r];
#pragma unroll
    for (int dt = 0; dt < 4; ++dt)
      ob0[(size_t)(g * 4 + r) * 384 + dt * 16 + c] = (f16)(o0[dt][r] * iv);
  }
  if (qt != 24) {
    f16* ob1 = op + ((size_t)(b * NQ + qt * 128 + 64 + wave * 16)) * 384 + h * 64;
#pragma unroll
    for (int r = 0; r < 4; ++r) {
      const float iv = 1.0f / osum1[r];
#pragma unroll
      for (int dt = 0; dt < 4; ++dt)
        ob1[(size_t)(g * 4 + r) * 384 + dt * 16 + c] = (f16)(o1[dt][r] * iv);
    }
  }
}

extern "C" void kernel_launch(void* const* d_in, const int* in_sizes, int n_in,
                              void* d_out, int out_size, void* d_ws, size_t ws_size,
                              hipStream_t stream) {
  const float* inputs_q  = (const float*)d_in[0];
  const float* inputs_kv = (const float*)d_in[1];
  const float* out_kern  = (const float*)d_in[2];
  const float* q_dwk = (const float*)d_in[3];
  const float* q_bs  = (const float*)d_in[4];
  const float* q_bb  = (const float*)d_in[5];
  const float* q_bm  = (const float*)d_in[6];
  const float* q_bv  = (const float*)d_in[7];
  const float* q_pwk = (const float*)d_in[8];
  const float* k_dwk = (const float*)d_in[9];
  const float* k_bs  = (const float*)d_in[10];
  const float* k_bb  = (const float*)d_in[11];
  const float* k_bm  = (const float*)d_in[12];
  const float* k_bv  = (const float*)d_in[13];
  const float* k_pwk = (const float*)d_in[14];
  const float* v_dwk = (const float*)d_in[15];
  const float* v_bs  = (const float*)d_in[16];
  const float* v_bb  = (const float*)d_in[17];
  const float* v_bm  = (const float*)d_in[18];
  const float* v_bv  = (const float*)d_in[19];
  const float* v_pwk = (const float*)d_in[20];

  char* wsb = (char*)d_ws;
  f16* qdw = (f16*)(wsb + 0);             // 25088*384 f16
  f16* kdw = (f16*)(wsb + 19267584);      // 6272*384 f16
  f16* vdw = (f16*)(wsb + 24084480);      // 6272*384 f16
  f16* qf  = (f16*)(wsb + 28901376);      // 25088*384 f16
  f16* kf  = (f16*)(wsb + 48168960);      // 6272*384 f16
  f16* vtp = (f16*)(wsb + 57802752);      // 8*384*784 f16
  f16* of  = (f16*)(wsb + 62619648);      // 25088*384 f16
  f16* wqt = (f16*)(wsb + 81887232);      // 384*384 f16 x4
  f16* wkt = (f16*)(wsb + 82182144);
  f16* wvt = (f16*)(wsb + 82477056);
  f16* wot = (f16*)(wsb + 82771968);

  // 1. fused preprocess: dw+BN (q, k&v) + weight transpose-convert
  preprocess<<<7632, 256, 0, stream>>>(
      inputs_q, inputs_kv,
      q_dwk, q_bs, q_bb, q_bm, q_bv,
      k_dwk, k_bs, k_bb, k_bm, k_bv,
      v_dwk, v_bs, v_bb, v_bm, v_bv,
      q_pwk, k_pwk, v_pwk, out_kern, wqt, wkt, wvt, wot,
      qdw, kdw, vdw);
  // 2. fused q/k/v pointwise GEMMs (V written transposed; q folded with 1/8*log2e)
  gemm_qkv<<<882, 256, 0, stream>>>(qdw, wqt, qf, 0.125f * LOG2E,
                                    kdw, wkt, kf, vdw, wvt, vtp);
  // 3. MFMA attention (QBLK=128) -> f16 O
  attn_mfma<<<BB * NHD * 25, 256, 0, stream>>>(qf, kf, vtp, of);
  // 4. output projection (MFMA, fp32 out)
  gemm_mfma<0><<<dim3(196, 3), 256, 0, stream>>>(of, wot, (float*)d_out, nullptr, 1.0f);
}

// Round 12
// 153.744 us; speedup vs baseline: 1.3276x; 1.0717x over previous
//
#include <hip/hip_runtime.h>
#include <hip/hip_bf16.h>
#include <hip/hip_fp16.h>

// Problem constants
#define BB 8
#define HH 56
#define WW 56
#define CC 384
#define NHD 6
#define DD 64
#define HK 28
#define WK 28
#define NQ (HH*WW)       // 3136
#define NKV (HK*WK)      // 784
#define NTOK (BB*NQ)     // 25088
#define NTOKKV (BB*NKV)  // 6272
#define BN_EPS 1e-5f
#define LOG2E 1.44269504f

typedef _Float16 f16;
typedef _Float16 f16x2 __attribute__((ext_vector_type(2)));
typedef _Float16 f16x4 __attribute__((ext_vector_type(4)));
typedef _Float16 f16x8 __attribute__((ext_vector_type(8)));
typedef float f32x4 __attribute__((ext_vector_type(4)));

__device__ __forceinline__ float fast_exp2(float x) {
#if __has_builtin(__builtin_amdgcn_exp2f)
  return __builtin_amdgcn_exp2f(x);   // v_exp_f32 (2^x)
#else
  return __expf(x * 0.69314718056f);
#endif
}

__device__ __forceinline__ f16x4 pack4(float p0, float p1, float p2, float p3) {
#if __has_builtin(__builtin_amdgcn_cvt_pkrtz)
  f16x2 a = __builtin_bit_cast(f16x2, __builtin_amdgcn_cvt_pkrtz(p0, p1));
  f16x2 b = __builtin_bit_cast(f16x2, __builtin_amdgcn_cvt_pkrtz(p2, p3));
  return __builtin_shufflevector(a, b, 0, 1, 2, 3);
#else
  f16x4 r; r[0] = (f16)p0; r[1] = (f16)p1; r[2] = (f16)p2; r[3] = (f16)p3;
  return r;
#endif
}

// ---------------- dw conv + BN bodies (called from fused preprocess) ----------------
__device__ __forceinline__ void dw_s1_body(
    int blk, int tid, const float* __restrict__ in, const float* __restrict__ w,
    const float* __restrict__ bns, const float* __restrict__ bnb,
    const float* __restrict__ bnm, const float* __restrict__ bnv,
    f16* __restrict__ out) {
  int idx = blk * 256 + tid;                     // < (NTOK/2)*96 = 1204224
  int pp = idx / 96;
  int c = (idx % 96) * 4;
  int b = pp / (HH * WK);
  int rem = pp % (HH * WK);
  int y = rem / WK, xh = rem % WK;
  int x0 = xh * 2;
  float a0x = 0, a0y = 0, a0z = 0, a0w = 0;
  float a1x = 0, a1y = 0, a1z = 0, a1w = 0;
#pragma unroll
  for (int kh = 0; kh < 3; ++kh) {
    int iy = y + kh - 1;
    if ((unsigned)iy >= (unsigned)HH) continue;
    const float* rp = in + ((size_t)(b * HH + iy) * WW) * CC + c;
    const float4 z4 = {0.f, 0.f, 0.f, 0.f};
    const float4 v0 = (x0 > 0) ? *(const float4*)(rp + (size_t)(x0 - 1) * CC) : z4;
    const float4 v1 = *(const float4*)(rp + (size_t)x0 * CC);
    const float4 v2 = *(const float4*)(rp + (size_t)(x0 + 1) * CC);
    const float4 v3 = (x0 < 54) ? *(const float4*)(rp + (size_t)(x0 + 2) * CC) : z4;
    const float4 w0 = *(const float4*)(w + (kh * 3 + 0) * CC + c);
    const float4 w1 = *(const float4*)(w + (kh * 3 + 1) * CC + c);
    const float4 w2 = *(const float4*)(w + (kh * 3 + 2) * CC + c);
    a0x = fmaf(v0.x, w0.x, fmaf(v1.x, w1.x, fmaf(v2.x, w2.x, a0x)));
    a0y = fmaf(v0.y, w0.y, fmaf(v1.y, w1.y, fmaf(v2.y, w2.y, a0y)));
    a0z = fmaf(v0.z, w0.z, fmaf(v1.z, w1.z, fmaf(v2.z, w2.z, a0z)));
    a0w = fmaf(v0.w, w0.w, fmaf(v1.w, w1.w, fmaf(v2.w, w2.w, a0w)));
    a1x = fmaf(v1.x, w0.x, fmaf(v2.x, w1.x, fmaf(v3.x, w2.x, a1x)));
    a1y = fmaf(v1.y, w0.y, fmaf(v2.y, w1.y, fmaf(v3.y, w2.y, a1y)));
    a1z = fmaf(v1.z, w0.z, fmaf(v2.z, w1.z, fmaf(v3.z, w2.z, a1z)));
    a1w = fmaf(v1.w, w0.w, fmaf(v2.w, w1.w, fmaf(v3.w, w2.w, a1w)));
  }
  const float4 s = *(const float4*)(bns + c);
  const float4 bi = *(const float4*)(bnb + c);
  const float4 m = *(const float4*)(bnm + c);
  const float4 va = *(const float4*)(bnv + c);
  f16x4 r0, r1;
  float g;
  g = s.x * rsqrtf(va.x + BN_EPS); r0[0] = (f16)fmaf(a0x - m.x, g, bi.x); r1[0] = (f16)fmaf(a1x - m.x, g, bi.x);
  g = s.y * rsqrtf(va.y + BN_EPS); r0[1] = (f16)fmaf(a0y - m.y, g, bi.y); r1[1] = (f16)fmaf(a1y - m.y, g, bi.y);
  g = s.z * rsqrtf(va.z + BN_EPS); r0[2] = (f16)fmaf(a0z - m.z, g, bi.z); r1[2] = (f16)fmaf(a1z - m.z, g, bi.z);
  g = s.w * rsqrtf(va.w + BN_EPS); r0[3] = (f16)fmaf(a0w - m.w, g, bi.w); r1[3] = (f16)fmaf(a1w - m.w, g, bi.w);
  const size_t pix0 = (size_t)b * NQ + y * WW + x0;
  *(f16x4*)(out + pix0 * CC + c) = r0;
  *(f16x4*)(out + (pix0 + 1) * CC + c) = r1;
}

__device__ __forceinline__ void dw_s2_body(
    int blk, int tid, const float* __restrict__ in,
    const float* __restrict__ wk_, const float* __restrict__ kbs, const float* __restrict__ kbb,
    const float* __restrict__ kbm, const float* __restrict__ kbv,
    const float* __restrict__ wv_, const float* __restrict__ vbs, const float* __restrict__ vbb,
    const float* __restrict__ vbm, const float* __restrict__ vbv,
    f16* __restrict__ outk, f16* __restrict__ outv) {
  int idx = blk * 256 + tid;                     // < NTOKKV*96
  int pix = idx / 96;
  int c = (idx % 96) * 4;
  int b = pix / (HK * WK);
  int p = pix % (HK * WK);
  int oy = p / WK, ox = p % WK;
  float kx = 0, ky = 0, kz = 0, kw4 = 0;
  float vx = 0, vy = 0, vz = 0, vw4 = 0;
#pragma unroll
  for (int kh = 0; kh < 3; ++kh) {
    int iy = oy * 2 + kh;
    if (iy >= HH) continue;
#pragma unroll
    for (int kwi = 0; kwi < 3; ++kwi) {
      int ix = ox * 2 + kwi;
      if (ix >= WW) continue;
      const float4 v = *(const float4*)(in + (((size_t)(b * HH + iy) * WW + ix) * CC + c));
      const float4 a = *(const float4*)(wk_ + ((kh * 3 + kwi) * CC + c));
      const float4 bq = *(const float4*)(wv_ + ((kh * 3 + kwi) * CC + c));
      kx = fmaf(v.x, a.x, kx); ky = fmaf(v.y, a.y, ky);
      kz = fmaf(v.z, a.z, kz); kw4 = fmaf(v.w, a.w, kw4);
      vx = fmaf(v.x, bq.x, vx); vy = fmaf(v.y, bq.y, vy);
      vz = fmaf(v.z, bq.z, vz); vw4 = fmaf(v.w, bq.w, vw4);
    }
  }
  {
    const float4 s = *(const float4*)(kbs + c);
    const float4 bi = *(const float4*)(kbb + c);
    const float4 m = *(const float4*)(kbm + c);
    const float4 va = *(const float4*)(kbv + c);
    f16x4 r; float g;
    g = s.x * rsqrtf(va.x + BN_EPS); r[0] = (f16)fmaf(kx - m.x, g, bi.x);
    g = s.y * rsqrtf(va.y + BN_EPS); r[1] = (f16)fmaf(ky - m.y, g, bi.y);
    g = s.z * rsqrtf(va.z + BN_EPS); r[2] = (f16)fmaf(kz - m.z, g, bi.z);
    g = s.w * rsqrtf(va.w + BN_EPS); r[3] = (f16)fmaf(kw4 - m.w, g, bi.w);
    *(f16x4*)(outk + (size_t)pix * CC + c) = r;
  }
  {
    const float4 s = *(const float4*)(vbs + c);
    const float4 bi = *(const float4*)(vbb + c);
    const float4 m = *(const float4*)(vbm + c);
    const float4 va = *(const float4*)(vbv + c);
    f16x4 r; float g;
    g = s.x * rsqrtf(va.x + BN_EPS); r[0] = (f16)fmaf(vx - m.x, g, bi.x);
    g = s.y * rsqrtf(va.y + BN_EPS); r[1] = (f16)fmaf(vy - m.y, g, bi.y);
    g = s.z * rsqrtf(va.z + BN_EPS); r[2] = (f16)fmaf(vz - m.z, g, bi.z);
    g = s.w * rsqrtf(va.w + BN_EPS); r[3] = (f16)fmaf(vw4 - m.w, g, bi.w);
    *(f16x4*)(outv + (size_t)pix * CC + c) = r;
  }
}

// ---- fused preprocess: dw_s1 (4704 blocks) + dw_s2_kv (2352) + convert_w (576) ----
__global__ __launch_bounds__(256) void preprocess(
    const float* __restrict__ inputs_q, const float* __restrict__ inputs_kv,
    const float* __restrict__ q_dwk, const float* __restrict__ q_bs,
    const float* __restrict__ q_bb, const float* __restrict__ q_bm,
    const float* __restrict__ q_bv,
    const float* __restrict__ k_dwk, const float* __restrict__ k_bs,
    const float* __restrict__ k_bb, const float* __restrict__ k_bm,
    const float* __restrict__ k_bv,
    const float* __restrict__ v_dwk, const float* __restrict__ v_bs,
    const float* __restrict__ v_bb, const float* __restrict__ v_bm,
    const float* __restrict__ v_bv,
    const float* __restrict__ w0, const float* __restrict__ w1,
    const float* __restrict__ w2, const float* __restrict__ w3,
    f16* __restrict__ o0, f16* __restrict__ o1,
    f16* __restrict__ o2, f16* __restrict__ o3,
    f16* __restrict__ qdw, f16* __restrict__ kdw, f16* __restrict__ vdw) {
  __shared__ float t[32][33];
  const int blk = blockIdx.x;
  const int tid = threadIdx.x;
  if (blk < 4704) {
    dw_s1_body(blk, tid, inputs_q, q_dwk, q_bs, q_bb, q_bm, q_bv, qdw);
  } else if (blk < 7056) {
    dw_s2_body(blk - 4704, tid, inputs_kv,
               k_dwk, k_bs, k_bb, k_bm, k_bv,
               v_dwk, v_bs, v_bb, v_bm, v_bv, kdw, vdw);
  } else {
    const int r = blk - 7056;                 // 0..575  (12 x 12 x 4)
    const int z = r / 144, rem = r % 144;
    const int bx = rem % 12, by = rem / 12;
    const float* src = z == 0 ? w0 : z == 1 ? w1 : z == 2 ? w2 : w3;
    f16* dst = z == 0 ? o0 : z == 1 ? o1 : z == 2 ? o2 : o3;
    const int k0 = bx * 32, n0 = by * 32;
    const int x = tid & 31, y = tid >> 5;
#pragma unroll
    for (int i = 0; i < 4; ++i) t[y + i * 8][x] = src[(size_t)(k0 + y + i * 8) * 384 + n0 + x];
    __syncthreads();
#pragma unroll
    for (int i = 0; i < 4; ++i)
      dst[(size_t)(n0 + y + i * 8) * 384 + k0 + x] = (f16)t[x][y + i * 8];
  }
}

// ------------- f16 MFMA GEMM body (128x128 tile, BK=64, 4 waves, 4x4 frags) -------------
// MODE 0: fp32 row-major; MODE 1: f16 row-major; MODE 2: f16 V^T (vtp [b*384+d][784])
// LDS rows (128B) chunk-swizzled: 16B chunk ch stored at ch^(row&7); staged via
// linear global_load_lds dest + inverse-swizzled per-lane SOURCE (rule 21).
template <int MODE>
__device__ __forceinline__ void gemm_body(
    const f16* __restrict__ A, const f16* __restrict__ Bt,
    float* __restrict__ Cf, f16* __restrict__ Ch, float scale,
    int row0, int col0) {
  __shared__ f16 As[128 * 64];   // [row][k], 128 B per row
  __shared__ f16 Bs[128 * 64];   // [col][k], 128 B per col
  const int tid = threadIdx.x;
  const int wave = tid >> 6, lane = tid & 63;
  const int c = lane & 15, g = lane >> 4;
  const int wr = wave >> 1, wc = wave & 1;     // 2x2 waves, each 64x64

  // staging: slot s = row*8 + stored_chunk; call j covers slots j*256 + wave*64 + lane
  const int s_base = wave * 64 + lane;
  f32x4 acc[4][4] = {};

  for (int k0 = 0; k0 < 384; k0 += 64) {
    __syncthreads();
#pragma unroll
    for (int j = 0; j < 4; ++j) {
      const int s = j * 256 + s_base;
      const int row = s >> 3, sch = s & 7;
      const int lch = sch ^ (row & 7);         // logical k-chunk fetched
      const f16* sa = A + (size_t)(row0 + row) * 384 + k0 + lch * 8;
      __builtin_amdgcn_global_load_lds(
          (const __attribute__((address_space(1))) void*)sa,
          (__attribute__((address_space(3))) void*)(As + j * 2048 + wave * 512), 16, 0, 0);
      const f16* sb = Bt + (size_t)(col0 + row) * 384 + k0 + lch * 8;
      __builtin_amdgcn_global_load_lds(
          (const __attribute__((address_space(1))) void*)sb,
          (__attribute__((address_space(3))) void*)(Bs + j * 2048 + wave * 512), 16, 0, 0);
    }
    __syncthreads();

#pragma unroll
    for (int kh = 0; kh < 2; ++kh) {
      f16x8 bf[4];
#pragma unroll
      for (int n = 0; n < 4; ++n) {
        const int row = wc * 64 + n * 16 + c;
        bf[n] = *(const f16x8*)(Bs + (size_t)row * 64 + ((kh * 4 + g) ^ (row & 7)) * 8);
      }
#pragma unroll
      for (int m = 0; m < 4; ++m) {
        const int row = wr * 64 + m * 16 + c;
        f16x8 af = *(const f16x8*)(As + (size_t)row * 64 + ((kh * 4 + g) ^ (row & 7)) * 8);
#pragma unroll
        for (int n = 0; n < 4; ++n)
          acc[m][n] = __builtin_amdgcn_mfma_f32_16x16x32_f16(af, bf[n], acc[m][n], 0, 0, 0);
      }
    }
  }

  if (MODE == 2) {
    // transposed V store: acc[m][n][r] = V[token = row0+wr*64+m*16+g*4+r][d = col0+wc*64+n*16+c]
#pragma unroll
    for (int m = 0; m < 4; ++m)
#pragma unroll
      for (int n = 0; n < 4; ++n) {
        const int gr = row0 + wr * 64 + m * 16 + g * 4;
        const int col = col0 + wc * 64 + n * 16 + c;
        const int bb = gr / NKV;
        const int kv = gr - bb * NKV;           // 4-pack cannot cross batch (784%4==0, gr%4==0)
        f16x4 pk;
#pragma unroll
        for (int r = 0; r < 4; ++r) pk[r] = (f16)(acc[m][n][r] * scale);
        *(f16x4*)(Ch + ((size_t)bb * 384 + col) * NKV + kv) = pk;
      }
  } else {
#pragma unroll
    for (int m = 0; m < 4; ++m)
#pragma unroll
      for (int n = 0; n < 4; ++n)
#pragma unroll
        for (int r = 0; r < 4; ++r) {
          const size_t row = row0 + wr * 64 + m * 16 + g * 4 + r;
          const size_t col = col0 + wc * 64 + n * 16 + c;
          if (MODE == 1) Ch[row * 384 + col] = (f16)(acc[m][n][r] * scale);
          else           Cf[row * 384 + col] = acc[m][n][r] * scale;
        }
  }
}

// fused q/k/v pointwise GEMMs: 882 flat blocks = q(196x3) + k(49x3) + v(49x3)
__global__ __launch_bounds__(256) void gemm_qkv(
    const f16* __restrict__ qdw, const f16* __restrict__ wqt, f16* __restrict__ qf, float qscale,
    const f16* __restrict__ kdw, const f16* __restrict__ wkt, f16* __restrict__ kf,
    const f16* __restrict__ vdw, const f16* __restrict__ wvt, f16* __restrict__ vtp) {
  const int blk = blockIdx.x;
  if (blk < 588) {
    gemm_body<1>(qdw, wqt, nullptr, qf, qscale, (blk % 196) * 128, (blk / 196) * 128);
  } else if (blk < 735) {
    const int r = blk - 588;
    gemm_body<1>(kdw, wkt, nullptr, kf, 1.0f, (r % 49) * 128, (r / 49) * 128);
  } else {
    const int r = blk - 735;
    gemm_body<2>(vdw, wvt, nullptr, vtp, 1.0f, (r % 49) * 128, (r / 49) * 128);
  }
}

template <int MODE>
__global__ __launch_bounds__(256) void gemm_mfma(
    const f16* __restrict__ A, const f16* __restrict__ Bt,
    float* __restrict__ Cf, f16* __restrict__ Ch, float scale) {
  gemm_body<MODE>(A, Bt, Cf, Ch, scale, blockIdx.x * 128, blockIdx.y * 128);
}

// ------------- f16 MFMA flash attention, swapped-QK^T, QBLK=64 (R10 structure + setprio) -------------
// grid = B*NH*49; block 256 (4 waves x 16 q rows). KVT=64.
// Q pre-scaled by 0.125*log2(e); softmax = native exp2.
// S^T = mfma(A=K, B=Q): lane (c,g) holds S[kv = t0+ct*16+g*4+r][q = c].
// lsum via MFMA ones-trick (row layout q=g*4+r, same as O).
__global__ __launch_bounds__(256) void attn_mfma(
    const f16* __restrict__ qp, const f16* __restrict__ kp,
    const f16* __restrict__ vt, f16* __restrict__ op) {
  __shared__ f16 Ks[64 * 64];      // [kv][d], chunk ch at ch^(kv&7)
  __shared__ f16 Vs[64 * 64];      // [d][kv], chunk ch at ch^(d&7)
  __shared__ f16 Ps[4][16 * 64];   // per-wave [q][kv], ch^(q&7)
  const int bid = blockIdx.x;
  const int qt = bid % 49;
  const int bh = bid / 49;
  const int h = bh % NHD, b = bh / NHD;
  const int tid = threadIdx.x;
  const int wave = tid >> 6, lane = tid & 63;
  const int c = lane & 15, g = lane >> 4;

  const size_t qrow = (size_t)b * NQ + qt * 64 + wave * 16 + c;
  f16x8 qa[2];
  qa[0] = *(const f16x8*)(qp + qrow * 384 + h * 64 + g * 8);
  qa[1] = *(const f16x8*)(qp + qrow * 384 + h * 64 + 32 + g * 8);

  f16x8 vones;
#pragma unroll
  for (int j = 0; j < 8; ++j) vones[j] = (f16)1.0f;

  const int tid8 = tid >> 3, tch = tid & 7;
  const int lch = tch ^ (tid8 & 7);            // logical chunk fetched

  const f16* kbase = kp + ((size_t)b * NKV) * 384 + h * 64;
  const f16* vbase = vt + ((size_t)(b * 384 + h * 64)) * NKV;

  float mrun = -1e30f;                // for q = c (redundant across g)
  f32x4 o[4] = {};                    // O[q=g*4+r][d=dt*16+c]
  f32x4 osum = {};                    // lsum[q=g*4+r]
  f16* prow = &Ps[wave][0];

  for (int t0 = 0; t0 < NKV; t0 += 64) {
    __syncthreads();
    {
      int kv0 = t0 + tid8; if (kv0 > NKV - 1) kv0 = NKV - 1;
      int kv1 = t0 + 32 + tid8; if (kv1 > NKV - 1) kv1 = NKV - 1;
      __builtin_amdgcn_global_load_lds(
          (const __attribute__((address_space(1))) void*)(kbase + (size_t)kv0 * 384 + lch * 8),
          (__attribute__((address_space(3))) void*)(Ks + wave * 512), 16, 0, 0);
      __builtin_amdgcn_global_load_lds(
          (const __attribute__((address_space(1))) void*)(kbase + (size_t)kv1 * 384 + lch * 8),
          (__attribute__((address_space(3))) void*)(Ks + 2048 + wave * 512), 16, 0, 0);
      int col = t0 + lch * 8; if (col > NKV - 8) col = NKV - 8;
      __builtin_amdgcn_global_load_lds(
          (const __attribute__((address_space(1))) void*)(vbase + (size_t)tid8 * NKV + col),
          (__attribute__((address_space(3))) void*)(Vs + wave * 512), 16, 0, 0);
      __builtin_amdgcn_global_load_lds(
          (const __attribute__((address_space(1))) void*)(vbase + (size_t)(32 + tid8) * NKV + col),
          (__attribute__((address_space(3))) void*)(Vs + 2048 + wave * 512), 16, 0, 0);
    }
    __syncthreads();

    // S^T tiles: s[ct] = K[t0+ct*16..+16) . Q^T, accumulated over kh
    f32x4 s[4] = {};
    __builtin_amdgcn_s_setprio(1);
#pragma unroll
    for (int kh = 0; kh < 2; ++kh) {
#pragma unroll
      for (int ct = 0; ct < 4; ++ct) {
        const int row = ct * 16 + c;
        const int sch = (kh * 4 + g) ^ (row & 7);
        f16x8 kb = *(const f16x8*)(Ks + row * 64 + sch * 8);
        s[ct] = __builtin_amdgcn_mfma_f32_16x16x32_f16(kb, qa[kh], s[ct], 0, 0, 0);
      }
    }
    __builtin_amdgcn_s_setprio(0);
    // tail mask
    if (t0 + 64 > NKV) {
#pragma unroll
      for (int ct = 0; ct < 4; ++ct)
#pragma unroll
        for (int r = 0; r < 4; ++r)
          if (t0 + ct * 16 + g * 4 + r >= NKV) s[ct][r] = -1e30f;
    }

    // tile max for q=c
    float mt = s[0][0];
#pragma unroll
    for (int ct = 0; ct < 4; ++ct)
#pragma unroll
      for (int r = 0; r < 4; ++r) mt = fmaxf(mt, s[ct][r]);
    mt = fmaxf(mt, __shfl_xor(mt, 16));
    mt = fmaxf(mt, __shfl_xor(mt, 32));

    // defer-max (log2 units; P bounded by 2^8)
    if (__ballot(mt > mrun + 8.0f)) {
      const float mnew = fmaxf(mrun, mt);
      const float corr = fast_exp2(mrun - mnew);
      mrun = mnew;
#pragma unroll
      for (int r = 0; r < 4; ++r) {
        const float co = __shfl(corr, g * 4 + r);
#pragma unroll
        for (int dt = 0; dt < 4; ++dt) o[dt][r] *= co;
        osum[r] *= co;
      }
    }

    // P = exp2(S - mrun); pack f16 (pkrtz), store to per-wave LDS
#pragma unroll
    for (int ct = 0; ct < 4; ++ct) {
      const float p0 = fast_exp2(s[ct][0] - mrun);
      const float p1 = fast_exp2(s[ct][1] - mrun);
      const float p2 = fast_exp2(s[ct][2] - mrun);
      const float p3 = fast_exp2(s[ct][3] - mrun);
      const int sch = (ct * 2 + (g >> 1)) ^ (c & 7);
      *(f16x4*)(prow + c * 64 + sch * 8 + (g & 1) * 4) = pack4(p0, p1, p2, p3);
    }

    // PV + lsum: o[dt] += P * V; osum += P * 1 (two k-slices of 32)
    __builtin_amdgcn_s_setprio(1);
#pragma unroll
    for (int ks = 0; ks < 2; ++ks) {
      const int sp = (ks * 4 + g) ^ (c & 7);
      f16x8 pa = *(const f16x8*)(prow + c * 64 + sp * 8);
#pragma unroll
      for (int dt = 0; dt < 4; ++dt) {
        const int d = dt * 16 + c;
        f16x8 vb = *(const f16x8*)(Vs + d * 64 + sp * 8);  // (ks*4+g)^(d&7) == sp
        o[dt] = __builtin_amdgcn_mfma_f32_16x16x32_f16(pa, vb, o[dt], 0, 0, 0);
      }
      osum = __builtin_amdgcn_mfma_f32_16x16x32_f16(pa, vones, osum, 0, 0, 0);
    }
    __builtin_amdgcn_s_setprio(0);
  }

  // epilogue: osum already in q=g*4+r row layout -> no shuffles
  f16* obase = op + ((size_t)(b * NQ + qt * 64 + wave * 16)) * 384 + h * 64;
#pragma unroll
  for (int r = 0; r < 4; ++r) {
    const float iv = 1.0f / osum[r];
#pragma unroll
    for (int dt = 0; dt < 4; ++dt)
      obase[(size_t)(g * 4 + r) * 384 + dt * 16 + c] = (f16)(o[dt][r] * iv);
  }
}

extern "C" void kernel_launch(void* const* d_in, const int* in_sizes, int n_in,
                              void* d_out, int out_size, void* d_ws, size_t ws_size,
                              hipStream_t stream) {
  const float* inputs_q  = (const float*)d_in[0];
  const float* inputs_kv = (const float*)d_in[1];
  const float* out_kern  = (const float*)d_in[2];
  const float* q_dwk = (const float*)d_in[3];
  const float* q_bs  = (const float*)d_in[4];
  const float* q_bb  = (const float*)d_in[5];
  const float* q_bm  = (const float*)d_in[6];
  const float* q_bv  = (const float*)d_in[7];
  const float* q_pwk = (const float*)d_in[8];
  const float* k_dwk = (const float*)d_in[9];
  const float* k_bs  = (const float*)d_in[10];
  const float* k_bb  = (const float*)d_in[11];
  const float* k_bm  = (const float*)d_in[12];
  const float* k_bv  = (const float*)d_in[13];
  const float* k_pwk = (const float*)d_in[14];
  const float* v_dwk = (const float*)d_in[15];
  const float* v_bs  = (const float*)d_in[16];
  const float* v_bb  = (const float*)d_in[17];
  const float* v_bm  = (const float*)d_in[18];
  const float* v_bv  = (const float*)d_in[19];
  const float* v_pwk = (const float*)d_in[20];

  char* wsb = (char*)d_ws;
  f16* qdw = (f16*)(wsb + 0);             // 25088*384 f16
  f16* kdw = (f16*)(wsb + 19267584);      // 6272*384 f16
  f16* vdw = (f16*)(wsb + 24084480);      // 6272*384 f16
  f16* qf  = (f16*)(wsb + 28901376);      // 25088*384 f16
  f16* kf  = (f16*)(wsb + 48168960);      // 6272*384 f16
  f16* vtp = (f16*)(wsb + 57802752);      // 8*384*784 f16
  f16* of  = (f16*)(wsb + 62619648);      // 25088*384 f16
  f16* wqt = (f16*)(wsb + 81887232);      // 384*384 f16 x4
  f16* wkt = (f16*)(wsb + 82182144);
  f16* wvt = (f16*)(wsb + 82477056);
  f16* wot = (f16*)(wsb + 82771968);

  // 1. fused preprocess: dw+BN (q, k&v) + weight transpose-convert
  preprocess<<<7632, 256, 0, stream>>>(
      inputs_q, inputs_kv,
      q_dwk, q_bs, q_bb, q_bm, q_bv,
      k_dwk, k_bs, k_bb, k_bm, k_bv,
      v_dwk, v_bs, v_bb, v_bm, v_bv,
      q_pwk, k_pwk, v_pwk, out_kern, wqt, wkt, wvt, wot,
      qdw, kdw, vdw);
  // 2. fused q/k/v pointwise GEMMs (V written transposed; q folded with 1/8*log2e)
  gemm_qkv<<<882, 256, 0, stream>>>(qdw, wqt, qf, 0.125f * LOG2E,
                                    kdw, wkt, kf, vdw, wvt, vtp);
  // 3. MFMA attention (QBLK=64, setprio) -> f16 O
  attn_mfma<<<BB * NHD * 49, 256, 0, stream>>>(qf, kf, vtp, of);
  // 4. output projection (MFMA, fp32 out)
  gemm_mfma<0><<<dim3(196, 3), 256, 0, stream>>>(of, wot, (float*)d_out, nullptr, 1.0f);
}

// Round 13
// 153.642 us; speedup vs baseline: 1.3284x; 1.0007x over previous
//
#include <hip/hip_runtime.h>
#include <hip/hip_bf16.h>
#include <hip/hip_fp16.h>

// Problem constants
#define BB 8
#define HH 56
#define WW 56
#define CC 384
#define NHD 6
#define DD 64
#define HK 28
#define WK 28
#define NQ (HH*WW)       // 3136
#define NKV (HK*WK)      // 784
#define NTOK (BB*NQ)     // 25088
#define NTOKKV (BB*NKV)  // 6272
#define BN_EPS 1e-5f
#define LOG2E 1.44269504f

typedef _Float16 f16;
typedef _Float16 f16x2 __attribute__((ext_vector_type(2)));
typedef _Float16 f16x4 __attribute__((ext_vector_type(4)));
typedef _Float16 f16x8 __attribute__((ext_vector_type(8)));
typedef float f32x4 __attribute__((ext_vector_type(4)));

__device__ __forceinline__ float fast_exp2(float x) {
#if __has_builtin(__builtin_amdgcn_exp2f)
  return __builtin_amdgcn_exp2f(x);   // v_exp_f32 (2^x)
#else
  return __expf(x * 0.69314718056f);
#endif
}

__device__ __forceinline__ f16x4 pack4(float p0, float p1, float p2, float p3) {
#if __has_builtin(__builtin_amdgcn_cvt_pkrtz)
  f16x2 a = __builtin_bit_cast(f16x2, __builtin_amdgcn_cvt_pkrtz(p0, p1));
  f16x2 b = __builtin_bit_cast(f16x2, __builtin_amdgcn_cvt_pkrtz(p2, p3));
  return __builtin_shufflevector(a, b, 0, 1, 2, 3);
#else
  f16x4 r; r[0] = (f16)p0; r[1] = (f16)p1; r[2] = (f16)p2; r[3] = (f16)p3;
  return r;
#endif
}

// ---------------- dw conv + BN bodies (called from fused preprocess) ----------------
__device__ __forceinline__ void dw_s1_body(
    int blk, int tid, const float* __restrict__ in, const float* __restrict__ w,
    const float* __restrict__ bns, const float* __restrict__ bnb,
    const float* __restrict__ bnm, const float* __restrict__ bnv,
    f16* __restrict__ out) {
  int idx = blk * 256 + tid;                     // < (NTOK/2)*96 = 1204224
  int pp = idx / 96;
  int c = (idx % 96) * 4;
  int b = pp / (HH * WK);
  int rem = pp % (HH * WK);
  int y = rem / WK, xh = rem % WK;
  int x0 = xh * 2;
  float a0x = 0, a0y = 0, a0z = 0, a0w = 0;
  float a1x = 0, a1y = 0, a1z = 0, a1w = 0;
#pragma unroll
  for (int kh = 0; kh < 3; ++kh) {
    int iy = y + kh - 1;
    if ((unsigned)iy >= (unsigned)HH) continue;
    const float* rp = in + ((size_t)(b * HH + iy) * WW) * CC + c;
    const float4 z4 = {0.f, 0.f, 0.f, 0.f};
    const float4 v0 = (x0 > 0) ? *(const float4*)(rp + (size_t)(x0 - 1) * CC) : z4;
    const float4 v1 = *(const float4*)(rp + (size_t)x0 * CC);
    const float4 v2 = *(const float4*)(rp + (size_t)(x0 + 1) * CC);
    const float4 v3 = (x0 < 54) ? *(const float4*)(rp + (size_t)(x0 + 2) * CC) : z4;
    const float4 w0 = *(const float4*)(w + (kh * 3 + 0) * CC + c);
    const float4 w1 = *(const float4*)(w + (kh * 3 + 1) * CC + c);
    const float4 w2 = *(const float4*)(w + (kh * 3 + 2) * CC + c);
    a0x = fmaf(v0.x, w0.x, fmaf(v1.x, w1.x, fmaf(v2.x, w2.x, a0x)));
    a0y = fmaf(v0.y, w0.y, fmaf(v1.y, w1.y, fmaf(v2.y, w2.y, a0y)));
    a0z = fmaf(v0.z, w0.z, fmaf(v1.z, w1.z, fmaf(v2.z, w2.z, a0z)));
    a0w = fmaf(v0.w, w0.w, fmaf(v1.w, w1.w, fmaf(v2.w, w2.w, a0w)));
    a1x = fmaf(v1.x, w0.x, fmaf(v2.x, w1.x, fmaf(v3.x, w2.x, a1x)));
    a1y = fmaf(v1.y, w0.y, fmaf(v2.y, w1.y, fmaf(v3.y, w2.y, a1y)));
    a1z = fmaf(v1.z, w0.z, fmaf(v2.z, w1.z, fmaf(v3.z, w2.z, a1z)));
    a1w = fmaf(v1.w, w0.w, fmaf(v2.w, w1.w, fmaf(v3.w, w2.w, a1w)));
  }
  const float4 s = *(const float4*)(bns + c);
  const float4 bi = *(const float4*)(bnb + c);
  const float4 m = *(const float4*)(bnm + c);
  const float4 va = *(const float4*)(bnv + c);
  f16x4 r0, r1;
  float g;
  g = s.x * rsqrtf(va.x + BN_EPS); r0[0] = (f16)fmaf(a0x - m.x, g, bi.x); r1[0] = (f16)fmaf(a1x - m.x, g, bi.x);
  g = s.y * rsqrtf(va.y + BN_EPS); r0[1] = (f16)fmaf(a0y - m.y, g, bi.y); r1[1] = (f16)fmaf(a1y - m.y, g, bi.y);
  g = s.z * rsqrtf(va.z + BN_EPS); r0[2] = (f16)fmaf(a0z - m.z, g, bi.z); r1[2] = (f16)fmaf(a1z - m.z, g, bi.z);
  g = s.w * rsqrtf(va.w + BN_EPS); r0[3] = (f16)fmaf(a0w - m.w, g, bi.w); r1[3] = (f16)fmaf(a1w - m.w, g, bi.w);
  const size_t pix0 = (size_t)b * NQ + y * WW + x0;
  *(f16x4*)(out + pix0 * CC + c) = r0;
  *(f16x4*)(out + (pix0 + 1) * CC + c) = r1;
}

__device__ __forceinline__ void dw_s2_body(
    int blk, int tid, const float* __restrict__ in,
    const float* __restrict__ wk_, const float* __restrict__ kbs, const float* __restrict__ kbb,
    const float* __restrict__ kbm, const float* __restrict__ kbv,
    const float* __restrict__ wv_, const float* __restrict__ vbs, const float* __restrict__ vbb,
    const float* __restrict__ vbm, const float* __restrict__ vbv,
    f16* __restrict__ outk, f16* __restrict__ outv) {
  int idx = blk * 256 + tid;                     // < NTOKKV*96
  int pix = idx / 96;
  int c = (idx % 96) * 4;
  int b = pix / (HK * WK);
  int p = pix % (HK * WK);
  int oy = p / WK, ox = p % WK;
  float kx = 0, ky = 0, kz = 0, kw4 = 0;
  float vx = 0, vy = 0, vz = 0, vw4 = 0;
#pragma unroll
  for (int kh = 0; kh < 3; ++kh) {
    int iy = oy * 2 + kh;
    if (iy >= HH) continue;
#pragma unroll
    for (int kwi = 0; kwi < 3; ++kwi) {
      int ix = ox * 2 + kwi;
      if (ix >= WW) continue;
      const float4 v = *(const float4*)(in + (((size_t)(b * HH + iy) * WW + ix) * CC + c));
      const float4 a = *(const float4*)(wk_ + ((kh * 3 + kwi) * CC + c));
      const float4 bq = *(const float4*)(wv_ + ((kh * 3 + kwi) * CC + c));
      kx = fmaf(v.x, a.x, kx); ky = fmaf(v.y, a.y, ky);
      kz = fmaf(v.z, a.z, kz); kw4 = fmaf(v.w, a.w, kw4);
      vx = fmaf(v.x, bq.x, vx); vy = fmaf(v.y, bq.y, vy);
      vz = fmaf(v.z, bq.z, vz); vw4 = fmaf(v.w, bq.w, vw4);
    }
  }
  {
    const float4 s = *(const float4*)(kbs + c);
    const float4 bi = *(const float4*)(kbb + c);
    const float4 m = *(const float4*)(kbm + c);
    const float4 va = *(const float4*)(kbv + c);
    f16x4 r; float g;
    g = s.x * rsqrtf(va.x + BN_EPS); r[0] = (f16)fmaf(kx - m.x, g, bi.x);
    g = s.y * rsqrtf(va.y + BN_EPS); r[1] = (f16)fmaf(ky - m.y, g, bi.y);
    g = s.z * rsqrtf(va.z + BN_EPS); r[2] = (f16)fmaf(kz - m.z, g, bi.z);
    g = s.w * rsqrtf(va.w + BN_EPS); r[3] = (f16)fmaf(kw4 - m.w, g, bi.w);
    *(f16x4*)(outk + (size_t)pix * CC + c) = r;
  }
  {
    const float4 s = *(const float4*)(vbs + c);
    const float4 bi = *(const float4*)(vbb + c);
    const float4 m = *(const float4*)(vbm + c);
    const float4 va = *(const float4*)(vbv + c);
    f16x4 r; float g;
    g = s.x * rsqrtf(va.x + BN_EPS); r[0] = (f16)fmaf(vx - m.x, g, bi.x);
    g = s.y * rsqrtf(va.y + BN_EPS); r[1] = (f16)fmaf(vy - m.y, g, bi.y);
    g = s.z * rsqrtf(va.z + BN_EPS); r[2] = (f16)fmaf(vz - m.z, g, bi.z);
    g = s.w * rsqrtf(va.w + BN_EPS); r[3] = (f16)fmaf(vw4 - m.w, g, bi.w);
    *(f16x4*)(outv + (size_t)pix * CC + c) = r;
  }
}

// ---- fused preprocess: dw_s1 (4704 blocks) + dw_s2_kv (2352) + convert_w (576) ----
__global__ __launch_bounds__(256) void preprocess(
    const float* __restrict__ inputs_q, const float* __restrict__ inputs_kv,
    const float* __restrict__ q_dwk, const float* __restrict__ q_bs,
    const float* __restrict__ q_bb, const float* __restrict__ q_bm,
    const float* __restrict__ q_bv,
    const float* __restrict__ k_dwk, const float* __restrict__ k_bs,
    const float* __restrict__ k_bb, const float* __restrict__ k_bm,
    const float* __restrict__ k_bv,
    const float* __restrict__ v_dwk, const float* __restrict__ v_bs,
    const float* __restrict__ v_bb, const float* __restrict__ v_bm,
    const float* __restrict__ v_bv,
    const float* __restrict__ w0, const float* __restrict__ w1,
    const float* __restrict__ w2, const float* __restrict__ w3,
    f16* __restrict__ o0, f16* __restrict__ o1,
    f16* __restrict__ o2, f16* __restrict__ o3,
    f16* __restrict__ qdw, f16* __restrict__ kdw, f16* __restrict__ vdw) {
  __shared__ float t[32][33];
  const int blk = blockIdx.x;
  const int tid = threadIdx.x;
  if (blk < 4704) {
    dw_s1_body(blk, tid, inputs_q, q_dwk, q_bs, q_bb, q_bm, q_bv, qdw);
  } else if (blk < 7056) {
    dw_s2_body(blk - 4704, tid, inputs_kv,
               k_dwk, k_bs, k_bb, k_bm, k_bv,
               v_dwk, v_bs, v_bb, v_bm, v_bv, kdw, vdw);
  } else {
    const int r = blk - 7056;                 // 0..575  (12 x 12 x 4)
    const int z = r / 144, rem = r % 144;
    const int bx = rem % 12, by = rem / 12;
    const float* src = z == 0 ? w0 : z == 1 ? w1 : z == 2 ? w2 : w3;
    f16* dst = z == 0 ? o0 : z == 1 ? o1 : z == 2 ? o2 : o3;
    const int k0 = bx * 32, n0 = by * 32;
    const int x = tid & 31, y = tid >> 5;
#pragma unroll
    for (int i = 0; i < 4; ++i) t[y + i * 8][x] = src[(size_t)(k0 + y + i * 8) * 384 + n0 + x];
    __syncthreads();
#pragma unroll
    for (int i = 0; i < 4; ++i)
      dst[(size_t)(n0 + y + i * 8) * 384 + k0 + x] = (f16)t[x][y + i * 8];
  }
}

// ------------- f16 MFMA GEMM body (128x128 tile, BK=64, 4 waves, 4x4 frags) -------------
// MODE 0: fp32 row-major; MODE 1: f16 row-major; MODE 2: f16 V^T (vtp [b*384+d][784])
template <int MODE>
__device__ __forceinline__ void gemm_body(
    const f16* __restrict__ A, const f16* __restrict__ Bt,
    float* __restrict__ Cf, f16* __restrict__ Ch, float scale,
    int row0, int col0) {
  __shared__ f16 As[128 * 64];   // [row][k], 128 B per row
  __shared__ f16 Bs[128 * 64];   // [col][k], 128 B per col
  const int tid = threadIdx.x;
  const int wave = tid >> 6, lane = tid & 63;
  const int c = lane & 15, g = lane >> 4;
  const int wr = wave >> 1, wc = wave & 1;     // 2x2 waves, each 64x64

  const int s_base = wave * 64 + lane;
  f32x4 acc[4][4] = {};

  for (int k0 = 0; k0 < 384; k0 += 64) {
    __syncthreads();
#pragma unroll
    for (int j = 0; j < 4; ++j) {
      const int s = j * 256 + s_base;
      const int row = s >> 3, sch = s & 7;
      const int lch = sch ^ (row & 7);         // logical k-chunk fetched
      const f16* sa = A + (size_t)(row0 + row) * 384 + k0 + lch * 8;
      __builtin_amdgcn_global_load_lds(
          (const __attribute__((address_space(1))) void*)sa,
          (__attribute__((address_space(3))) void*)(As + j * 2048 + wave * 512), 16, 0, 0);
      const f16* sb = Bt + (size_t)(col0 + row) * 384 + k0 + lch * 8;
      __builtin_amdgcn_global_load_lds(
          (const __attribute__((address_space(1))) void*)sb,
          (__attribute__((address_space(3))) void*)(Bs + j * 2048 + wave * 512), 16, 0, 0);
    }
    __syncthreads();

#pragma unroll
    for (int kh = 0; kh < 2; ++kh) {
      f16x8 bf[4];
#pragma unroll
      for (int n = 0; n < 4; ++n) {
        const int row = wc * 64 + n * 16 + c;
        bf[n] = *(const f16x8*)(Bs + (size_t)row * 64 + ((kh * 4 + g) ^ (row & 7)) * 8);
      }
#pragma unroll
      for (int m = 0; m < 4; ++m) {
        const int row = wr * 64 + m * 16 + c;
        f16x8 af = *(const f16x8*)(As + (size_t)row * 64 + ((kh * 4 + g) ^ (row & 7)) * 8);
#pragma unroll
        for (int n = 0; n < 4; ++n)
          acc[m][n] = __builtin_amdgcn_mfma_f32_16x16x32_f16(af, bf[n], acc[m][n], 0, 0, 0);
      }
    }
  }

  if (MODE == 2) {
#pragma unroll
    for (int m = 0; m < 4; ++m)
#pragma unroll
      for (int n = 0; n < 4; ++n) {
        const int gr = row0 + wr * 64 + m * 16 + g * 4;
        const int col = col0 + wc * 64 + n * 16 + c;
        const int bb = gr / NKV;
        const int kv = gr - bb * NKV;           // 4-pack cannot cross batch (784%4==0, gr%4==0)
        f16x4 pk;
#pragma unroll
        for (int r = 0; r < 4; ++r) pk[r] = (f16)(acc[m][n][r] * scale);
        *(f16x4*)(Ch + ((size_t)bb * 384 + col) * NKV + kv) = pk;
      }
  } else {
#pragma unroll
    for (int m = 0; m < 4; ++m)
#pragma unroll
      for (int n = 0; n < 4; ++n)
#pragma unroll
        for (int r = 0; r < 4; ++r) {
          const size_t row = row0 + wr * 64 + m * 16 + g * 4 + r;
          const size_t col = col0 + wc * 64 + n * 16 + c;
          if (MODE == 1) Ch[row * 384 + col] = (f16)(acc[m][n][r] * scale);
          else           Cf[row * 384 + col] = acc[m][n][r] * scale;
        }
  }
}

// fused q/k/v pointwise GEMMs: 882 flat blocks = q(196x3) + k(49x3) + v(49x3)
__global__ __launch_bounds__(256) void gemm_qkv(
    const f16* __restrict__ qdw, const f16* __restrict__ wqt, f16* __restrict__ qf, float qscale,
    const f16* __restrict__ kdw, const f16* __restrict__ wkt, f16* __restrict__ kf,
    const f16* __restrict__ vdw, const f16* __restrict__ wvt, f16* __restrict__ vtp) {
  const int blk = blockIdx.x;
  if (blk < 588) {
    gemm_body<1>(qdw, wqt, nullptr, qf, qscale, (blk % 196) * 128, (blk / 196) * 128);
  } else if (blk < 735) {
    const int r = blk - 588;
    gemm_body<1>(kdw, wkt, nullptr, kf, 1.0f, (r % 49) * 128, (r / 49) * 128);
  } else {
    const int r = blk - 735;
    gemm_body<2>(vdw, wvt, nullptr, vtp, 1.0f, (r % 49) * 128, (r / 49) * 128);
  }
}

template <int MODE>
__global__ __launch_bounds__(256) void gemm_mfma(
    const f16* __restrict__ A, const f16* __restrict__ Bt,
    float* __restrict__ Cf, f16* __restrict__ Ch, float scale) {
  gemm_body<MODE>(A, Bt, Cf, Ch, scale, blockIdx.x * 128, blockIdx.y * 128);
}

// ------------- f16 MFMA flash attention, swapped-QK^T, KVSTEP=128, XCD-chunked -------------
// grid = 2352 (8 XCD chunks x 294); lb = (bid&7)*294 + (bid>>3): each XCD owns
// exactly 6 complete (b,h) pairs (K/V 1.2MB << 4MB L2) -> no cross-XCD K/V duplication.
// block 256 (4 waves x 16 q rows). Stage 128 KV rows per barrier pair; compute as
// two wave-local 64-halves (no inner barrier). lsum via MFMA ones-trick.
#define KVSTEP 128
__global__ __launch_bounds__(256) void attn_mfma(
    const f16* __restrict__ qp, const f16* __restrict__ kp,
    const f16* __restrict__ vt, f16* __restrict__ op) {
  __shared__ f16 Ks[KVSTEP * 64];  // [kv][d], 128B rows, chunk ch at ch^(kv&7)
  __shared__ f16 Vs[64 * KVSTEP];  // [d][kv], 256B rows, chunk ch at ch^(d&15)
  __shared__ f16 Ps[4][16 * 64];   // per-wave [q][kv-local], ch^(q&7)
  const int bid0 = blockIdx.x;
  const int lb = (bid0 & 7) * 294 + (bid0 >> 3);   // bijective (2352 = 8*294)
  const int qt = lb % 49;
  const int bh = lb / 49;
  const int h = bh % NHD, b = bh / NHD;
  const int tid = threadIdx.x;
  const int wave = tid >> 6, lane = tid & 63;
  const int c = lane & 15, g = lane >> 4;

  const size_t qrow = (size_t)b * NQ + qt * 64 + wave * 16 + c;
  f16x8 qa[2];
  qa[0] = *(const f16x8*)(qp + qrow * 384 + h * 64 + g * 8);
  qa[1] = *(const f16x8*)(qp + qrow * 384 + h * 64 + 32 + g * 8);

  f16x8 vones;
#pragma unroll
  for (int j = 0; j < 8; ++j) vones[j] = (f16)1.0f;

  const f16* kbase = kp + ((size_t)b * NKV) * 384 + h * 64;
  const f16* vbase = vt + ((size_t)(b * 384 + h * 64)) * NKV;

  float mrun = -1e30f;                // for q = c (redundant across g)
  f32x4 o[4] = {};                    // O[q=g*4+r][d=dt*16+c]
  f32x4 osum = {};                    // lsum[q=g*4+r]
  f16* prow = &Ps[wave][0];

  for (int st = 0; st < 7; ++st) {
    const int t0 = st * KVSTEP;
    __syncthreads();
    {
#pragma unroll
      for (int j = 0; j < 4; ++j) {
        // K: slot s = kv*8 + stored_chunk
        const int sk = j * 256 + tid;
        const int kvr = sk >> 3, skc = sk & 7;
        int krow = t0 + kvr; if (krow > NKV - 1) krow = NKV - 1;
        __builtin_amdgcn_global_load_lds(
            (const __attribute__((address_space(1))) void*)(kbase + (size_t)krow * 384 + ((skc ^ (kvr & 7)) * 8)),
            (__attribute__((address_space(3))) void*)(Ks + j * 2048 + wave * 512), 16, 0, 0);
        // V: slot s = d*16 + stored_chunk
        const int dr = sk >> 4, svc = sk & 15;
        int col = t0 + (svc ^ (dr & 15)) * 8; if (col > NKV - 8) col = NKV - 8;
        __builtin_amdgcn_global_load_lds(
            (const __attribute__((address_space(1))) void*)(vbase + (size_t)dr * NKV + col),
            (__attribute__((address_space(3))) void*)(Vs + j * 2048 + wave * 512), 16, 0, 0);
      }
    }
    __syncthreads();

#pragma unroll
    for (int half = 0; half < 2; ++half) {
      const int tt = t0 + half * 64;
      if (tt >= NKV) continue;              // uniform skip (st=6 half=1)

      // S^T tiles: s[ct] = K[tt+ct*16..+16) . Q^T
      f32x4 s[4] = {};
      __builtin_amdgcn_s_setprio(1);
#pragma unroll
      for (int kh = 0; kh < 2; ++kh) {
#pragma unroll
        for (int ct = 0; ct < 4; ++ct) {
          const int row = half * 64 + ct * 16 + c;
          const int sch = (kh * 4 + g) ^ (row & 7);
          f16x8 kb = *(const f16x8*)(Ks + row * 64 + sch * 8);
          s[ct] = __builtin_amdgcn_mfma_f32_16x16x32_f16(kb, qa[kh], s[ct], 0, 0, 0);
        }
      }
      __builtin_amdgcn_s_setprio(0);
      // tail mask
      if (tt + 64 > NKV) {
#pragma unroll
        for (int ct = 0; ct < 4; ++ct)
#pragma unroll
          for (int r = 0; r < 4; ++r)
            if (tt + ct * 16 + g * 4 + r >= NKV) s[ct][r] = -1e30f;
      }

      // tile max for q=c
      float mt = s[0][0];
#pragma unroll
      for (int ct = 0; ct < 4; ++ct)
#pragma unroll
        for (int r = 0; r < 4; ++r) mt = fmaxf(mt, s[ct][r]);
      mt = fmaxf(mt, __shfl_xor(mt, 16));
      mt = fmaxf(mt, __shfl_xor(mt, 32));

      // defer-max (log2 units; P bounded by 2^8)
      if (__ballot(mt > mrun + 8.0f)) {
        const float mnew = fmaxf(mrun, mt);
        const float corr = fast_exp2(mrun - mnew);
        mrun = mnew;
#pragma unroll
        for (int r = 0; r < 4; ++r) {
          const float co = __shfl(corr, g * 4 + r);
#pragma unroll
          for (int dt = 0; dt < 4; ++dt) o[dt][r] *= co;
          osum[r] *= co;
        }
      }

      // P = exp2(S - mrun); pack f16 (pkrtz), store to per-wave LDS
#pragma unroll
      for (int ct = 0; ct < 4; ++ct) {
        const float p0 = fast_exp2(s[ct][0] - mrun);
        const float p1 = fast_exp2(s[ct][1] - mrun);
        const float p2 = fast_exp2(s[ct][2] - mrun);
        const float p3 = fast_exp2(s[ct][3] - mrun);
        const int sch = (ct * 2 + (g >> 1)) ^ (c & 7);
        *(f16x4*)(prow + c * 64 + sch * 8 + (g & 1) * 4) = pack4(p0, p1, p2, p3);
      }

      // PV + lsum: o[dt] += P * V; osum += P * 1 (two k-slices of 32)
      __builtin_amdgcn_s_setprio(1);
#pragma unroll
      for (int ks = 0; ks < 2; ++ks) {
        const int sp = (ks * 4 + g) ^ (c & 7);
        f16x8 pa = *(const f16x8*)(prow + c * 64 + sp * 8);
#pragma unroll
        for (int dt = 0; dt < 4; ++dt) {
          const int d = dt * 16 + c;
          const int cidx = (half * 8 + ks * 4 + g) ^ (d & 15);   // d&15 == c
          f16x8 vb = *(const f16x8*)(Vs + (size_t)d * KVSTEP + cidx * 8);
          o[dt] = __builtin_amdgcn_mfma_f32_16x16x32_f16(pa, vb, o[dt], 0, 0, 0);
        }
        osum = __builtin_amdgcn_mfma_f32_16x16x32_f16(pa, vones, osum, 0, 0, 0);
      }
      __builtin_amdgcn_s_setprio(0);
    }
  }

  // epilogue: osum already in q=g*4+r row layout -> no shuffles
  f16* obase = op + ((size_t)(b * NQ + qt * 64 + wave * 16)) * 384 + h * 64;
#pragma unroll
  for (int r = 0; r < 4; ++r) {
    const float iv = 1.0f / osum[r];
#pragma unroll
    for (int dt = 0; dt < 4; ++dt)
      obase[(size_t)(g * 4 + r) * 384 + dt * 16 + c] = (f16)(o[dt][r] * iv);
  }
}

extern "C" void kernel_launch(void* const* d_in, const int* in_sizes, int n_in,
                              void* d_out, int out_size, void* d_ws, size_t ws_size,
                              hipStream_t stream) {
  const float* inputs_q  = (const float*)d_in[0];
  const float* inputs_kv = (const float*)d_in[1];
  const float* out_kern  = (const float*)d_in[2];
  const float* q_dwk = (const float*)d_in[3];
  const float* q_bs  = (const float*)d_in[4];
  const float* q_bb  = (const float*)d_in[5];
  const float* q_bm  = (const float*)d_in[6];
  const float* q_bv  = (const float*)d_in[7];
  const float* q_pwk = (const float*)d_in[8];
  const float* k_dwk = (const float*)d_in[9];
  const float* k_bs  = (const float*)d_in[10];
  const float* k_bb  = (const float*)d_in[11];
  const float* k_bm  = (const float*)d_in[12];
  const float* k_bv  = (const float*)d_in[13];
  const float* k_pwk = (const float*)d_in[14];
  const float* v_dwk = (const float*)d_in[15];
  const float* v_bs  = (const float*)d_in[16];
  const float* v_bb  = (const float*)d_in[17];
  const float* v_bm  = (const float*)d_in[18];
  const float* v_bv  = (const float*)d_in[19];
  const float* v_pwk = (const float*)d_in[20];

  char* wsb = (char*)d_ws;
  f16* qdw = (f16*)(wsb + 0);             // 25088*384 f16
  f16* kdw = (f16*)(wsb + 19267584);      // 6272*384 f16
  f16* vdw = (f16*)(wsb + 24084480);      // 6272*384 f16
  f16* qf  = (f16*)(wsb + 28901376);      // 25088*384 f16
  f16* kf  = (f16*)(wsb + 48168960);      // 6272*384 f16
  f16* vtp = (f16*)(wsb + 57802752);      // 8*384*784 f16
  f16* of  = (f16*)(wsb + 62619648);      // 25088*384 f16
  f16* wqt = (f16*)(wsb + 81887232);      // 384*384 f16 x4
  f16* wkt = (f16*)(wsb + 82182144);
  f16* wvt = (f16*)(wsb + 82477056);
  f16* wot = (f16*)(wsb + 82771968);

  // 1. fused preprocess: dw+BN (q, k&v) + weight transpose-convert
  preprocess<<<7632, 256, 0, stream>>>(
      inputs_q, inputs_kv,
      q_dwk, q_bs, q_bb, q_bm, q_bv,
      k_dwk, k_bs, k_bb, k_bm, k_bv,
      v_dwk, v_bs, v_bb, v_bm, v_bv,
      q_pwk, k_pwk, v_pwk, out_kern, wqt, wkt, wvt, wot,
      qdw, kdw, vdw);
  // 2. fused q/k/v pointwise GEMMs (V written transposed; q folded with 1/8*log2e)
  gemm_qkv<<<882, 256, 0, stream>>>(qdw, wqt, qf, 0.125f * LOG2E,
                                    kdw, wkt, kf, vdw, wvt, vtp);
  // 3. MFMA attention (KVSTEP=128, XCD-chunked) -> f16 O
  attn_mfma<<<BB * NHD * 49, 256, 0, stream>>>(qf, kf, vtp, of);
  // 4. output projection (MFMA, fp32 out)
  gemm_mfma<0><<<dim3(196, 3), 256, 0, stream>>>(of, wot, (float*)d_out, nullptr, 1.0f);
}

// Round 14
// 150.962 us; speedup vs baseline: 1.3520x; 1.0178x over previous
//
#include <hip/hip_runtime.h>
#include <hip/hip_bf16.h>
#include <hip/hip_fp16.h>

// Problem constants
#define BB 8
#define HH 56
#define WW 56
#define CC 384
#define NHD 6
#define DD 64
#define HK 28
#define WK 28
#define NQ (HH*WW)       // 3136
#define NKV (HK*WK)      // 784
#define NTOK (BB*NQ)     // 25088
#define NTOKKV (BB*NKV)  // 6272
#define BN_EPS 1e-5f
#define LOG2E 1.44269504f

typedef _Float16 f16;
typedef _Float16 f16x2 __attribute__((ext_vector_type(2)));
typedef _Float16 f16x4 __attribute__((ext_vector_type(4)));
typedef _Float16 f16x8 __attribute__((ext_vector_type(8)));
typedef float f32x4 __attribute__((ext_vector_type(4)));

__device__ __forceinline__ float fast_exp2(float x) {
#if __has_builtin(__builtin_amdgcn_exp2f)
  return __builtin_amdgcn_exp2f(x);   // v_exp_f32 (2^x)
#else
  return __expf(x * 0.69314718056f);
#endif
}

__device__ __forceinline__ f16x4 pack4(float p0, float p1, float p2, float p3) {
#if __has_builtin(__builtin_amdgcn_cvt_pkrtz)
  f16x2 a = __builtin_bit_cast(f16x2, __builtin_amdgcn_cvt_pkrtz(p0, p1));
  f16x2 b = __builtin_bit_cast(f16x2, __builtin_amdgcn_cvt_pkrtz(p2, p3));
  return __builtin_shufflevector(a, b, 0, 1, 2, 3);
#else
  f16x4 r; r[0] = (f16)p0; r[1] = (f16)p1; r[2] = (f16)p2; r[3] = (f16)p3;
  return r;
#endif
}

// ---------------- dw conv + BN bodies (called from fused preprocess) ----------------
__device__ __forceinline__ void dw_s1_body(
    int blk, int tid, const float* __restrict__ in, const float* __restrict__ w,
    const float* __restrict__ bns, const float* __restrict__ bnb,
    const float* __restrict__ bnm, const float* __restrict__ bnv,
    f16* __restrict__ out) {
  int idx = blk * 256 + tid;                     // < (NTOK/2)*96 = 1204224
  int pp = idx / 96;
  int c = (idx % 96) * 4;
  int b = pp / (HH * WK);
  int rem = pp % (HH * WK);
  int y = rem / WK, xh = rem % WK;
  int x0 = xh * 2;
  float a0x = 0, a0y = 0, a0z = 0, a0w = 0;
  float a1x = 0, a1y = 0, a1z = 0, a1w = 0;
#pragma unroll
  for (int kh = 0; kh < 3; ++kh) {
    int iy = y + kh - 1;
    if ((unsigned)iy >= (unsigned)HH) continue;
    const float* rp = in + ((size_t)(b * HH + iy) * WW) * CC + c;
    const float4 z4 = {0.f, 0.f, 0.f, 0.f};
    const float4 v0 = (x0 > 0) ? *(const float4*)(rp + (size_t)(x0 - 1) * CC) : z4;
    const float4 v1 = *(const float4*)(rp + (size_t)x0 * CC);
    const float4 v2 = *(const float4*)(rp + (size_t)(x0 + 1) * CC);
    const float4 v3 = (x0 < 54) ? *(const float4*)(rp + (size_t)(x0 + 2) * CC) : z4;
    const float4 w0 = *(const float4*)(w + (kh * 3 + 0) * CC + c);
    const float4 w1 = *(const float4*)(w + (kh * 3 + 1) * CC + c);
    const float4 w2 = *(const float4*)(w + (kh * 3 + 2) * CC + c);
    a0x = fmaf(v0.x, w0.x, fmaf(v1.x, w1.x, fmaf(v2.x, w2.x, a0x)));
    a0y = fmaf(v0.y, w0.y, fmaf(v1.y, w1.y, fmaf(v2.y, w2.y, a0y)));
    a0z = fmaf(v0.z, w0.z, fmaf(v1.z, w1.z, fmaf(v2.z, w2.z, a0z)));
    a0w = fmaf(v0.w, w0.w, fmaf(v1.w, w1.w, fmaf(v2.w, w2.w, a0w)));
    a1x = fmaf(v1.x, w0.x, fmaf(v2.x, w1.x, fmaf(v3.x, w2.x, a1x)));
    a1y = fmaf(v1.y, w0.y, fmaf(v2.y, w1.y, fmaf(v3.y, w2.y, a1y)));
    a1z = fmaf(v1.z, w0.z, fmaf(v2.z, w1.z, fmaf(v3.z, w2.z, a1z)));
    a1w = fmaf(v1.w, w0.w, fmaf(v2.w, w1.w, fmaf(v3.w, w2.w, a1w)));
  }
  const float4 s = *(const float4*)(bns + c);
  const float4 bi = *(const float4*)(bnb + c);
  const float4 m = *(const float4*)(bnm + c);
  const float4 va = *(const float4*)(bnv + c);
  f16x4 r0, r1;
  float g;
  g = s.x * rsqrtf(va.x + BN_EPS); r0[0] = (f16)fmaf(a0x - m.x, g, bi.x); r1[0] = (f16)fmaf(a1x - m.x, g, bi.x);
  g = s.y * rsqrtf(va.y + BN_EPS); r0[1] = (f16)fmaf(a0y - m.y, g, bi.y); r1[1] = (f16)fmaf(a1y - m.y, g, bi.y);
  g = s.z * rsqrtf(va.z + BN_EPS); r0[2] = (f16)fmaf(a0z - m.z, g, bi.z); r1[2] = (f16)fmaf(a1z - m.z, g, bi.z);
  g = s.w * rsqrtf(va.w + BN_EPS); r0[3] = (f16)fmaf(a0w - m.w, g, bi.w); r1[3] = (f16)fmaf(a1w - m.w, g, bi.w);
  const size_t pix0 = (size_t)b * NQ + y * WW + x0;
  *(f16x4*)(out + pix0 * CC + c) = r0;
  *(f16x4*)(out + (pix0 + 1) * CC + c) = r1;
}

__device__ __forceinline__ void dw_s2_body(
    int blk, int tid, const float* __restrict__ in,
    const float* __restrict__ wk_, const float* __restrict__ kbs, const float* __restrict__ kbb,
    const float* __restrict__ kbm, const float* __restrict__ kbv,
    const float* __restrict__ wv_, const float* __restrict__ vbs, const float* __restrict__ vbb,
    const float* __restrict__ vbm, const float* __restrict__ vbv,
    f16* __restrict__ outk, f16* __restrict__ outv) {
  int idx = blk * 256 + tid;                     // < NTOKKV*96
  int pix = idx / 96;
  int c = (idx % 96) * 4;
  int b = pix / (HK * WK);
  int p = pix % (HK * WK);
  int oy = p / WK, ox = p % WK;
  float kx = 0, ky = 0, kz = 0, kw4 = 0;
  float vx = 0, vy = 0, vz = 0, vw4 = 0;
#pragma unroll
  for (int kh = 0; kh < 3; ++kh) {
    int iy = oy * 2 + kh;
    if (iy >= HH) continue;
#pragma unroll
    for (int kwi = 0; kwi < 3; ++kwi) {
      int ix = ox * 2 + kwi;
      if (ix >= WW) continue;
      const float4 v = *(const float4*)(in + (((size_t)(b * HH + iy) * WW + ix) * CC + c));
      const float4 a = *(const float4*)(wk_ + ((kh * 3 + kwi) * CC + c));
      const float4 bq = *(const float4*)(wv_ + ((kh * 3 + kwi) * CC + c));
      kx = fmaf(v.x, a.x, kx); ky = fmaf(v.y, a.y, ky);
      kz = fmaf(v.z, a.z, kz); kw4 = fmaf(v.w, a.w, kw4);
      vx = fmaf(v.x, bq.x, vx); vy = fmaf(v.y, bq.y, vy);
      vz = fmaf(v.z, bq.z, vz); vw4 = fmaf(v.w, bq.w, vw4);
    }
  }
  {
    const float4 s = *(const float4*)(kbs + c);
    const float4 bi = *(const float4*)(kbb + c);
    const float4 m = *(const float4*)(kbm + c);
    const float4 va = *(const float4*)(kbv + c);
    f16x4 r; float g;
    g = s.x * rsqrtf(va.x + BN_EPS); r[0] = (f16)fmaf(kx - m.x, g, bi.x);
    g = s.y * rsqrtf(va.y + BN_EPS); r[1] = (f16)fmaf(ky - m.y, g, bi.y);
    g = s.z * rsqrtf(va.z + BN_EPS); r[2] = (f16)fmaf(kz - m.z, g, bi.z);
    g = s.w * rsqrtf(va.w + BN_EPS); r[3] = (f16)fmaf(kw4 - m.w, g, bi.w);
    *(f16x4*)(outk + (size_t)pix * CC + c) = r;
  }
  {
    const float4 s = *(const float4*)(vbs + c);
    const float4 bi = *(const float4*)(vbb + c);
    const float4 m = *(const float4*)(vbm + c);
    const float4 va = *(const float4*)(vbv + c);
    f16x4 r; float g;
    g = s.x * rsqrtf(va.x + BN_EPS); r[0] = (f16)fmaf(vx - m.x, g, bi.x);
    g = s.y * rsqrtf(va.y + BN_EPS); r[1] = (f16)fmaf(vy - m.y, g, bi.y);
    g = s.z * rsqrtf(va.z + BN_EPS); r[2] = (f16)fmaf(vz - m.z, g, bi.z);
    g = s.w * rsqrtf(va.w + BN_EPS); r[3] = (f16)fmaf(vw4 - m.w, g, bi.w);
    *(f16x4*)(outv + (size_t)pix * CC + c) = r;
  }
}

// ---- fused preprocess: dw_s1 (4704 blocks) + dw_s2_kv (2352) + convert_w (576) ----
__global__ __launch_bounds__(256) void preprocess(
    const float* __restrict__ inputs_q, const float* __restrict__ inputs_kv,
    const float* __restrict__ q_dwk, const float* __restrict__ q_bs,
    const float* __restrict__ q_bb, const float* __restrict__ q_bm,
    const float* __restrict__ q_bv,
    const float* __restrict__ k_dwk, const float* __restrict__ k_bs,
    const float* __restrict__ k_bb, const float* __restrict__ k_bm,
    const float* __restrict__ k_bv,
    const float* __restrict__ v_dwk, const float* __restrict__ v_bs,
    const float* __restrict__ v_bb, const float* __restrict__ v_bm,
    const float* __restrict__ v_bv,
    const float* __restrict__ w0, const float* __restrict__ w1,
    const float* __restrict__ w2, const float* __restrict__ w3,
    f16* __restrict__ o0, f16* __restrict__ o1,
    f16* __restrict__ o2, f16* __restrict__ o3,
    f16* __restrict__ qdw, f16* __restrict__ kdw, f16* __restrict__ vdw) {
  __shared__ float t[32][33];
  const int blk = blockIdx.x;
  const int tid = threadIdx.x;
  if (blk < 4704) {
    dw_s1_body(blk, tid, inputs_q, q_dwk, q_bs, q_bb, q_bm, q_bv, qdw);
  } else if (blk < 7056) {
    dw_s2_body(blk - 4704, tid, inputs_kv,
               k_dwk, k_bs, k_bb, k_bm, k_bv,
               v_dwk, v_bs, v_bb, v_bm, v_bv, kdw, vdw);
  } else {
    const int r = blk - 7056;                 // 0..575  (12 x 12 x 4)
    const int z = r / 144, rem = r % 144;
    const int bx = rem % 12, by = rem / 12;
    const float* src = z == 0 ? w0 : z == 1 ? w1 : z == 2 ? w2 : w3;
    f16* dst = z == 0 ? o0 : z == 1 ? o1 : z == 2 ? o2 : o3;
    const int k0 = bx * 32, n0 = by * 32;
    const int x = tid & 31, y = tid >> 5;
#pragma unroll
    for (int i = 0; i < 4; ++i) t[y + i * 8][x] = src[(size_t)(k0 + y + i * 8) * 384 + n0 + x];
    __syncthreads();
#pragma unroll
    for (int i = 0; i < 4; ++i)
      dst[(size_t)(n0 + y + i * 8) * 384 + k0 + x] = (f16)t[x][y + i * 8];
  }
}

// ------------- f16 MFMA GEMM body (128x128 tile, BK=64, 4 waves, 4x4 frags) -------------
// MODE 0: fp32 row-major; MODE 1: f16 row-major; MODE 2: f16 V^T (vtp [b*384+d][784])
template <int MODE>
__device__ __forceinline__ void gemm_body(
    const f16* __restrict__ A, const f16* __restrict__ Bt,
    float* __restrict__ Cf, f16* __restrict__ Ch, float scale,
    int row0, int col0) {
  __shared__ f16 As[128 * 64];   // [row][k], 128 B per row
  __shared__ f16 Bs[128 * 64];   // [col][k], 128 B per col
  const int tid = threadIdx.x;
  const int wave = tid >> 6, lane = tid & 63;
  const int c = lane & 15, g = lane >> 4;
  const int wr = wave >> 1, wc = wave & 1;     // 2x2 waves, each 64x64

  const int s_base = wave * 64 + lane;
  f32x4 acc[4][4] = {};

  for (int k0 = 0; k0 < 384; k0 += 64) {
    __syncthreads();
#pragma unroll
    for (int j = 0; j < 4; ++j) {
      const int s = j * 256 + s_base;
      const int row = s >> 3, sch = s & 7;
      const int lch = sch ^ (row & 7);         // logical k-chunk fetched
      const f16* sa = A + (size_t)(row0 + row) * 384 + k0 + lch * 8;
      __builtin_amdgcn_global_load_lds(
          (const __attribute__((address_space(1))) void*)sa,
          (__attribute__((address_space(3))) void*)(As + j * 2048 + wave * 512), 16, 0, 0);
      const f16* sb = Bt + (size_t)(col0 + row) * 384 + k0 + lch * 8;
      __builtin_amdgcn_global_load_lds(
          (const __attribute__((address_space(1))) void*)sb,
          (__attribute__((address_space(3))) void*)(Bs + j * 2048 + wave * 512), 16, 0, 0);
    }
    __syncthreads();

#pragma unroll
    for (int kh = 0; kh < 2; ++kh) {
      f16x8 bf[4];
#pragma unroll
      for (int n = 0; n < 4; ++n) {
        const int row = wc * 64 + n * 16 + c;
        bf[n] = *(const f16x8*)(Bs + (size_t)row * 64 + ((kh * 4 + g) ^ (row & 7)) * 8);
      }
#pragma unroll
      for (int m = 0; m < 4; ++m) {
        const int row = wr * 64 + m * 16 + c;
        f16x8 af = *(const f16x8*)(As + (size_t)row * 64 + ((kh * 4 + g) ^ (row & 7)) * 8);
#pragma unroll
        for (int n = 0; n < 4; ++n)
          acc[m][n] = __builtin_amdgcn_mfma_f32_16x16x32_f16(af, bf[n], acc[m][n], 0, 0, 0);
      }
    }
  }

  if (MODE == 2) {
#pragma unroll
    for (int m = 0; m < 4; ++m)
#pragma unroll
      for (int n = 0; n < 4; ++n) {
        const int gr = row0 + wr * 64 + m * 16 + g * 4;
        const int col = col0 + wc * 64 + n * 16 + c;
        const int bb = gr / NKV;
        const int kv = gr - bb * NKV;           // 4-pack cannot cross batch (784%4==0, gr%4==0)
        f16x4 pk;
#pragma unroll
        for (int r = 0; r < 4; ++r) pk[r] = (f16)(acc[m][n][r] * scale);
        *(f16x4*)(Ch + ((size_t)bb * 384 + col) * NKV + kv) = pk;
      }
  } else {
#pragma unroll
    for (int m = 0; m < 4; ++m)
#pragma unroll
      for (int n = 0; n < 4; ++n)
#pragma unroll
        for (int r = 0; r < 4; ++r) {
          const size_t row = row0 + wr * 64 + m * 16 + g * 4 + r;
          const size_t col = col0 + wc * 64 + n * 16 + c;
          if (MODE == 1) Ch[row * 384 + col] = (f16)(acc[m][n][r] * scale);
          else           Cf[row * 384 + col] = acc[m][n][r] * scale;
        }
  }
}

// fused q/k/v pointwise GEMMs: 882 flat blocks = q(196x3) + k(49x3) + v(49x3)
__global__ __launch_bounds__(256) void gemm_qkv(
    const f16* __restrict__ qdw, const f16* __restrict__ wqt, f16* __restrict__ qf, float qscale,
    const f16* __restrict__ kdw, const f16* __restrict__ wkt, f16* __restrict__ kf,
    const f16* __restrict__ vdw, const f16* __restrict__ wvt, f16* __restrict__ vtp) {
  const int blk = blockIdx.x;
  if (blk < 588) {
    gemm_body<1>(qdw, wqt, nullptr, qf, qscale, (blk % 196) * 128, (blk / 196) * 128);
  } else if (blk < 735) {
    const int r = blk - 588;
    gemm_body<1>(kdw, wkt, nullptr, kf, 1.0f, (r % 49) * 128, (r / 49) * 128);
  } else {
    const int r = blk - 735;
    gemm_body<2>(vdw, wvt, nullptr, vtp, 1.0f, (r % 49) * 128, (r / 49) * 128);
  }
}

template <int MODE>
__global__ __launch_bounds__(256) void gemm_mfma(
    const f16* __restrict__ A, const f16* __restrict__ Bt,
    float* __restrict__ Cf, f16* __restrict__ Ch, float scale) {
  gemm_body<MODE>(A, Bt, Cf, Ch, scale, blockIdx.x * 128, blockIdx.y * 128);
}

// ------------- f16 MFMA flash attention, swapped-QK^T, KVT=64, XCD-chunked -------------
// grid = 2352; lb = (bid&7)*294 + (bid>>3): each XCD owns 6 complete (b,h) pairs
// (K/V 1.2MB << 4MB L2) -> K/V stage loads hit XCD-local L2 (~200cy not ~900cy).
// block 256 (4 waves x 16 q rows). lsum via MFMA ones-trick.
__global__ __launch_bounds__(256) void attn_mfma(
    const f16* __restrict__ qp, const f16* __restrict__ kp,
    const f16* __restrict__ vt, f16* __restrict__ op) {
  __shared__ f16 Ks[64 * 64];      // [kv][d], chunk ch at ch^(kv&7)
  __shared__ f16 Vs[64 * 64];      // [d][kv], chunk ch at ch^(d&7)
  __shared__ f16 Ps[4][16 * 64];   // per-wave [q][kv], ch^(q&7)
  const int bid0 = blockIdx.x;
  const int lb = (bid0 & 7) * 294 + (bid0 >> 3);   // bijective (2352 = 8*294)
  const int qt = lb % 49;
  const int bh = lb / 49;
  const int h = bh % NHD, b = bh / NHD;
  const int tid = threadIdx.x;
  const int wave = tid >> 6, lane = tid & 63;
  const int c = lane & 15, g = lane >> 4;

  const size_t qrow = (size_t)b * NQ + qt * 64 + wave * 16 + c;
  f16x8 qa[2];
  qa[0] = *(const f16x8*)(qp + qrow * 384 + h * 64 + g * 8);
  qa[1] = *(const f16x8*)(qp + qrow * 384 + h * 64 + 32 + g * 8);

  f16x8 vones;
#pragma unroll
  for (int j = 0; j < 8; ++j) vones[j] = (f16)1.0f;

  const int tid8 = tid >> 3, tch = tid & 7;
  const int lch = tch ^ (tid8 & 7);            // logical chunk fetched

  const f16* kbase = kp + ((size_t)b * NKV) * 384 + h * 64;
  const f16* vbase = vt + ((size_t)(b * 384 + h * 64)) * NKV;

  float mrun = -1e30f;                // for q = c (redundant across g)
  f32x4 o[4] = {};                    // O[q=g*4+r][d=dt*16+c]
  f32x4 osum = {};                    // lsum[q=g*4+r]
  f16* prow = &Ps[wave][0];

  for (int t0 = 0; t0 < NKV; t0 += 64) {
    __syncthreads();
    {
      int kv0 = t0 + tid8; if (kv0 > NKV - 1) kv0 = NKV - 1;
      int kv1 = t0 + 32 + tid8; if (kv1 > NKV - 1) kv1 = NKV - 1;
      __builtin_amdgcn_global_load_lds(
          (const __attribute__((address_space(1))) void*)(kbase + (size_t)kv0 * 384 + lch * 8),
          (__attribute__((address_space(3))) void*)(Ks + wave * 512), 16, 0, 0);
      __builtin_amdgcn_global_load_lds(
          (const __attribute__((address_space(1))) void*)(kbase + (size_t)kv1 * 384 + lch * 8),
          (__attribute__((address_space(3))) void*)(Ks + 2048 + wave * 512), 16, 0, 0);
      int col = t0 + lch * 8; if (col > NKV - 8) col = NKV - 8;
      __builtin_amdgcn_global_load_lds(
          (const __attribute__((address_space(1))) void*)(vbase + (size_t)tid8 * NKV + col),
          (__attribute__((address_space(3))) void*)(Vs + wave * 512), 16, 0, 0);
      __builtin_amdgcn_global_load_lds(
          (const __attribute__((address_space(1))) void*)(vbase + (size_t)(32 + tid8) * NKV + col),
          (__attribute__((address_space(3))) void*)(Vs + 2048 + wave * 512), 16, 0, 0);
    }
    __syncthreads();

    // S^T tiles: s[ct] = K[t0+ct*16..+16) . Q^T, accumulated over kh
    f32x4 s[4] = {};
    __builtin_amdgcn_s_setprio(1);
#pragma unroll
    for (int kh = 0; kh < 2; ++kh) {
#pragma unroll
      for (int ct = 0; ct < 4; ++ct) {
        const int row = ct * 16 + c;
        const int sch = (kh * 4 + g) ^ (row & 7);
        f16x8 kb = *(const f16x8*)(Ks + row * 64 + sch * 8);
        s[ct] = __builtin_amdgcn_mfma_f32_16x16x32_f16(kb, qa[kh], s[ct], 0, 0, 0);
      }
    }
    __builtin_amdgcn_s_setprio(0);
    // tail mask
    if (t0 + 64 > NKV) {
#pragma unroll
      for (int ct = 0; ct < 4; ++ct)
#pragma unroll
        for (int r = 0; r < 4; ++r)
          if (t0 + ct * 16 + g * 4 + r >= NKV) s[ct][r] = -1e30f;
    }

    // tile max for q=c
    float mt = s[0][0];
#pragma unroll
    for (int ct = 0; ct < 4; ++ct)
#pragma unroll
      for (int r = 0; r < 4; ++r) mt = fmaxf(mt, s[ct][r]);
    mt = fmaxf(mt, __shfl_xor(mt, 16));
    mt = fmaxf(mt, __shfl_xor(mt, 32));

    // defer-max (log2 units; P bounded by 2^8)
    if (__ballot(mt > mrun + 8.0f)) {
      const float mnew = fmaxf(mrun, mt);
      const float corr = fast_exp2(mrun - mnew);
      mrun = mnew;
#pragma unroll
      for (int r = 0; r < 4; ++r) {
        const float co = __shfl(corr, g * 4 + r);
#pragma unroll
        for (int dt = 0; dt < 4; ++dt) o[dt][r] *= co;
        osum[r] *= co;
      }
    }

    // P = exp2(S - mrun); pack f16 (pkrtz), store to per-wave LDS
#pragma unroll
    for (int ct = 0; ct < 4; ++ct) {
      const float p0 = fast_exp2(s[ct][0] - mrun);
      const float p1 = fast_exp2(s[ct][1] - mrun);
      const float p2 = fast_exp2(s[ct][2] - mrun);
      const float p3 = fast_exp2(s[ct][3] - mrun);
      const int sch = (ct * 2 + (g >> 1)) ^ (c & 7);
      *(f16x4*)(prow + c * 64 + sch * 8 + (g & 1) * 4) = pack4(p0, p1, p2, p3);
    }

    // PV + lsum: o[dt] += P * V; osum += P * 1 (two k-slices of 32)
    __builtin_amdgcn_s_setprio(1);
#pragma unroll
    for (int ks = 0; ks < 2; ++ks) {
      const int sp = (ks * 4 + g) ^ (c & 7);
      f16x8 pa = *(const f16x8*)(prow + c * 64 + sp * 8);
#pragma unroll
      for (int dt = 0; dt < 4; ++dt) {
        const int d = dt * 16 + c;
        f16x8 vb = *(const f16x8*)(Vs + d * 64 + sp * 8);  // (ks*4+g)^(d&7) == sp
        o[dt] = __builtin_amdgcn_mfma_f32_16x16x32_f16(pa, vb, o[dt], 0, 0, 0);
      }
      osum = __builtin_amdgcn_mfma_f32_16x16x32_f16(pa, vones, osum, 0, 0, 0);
    }
    __builtin_amdgcn_s_setprio(0);
  }

  // epilogue: osum already in q=g*4+r row layout -> no shuffles
  f16* obase = op + ((size_t)(b * NQ + qt * 64 + wave * 16)) * 384 + h * 64;
#pragma unroll
  for (int r = 0; r < 4; ++r) {
    const float iv = 1.0f / osum[r];
#pragma unroll
    for (int dt = 0; dt < 4; ++dt)
      obase[(size_t)(g * 4 + r) * 384 + dt * 16 + c] = (f16)(o[dt][r] * iv);
  }
}

extern "C" void kernel_launch(void* const* d_in, const int* in_sizes, int n_in,
                              void* d_out, int out_size, void* d_ws, size_t ws_size,
                              hipStream_t stream) {
  const float* inputs_q  = (const float*)d_in[0];
  const float* inputs_kv = (const float*)d_in[1];
  const float* out_kern  = (const float*)d_in[2];
  const float* q_dwk = (const float*)d_in[3];
  const float* q_bs  = (const float*)d_in[4];
  const float* q_bb  = (const float*)d_in[5];
  const float* q_bm  = (const float*)d_in[6];
  const float* q_bv  = (const float*)d_in[7];
  const float* q_pwk = (const float*)d_in[8];
  const float* k_dwk = (const float*)d_in[9];
  const float* k_bs  = (const float*)d_in[10];
  const float* k_bb  = (const float*)d_in[11];
  const float* k_bm  = (const float*)d_in[12];
  const float* k_bv  = (const float*)d_in[13];
  const float* k_pwk = (const float*)d_in[14];
  const float* v_dwk = (const float*)d_in[15];
  const float* v_bs  = (const float*)d_in[16];
  const float* v_bb  = (const float*)d_in[17];
  const float* v_bm  = (const float*)d_in[18];
  const float* v_bv  = (const float*)d_in[19];
  const float* v_pwk = (const float*)d_in[20];

  char* wsb = (char*)d_ws;
  f16* qdw = (f16*)(wsb + 0);             // 25088*384 f16
  f16* kdw = (f16*)(wsb + 19267584);      // 6272*384 f16
  f16* vdw = (f16*)(wsb + 24084480);      // 6272*384 f16
  f16* qf  = (f16*)(wsb + 28901376);      // 25088*384 f16
  f16* kf  = (f16*)(wsb + 48168960);      // 6272*384 f16
  f16* vtp = (f16*)(wsb + 57802752);      // 8*384*784 f16
  f16* of  = (f16*)(wsb + 62619648);      // 25088*384 f16
  f16* wqt = (f16*)(wsb + 81887232);      // 384*384 f16 x4
  f16* wkt = (f16*)(wsb + 82182144);
  f16* wvt = (f16*)(wsb + 82477056);
  f16* wot = (f16*)(wsb + 82771968);

  // 1. fused preprocess: dw+BN (q, k&v) + weight transpose-convert
  preprocess<<<7632, 256, 0, stream>>>(
      inputs_q, inputs_kv,
      q_dwk, q_bs, q_bb, q_bm, q_bv,
      k_dwk, k_bs, k_bb, k_bm, k_bv,
      v_dwk, v_bs, v_bb, v_bm, v_bv,
      q_pwk, k_pwk, v_pwk, out_kern, wqt, wkt, wvt, wot,
      qdw, kdw, vdw);
  // 2. fused q/k/v pointwise GEMMs (V written transposed; q folded with 1/8*log2e)
  gemm_qkv<<<882, 256, 0, stream>>>(qdw, wqt, qf, 0.125f * LOG2E,
                                    kdw, wkt, kf, vdw, wvt, vtp);
  // 3. MFMA attention (KVT=64, XCD-chunked) -> f16 O
  attn_mfma<<<BB * NHD * 49, 256, 0, stream>>>(qf, kf, vtp, of);
  // 4. output projection (MFMA, fp32 out)
  gemm_mfma<0><<<dim3(196, 3), 256, 0, stream>>>(of, wot, (float*)d_out, nullptr, 1.0f);
}

// Round 15
// 150.192 us; speedup vs baseline: 1.3590x; 1.0051x over previous
//
#include <hip/hip_runtime.h>
#include <hip/hip_bf16.h>
#include <hip/hip_fp16.h>

// Problem constants
#define BB 8
#define HH 56
#define WW 56
#define CC 384
#define NHD 6
#define DD 64
#define HK 28
#define WK 28
#define NQ (HH*WW)       // 3136
#define NKV (HK*WK)      // 784
#define NTOK (BB*NQ)     // 25088
#define NTOKKV (BB*NKV)  // 6272
#define BN_EPS 1e-5f
#define LOG2E 1.44269504f

typedef _Float16 f16;
typedef _Float16 f16x2 __attribute__((ext_vector_type(2)));
typedef _Float16 f16x4 __attribute__((ext_vector_type(4)));
typedef _Float16 f16x8 __attribute__((ext_vector_type(8)));
typedef float f32x4 __attribute__((ext_vector_type(4)));

__device__ __forceinline__ float fast_exp2(float x) {
#if __has_builtin(__builtin_amdgcn_exp2f)
  return __builtin_amdgcn_exp2f(x);   // v_exp_f32 (2^x)
#else
  return __expf(x * 0.69314718056f);
#endif
}

__device__ __forceinline__ f16x4 pack4(float p0, float p1, float p2, float p3) {
#if __has_builtin(__builtin_amdgcn_cvt_pkrtz)
  f16x2 a = __builtin_bit_cast(f16x2, __builtin_amdgcn_cvt_pkrtz(p0, p1));
  f16x2 b = __builtin_bit_cast(f16x2, __builtin_amdgcn_cvt_pkrtz(p2, p3));
  return __builtin_shufflevector(a, b, 0, 1, 2, 3);
#else
  f16x4 r; r[0] = (f16)p0; r[1] = (f16)p1; r[2] = (f16)p2; r[3] = (f16)p3;
  return r;
#endif
}

// ---------------- dw conv + BN bodies (called from fused preprocess) ----------------
__device__ __forceinline__ void dw_s1_body(
    int blk, int tid, const float* __restrict__ in, const float* __restrict__ w,
    const float* __restrict__ bns, const float* __restrict__ bnb,
    const float* __restrict__ bnm, const float* __restrict__ bnv,
    f16* __restrict__ out) {
  int idx = blk * 256 + tid;                     // < (NTOK/2)*96 = 1204224
  int pp = idx / 96;
  int c = (idx % 96) * 4;
  int b = pp / (HH * WK);
  int rem = pp % (HH * WK);
  int y = rem / WK, xh = rem % WK;
  int x0 = xh * 2;
  float a0x = 0, a0y = 0, a0z = 0, a0w = 0;
  float a1x = 0, a1y = 0, a1z = 0, a1w = 0;
#pragma unroll
  for (int kh = 0; kh < 3; ++kh) {
    int iy = y + kh - 1;
    if ((unsigned)iy >= (unsigned)HH) continue;
    const float* rp = in + ((size_t)(b * HH + iy) * WW) * CC + c;
    const float4 z4 = {0.f, 0.f, 0.f, 0.f};
    const float4 v0 = (x0 > 0) ? *(const float4*)(rp + (size_t)(x0 - 1) * CC) : z4;
    const float4 v1 = *(const float4*)(rp + (size_t)x0 * CC);
    const float4 v2 = *(const float4*)(rp + (size_t)(x0 + 1) * CC);
    const float4 v3 = (x0 < 54) ? *(const float4*)(rp + (size_t)(x0 + 2) * CC) : z4;
    const float4 w0 = *(const float4*)(w + (kh * 3 + 0) * CC + c);
    const float4 w1 = *(const float4*)(w + (kh * 3 + 1) * CC + c);
    const float4 w2 = *(const float4*)(w + (kh * 3 + 2) * CC + c);
    a0x = fmaf(v0.x, w0.x, fmaf(v1.x, w1.x, fmaf(v2.x, w2.x, a0x)));
    a0y = fmaf(v0.y, w0.y, fmaf(v1.y, w1.y, fmaf(v2.y, w2.y, a0y)));
    a0z = fmaf(v0.z, w0.z, fmaf(v1.z, w1.z, fmaf(v2.z, w2.z, a0z)));
    a0w = fmaf(v0.w, w0.w, fmaf(v1.w, w1.w, fmaf(v2.w, w2.w, a0w)));
    a1x = fmaf(v1.x, w0.x, fmaf(v2.x, w1.x, fmaf(v3.x, w2.x, a1x)));
    a1y = fmaf(v1.y, w0.y, fmaf(v2.y, w1.y, fmaf(v3.y, w2.y, a1y)));
    a1z = fmaf(v1.z, w0.z, fmaf(v2.z, w1.z, fmaf(v3.z, w2.z, a1z)));
    a1w = fmaf(v1.w, w0.w, fmaf(v2.w, w1.w, fmaf(v3.w, w2.w, a1w)));
  }
  const float4 s = *(const float4*)(bns + c);
  const float4 bi = *(const float4*)(bnb + c);
  const float4 m = *(const float4*)(bnm + c);
  const float4 va = *(const float4*)(bnv + c);
  f16x4 r0, r1;
  float g;
  g = s.x * rsqrtf(va.x + BN_EPS); r0[0] = (f16)fmaf(a0x - m.x, g, bi.x); r1[0] = (f16)fmaf(a1x - m.x, g, bi.x);
  g = s.y * rsqrtf(va.y + BN_EPS); r0[1] = (f16)fmaf(a0y - m.y, g, bi.y); r1[1] = (f16)fmaf(a1y - m.y, g, bi.y);
  g = s.z * rsqrtf(va.z + BN_EPS); r0[2] = (f16)fmaf(a0z - m.z, g, bi.z); r1[2] = (f16)fmaf(a1z - m.z, g, bi.z);
  g = s.w * rsqrtf(va.w + BN_EPS); r0[3] = (f16)fmaf(a0w - m.w, g, bi.w); r1[3] = (f16)fmaf(a1w - m.w, g, bi.w);
  const size_t pix0 = (size_t)b * NQ + y * WW + x0;
  *(f16x4*)(out + pix0 * CC + c) = r0;
  *(f16x4*)(out + (pix0 + 1) * CC + c) = r1;
}

__device__ __forceinline__ void dw_s2_body(
    int blk, int tid, const float* __restrict__ in,
    const float* __restrict__ wk_, const float* __restrict__ kbs, const float* __restrict__ kbb,
    const float* __restrict__ kbm, const float* __restrict__ kbv,
    const float* __restrict__ wv_, const float* __restrict__ vbs, const float* __restrict__ vbb,
    const float* __restrict__ vbm, const float* __restrict__ vbv,
    f16* __restrict__ outk, f16* __restrict__ outv) {
  int idx = blk * 256 + tid;                     // < NTOKKV*96
  int pix = idx / 96;
  int c = (idx % 96) * 4;
  int b = pix / (HK * WK);
  int p = pix % (HK * WK);
  int oy = p / WK, ox = p % WK;
  float kx = 0, ky = 0, kz = 0, kw4 = 0;
  float vx = 0, vy = 0, vz = 0, vw4 = 0;
#pragma unroll
  for (int kh = 0; kh < 3; ++kh) {
    int iy = oy * 2 + kh;
    if (iy >= HH) continue;
#pragma unroll
    for (int kwi = 0; kwi < 3; ++kwi) {
      int ix = ox * 2 + kwi;
      if (ix >= WW) continue;
      const float4 v = *(const float4*)(in + (((size_t)(b * HH + iy) * WW + ix) * CC + c));
      const float4 a = *(const float4*)(wk_ + ((kh * 3 + kwi) * CC + c));
      const float4 bq = *(const float4*)(wv_ + ((kh * 3 + kwi) * CC + c));
      kx = fmaf(v.x, a.x, kx); ky = fmaf(v.y, a.y, ky);
      kz = fmaf(v.z, a.z, kz); kw4 = fmaf(v.w, a.w, kw4);
      vx = fmaf(v.x, bq.x, vx); vy = fmaf(v.y, bq.y, vy);
      vz = fmaf(v.z, bq.z, vz); vw4 = fmaf(v.w, bq.w, vw4);
    }
  }
  {
    const float4 s = *(const float4*)(kbs + c);
    const float4 bi = *(const float4*)(kbb + c);
    const float4 m = *(const float4*)(kbm + c);
    const float4 va = *(const float4*)(kbv + c);
    f16x4 r; float g;
    g = s.x * rsqrtf(va.x + BN_EPS); r[0] = (f16)fmaf(kx - m.x, g, bi.x);
    g = s.y * rsqrtf(va.y + BN_EPS); r[1] = (f16)fmaf(ky - m.y, g, bi.y);
    g = s.z * rsqrtf(va.z + BN_EPS); r[2] = (f16)fmaf(kz - m.z, g, bi.z);
    g = s.w * rsqrtf(va.w + BN_EPS); r[3] = (f16)fmaf(kw4 - m.w, g, bi.w);
    *(f16x4*)(outk + (size_t)pix * CC + c) = r;
  }
  {
    const float4 s = *(const float4*)(vbs + c);
    const float4 bi = *(const float4*)(vbb + c);
    const float4 m = *(const float4*)(vbm + c);
    const float4 va = *(const float4*)(vbv + c);
    f16x4 r; float g;
    g = s.x * rsqrtf(va.x + BN_EPS); r[0] = (f16)fmaf(vx - m.x, g, bi.x);
    g = s.y * rsqrtf(va.y + BN_EPS); r[1] = (f16)fmaf(vy - m.y, g, bi.y);
    g = s.z * rsqrtf(va.z + BN_EPS); r[2] = (f16)fmaf(vz - m.z, g, bi.z);
    g = s.w * rsqrtf(va.w + BN_EPS); r[3] = (f16)fmaf(vw4 - m.w, g, bi.w);
    *(f16x4*)(outv + (size_t)pix * CC + c) = r;
  }
}

// ---- fused preprocess: dw_s1 (4704 blocks) + dw_s2_kv (2352) + convert_w (576) ----
__global__ __launch_bounds__(256) void preprocess(
    const float* __restrict__ inputs_q, const float* __restrict__ inputs_kv,
    const float* __restrict__ q_dwk, const float* __restrict__ q_bs,
    const float* __restrict__ q_bb, const float* __restrict__ q_bm,
    const float* __restrict__ q_bv,
    const float* __restrict__ k_dwk, const float* __restrict__ k_bs,
    const float* __restrict__ k_bb, const float* __restrict__ k_bm,
    const float* __restrict__ k_bv,
    const float* __restrict__ v_dwk, const float* __restrict__ v_bs,
    const float* __restrict__ v_bb, const float* __restrict__ v_bm,
    const float* __restrict__ v_bv,
    const float* __restrict__ w0, const float* __restrict__ w1,
    const float* __restrict__ w2, const float* __restrict__ w3,
    f16* __restrict__ o0, f16* __restrict__ o1,
    f16* __restrict__ o2, f16* __restrict__ o3,
    f16* __restrict__ qdw, f16* __restrict__ kdw, f16* __restrict__ vdw) {
  __shared__ float t[32][33];
  const int blk = blockIdx.x;
  const int tid = threadIdx.x;
  if (blk < 4704) {
    dw_s1_body(blk, tid, inputs_q, q_dwk, q_bs, q_bb, q_bm, q_bv, qdw);
  } else if (blk < 7056) {
    dw_s2_body(blk - 4704, tid, inputs_kv,
               k_dwk, k_bs, k_bb, k_bm, k_bv,
               v_dwk, v_bs, v_bb, v_bm, v_bv, kdw, vdw);
  } else {
    const int r = blk - 7056;                 // 0..575  (12 x 12 x 4)
    const int z = r / 144, rem = r % 144;
    const int bx = rem % 12, by = rem / 12;
    const float* src = z == 0 ? w0 : z == 1 ? w1 : z == 2 ? w2 : w3;
    f16* dst = z == 0 ? o0 : z == 1 ? o1 : z == 2 ? o2 : o3;
    const int k0 = bx * 32, n0 = by * 32;
    const int x = tid & 31, y = tid >> 5;
#pragma unroll
    for (int i = 0; i < 4; ++i) t[y + i * 8][x] = src[(size_t)(k0 + y + i * 8) * 384 + n0 + x];
    __syncthreads();
#pragma unroll
    for (int i = 0; i < 4; ++i)
      dst[(size_t)(n0 + y + i * 8) * 384 + k0 + x] = (f16)t[x][y + i * 8];
  }
}

// ------------- f16 MFMA GEMM body (128x128 tile, BK=64, 4 waves, 4x4 frags) -------------
// MODE 0: fp32 row-major; MODE 1: f16 row-major; MODE 2: f16 V^T (vtp [b*384+d][784])
template <int MODE>
__device__ __forceinline__ void gemm_body(
    const f16* __restrict__ A, const f16* __restrict__ Bt,
    float* __restrict__ Cf, f16* __restrict__ Ch, float scale,
    int row0, int col0) {
  __shared__ f16 As[128 * 64];   // [row][k], 128 B per row
  __shared__ f16 Bs[128 * 64];   // [col][k], 128 B per col
  const int tid = threadIdx.x;
  const int wave = tid >> 6, lane = tid & 63;
  const int c = lane & 15, g = lane >> 4;
  const int wr = wave >> 1, wc = wave & 1;     // 2x2 waves, each 64x64

  const int s_base = wave * 64 + lane;
  f32x4 acc[4][4] = {};

  for (int k0 = 0; k0 < 384; k0 += 64) {
    __syncthreads();
#pragma unroll
    for (int j = 0; j < 4; ++j) {
      const int s = j * 256 + s_base;
      const int row = s >> 3, sch = s & 7;
      const int lch = sch ^ (row & 7);         // logical k-chunk fetched
      const f16* sa = A + (size_t)(row0 + row) * 384 + k0 + lch * 8;
      __builtin_amdgcn_global_load_lds(
          (const __attribute__((address_space(1))) void*)sa,
          (__attribute__((address_space(3))) void*)(As + j * 2048 + wave * 512), 16, 0, 0);
      const f16* sb = Bt + (size_t)(col0 + row) * 384 + k0 + lch * 8;
      __builtin_amdgcn_global_load_lds(
          (const __attribute__((address_space(1))) void*)sb,
          (__attribute__((address_space(3))) void*)(Bs + j * 2048 + wave * 512), 16, 0, 0);
    }
    __syncthreads();

#pragma unroll
    for (int kh = 0; kh < 2; ++kh) {
      f16x8 bf[4];
#pragma unroll
      for (int n = 0; n < 4; ++n) {
        const int row = wc * 64 + n * 16 + c;
        bf[n] = *(const f16x8*)(Bs + (size_t)row * 64 + ((kh * 4 + g) ^ (row & 7)) * 8);
      }
#pragma unroll
      for (int m = 0; m < 4; ++m) {
        const int row = wr * 64 + m * 16 + c;
        f16x8 af = *(const f16x8*)(As + (size_t)row * 64 + ((kh * 4 + g) ^ (row & 7)) * 8);
#pragma unroll
        for (int n = 0; n < 4; ++n)
          acc[m][n] = __builtin_amdgcn_mfma_f32_16x16x32_f16(af, bf[n], acc[m][n], 0, 0, 0);
      }
    }
  }

  if (MODE == 2) {
#pragma unroll
    for (int m = 0; m < 4; ++m)
#pragma unroll
      for (int n = 0; n < 4; ++n) {
        const int gr = row0 + wr * 64 + m * 16 + g * 4;
        const int col = col0 + wc * 64 + n * 16 + c;
        const int bb = gr / NKV;
        const int kv = gr - bb * NKV;           // 4-pack cannot cross batch (784%4==0, gr%4==0)
        f16x4 pk;
#pragma unroll
        for (int r = 0; r < 4; ++r) pk[r] = (f16)(acc[m][n][r] * scale);
        *(f16x4*)(Ch + ((size_t)bb * 384 + col) * NKV + kv) = pk;
      }
  } else {
#pragma unroll
    for (int m = 0; m < 4; ++m)
#pragma unroll
      for (int n = 0; n < 4; ++n)
#pragma unroll
        for (int r = 0; r < 4; ++r) {
          const size_t row = row0 + wr * 64 + m * 16 + g * 4 + r;
          const size_t col = col0 + wc * 64 + n * 16 + c;
          if (MODE == 1) Ch[row * 384 + col] = (f16)(acc[m][n][r] * scale);
          else           Cf[row * 384 + col] = acc[m][n][r] * scale;
        }
  }
}

// fused q/k/v pointwise GEMMs: 882 flat blocks = q(196x3) + k(49x3) + v(49x3)
__global__ __launch_bounds__(256) void gemm_qkv(
    const f16* __restrict__ qdw, const f16* __restrict__ wqt, f16* __restrict__ qf, float qscale,
    const f16* __restrict__ kdw, const f16* __restrict__ wkt, f16* __restrict__ kf,
    const f16* __restrict__ vdw, const f16* __restrict__ wvt, f16* __restrict__ vtp) {
  const int blk = blockIdx.x;
  if (blk < 588) {
    gemm_body<1>(qdw, wqt, nullptr, qf, qscale, (blk % 196) * 128, (blk / 196) * 128);
  } else if (blk < 735) {
    const int r = blk - 588;
    gemm_body<1>(kdw, wkt, nullptr, kf, 1.0f, (r % 49) * 128, (r / 49) * 128);
  } else {
    const int r = blk - 735;
    gemm_body<2>(vdw, wvt, nullptr, vtp, 1.0f, (r % 49) * 128, (r / 49) * 128);
  }
}

template <int MODE>
__global__ __launch_bounds__(256) void gemm_mfma(
    const f16* __restrict__ A, const f16* __restrict__ Bt,
    float* __restrict__ Cf, f16* __restrict__ Ch, float scale) {
  gemm_body<MODE>(A, Bt, Cf, Ch, scale, blockIdx.x * 128, blockIdx.y * 128);
}

// ------------- f16 MFMA flash attention, swapped-QK^T, KVT=64, XCD-chunked -------------
// grid = 2352; lb = (bid&7)*294 + (bid>>3): each XCD owns 6 complete (b,h) pairs.
// 12 full tiles (no clamps/masks) + specialized 16-row tail tile (t0=768):
// only ct=0 S-MFMAs, 4 exp2, zero-P for local kv 16..31, ks=0 PV slice.
__global__ __launch_bounds__(256) void attn_mfma(
    const f16* __restrict__ qp, const f16* __restrict__ kp,
    const f16* __restrict__ vt, f16* __restrict__ op) {
  __shared__ f16 Ks[64 * 64];      // [kv][d], chunk ch at ch^(kv&7)
  __shared__ f16 Vs[64 * 64];      // [d][kv], chunk ch at ch^(d&7)
  __shared__ f16 Ps[4][16 * 64];   // per-wave [q][kv], ch^(q&7)
  const int bid0 = blockIdx.x;
  const int lb = (bid0 & 7) * 294 + (bid0 >> 3);   // bijective (2352 = 8*294)
  const int qt = lb % 49;
  const int bh = lb / 49;
  const int h = bh % NHD, b = bh / NHD;
  const int tid = threadIdx.x;
  const int wave = tid >> 6, lane = tid & 63;
  const int c = lane & 15, g = lane >> 4;

  const size_t qrow = (size_t)b * NQ + qt * 64 + wave * 16 + c;
  f16x8 qa[2];
  qa[0] = *(const f16x8*)(qp + qrow * 384 + h * 64 + g * 8);
  qa[1] = *(const f16x8*)(qp + qrow * 384 + h * 64 + 32 + g * 8);

  f16x8 vones;
#pragma unroll
  for (int j = 0; j < 8; ++j) vones[j] = (f16)1.0f;

  const int tid8 = tid >> 3, tch = tid & 7;
  const int lch = tch ^ (tid8 & 7);            // logical chunk fetched

  const f16* kbase = kp + ((size_t)b * NKV) * 384 + h * 64;
  const f16* vbase = vt + ((size_t)(b * 384 + h * 64)) * NKV;

  float mrun = -1e30f;                // for q = c (redundant across g)
  f32x4 o[4] = {};                    // O[q=g*4+r][d=dt*16+c]
  f32x4 osum = {};                    // lsum[q=g*4+r]
  f16* prow = &Ps[wave][0];

  // -------- 12 full tiles: no clamps, no tail masks --------
  for (int ti = 0; ti < 12; ++ti) {
    const int t0 = ti * 64;
    __syncthreads();
    {
      __builtin_amdgcn_global_load_lds(
          (const __attribute__((address_space(1))) void*)(kbase + (size_t)(t0 + tid8) * 384 + lch * 8),
          (__attribute__((address_space(3))) void*)(Ks + wave * 512), 16, 0, 0);
      __builtin_amdgcn_global_load_lds(
          (const __attribute__((address_space(1))) void*)(kbase + (size_t)(t0 + 32 + tid8) * 384 + lch * 8),
          (__attribute__((address_space(3))) void*)(Ks + 2048 + wave * 512), 16, 0, 0);
      const int col = t0 + lch * 8;
      __builtin_amdgcn_global_load_lds(
          (const __attribute__((address_space(1))) void*)(vbase + (size_t)tid8 * NKV + col),
          (__attribute__((address_space(3))) void*)(Vs + wave * 512), 16, 0, 0);
      __builtin_amdgcn_global_load_lds(
          (const __attribute__((address_space(1))) void*)(vbase + (size_t)(32 + tid8) * NKV + col),
          (__attribute__((address_space(3))) void*)(Vs + 2048 + wave * 512), 16, 0, 0);
    }
    __syncthreads();

    // S^T tiles
    f32x4 s[4] = {};
    __builtin_amdgcn_s_setprio(1);
#pragma unroll
    for (int kh = 0; kh < 2; ++kh) {
#pragma unroll
      for (int ct = 0; ct < 4; ++ct) {
        const int row = ct * 16 + c;
        const int sch = (kh * 4 + g) ^ (row & 7);
        f16x8 kb = *(const f16x8*)(Ks + row * 64 + sch * 8);
        s[ct] = __builtin_amdgcn_mfma_f32_16x16x32_f16(kb, qa[kh], s[ct], 0, 0, 0);
      }
    }
    __builtin_amdgcn_s_setprio(0);

    // tile max for q=c
    float mt = s[0][0];
#pragma unroll
    for (int ct = 0; ct < 4; ++ct)
#pragma unroll
      for (int r = 0; r < 4; ++r) mt = fmaxf(mt, s[ct][r]);
    mt = fmaxf(mt, __shfl_xor(mt, 16));
    mt = fmaxf(mt, __shfl_xor(mt, 32));

    if (__ballot(mt > mrun + 8.0f)) {   // defer-max: P bounded by 2^8
      const float mnew = fmaxf(mrun, mt);
      const float corr = fast_exp2(mrun - mnew);
      mrun = mnew;
#pragma unroll
      for (int r = 0; r < 4; ++r) {
        const float co = __shfl(corr, g * 4 + r);
#pragma unroll
        for (int dt = 0; dt < 4; ++dt) o[dt][r] *= co;
        osum[r] *= co;
      }
    }

    // P = exp2(S - mrun); pack f16, store to per-wave LDS
#pragma unroll
    for (int ct = 0; ct < 4; ++ct) {
      const float p0 = fast_exp2(s[ct][0] - mrun);
      const float p1 = fast_exp2(s[ct][1] - mrun);
      const float p2 = fast_exp2(s[ct][2] - mrun);
      const float p3 = fast_exp2(s[ct][3] - mrun);
      const int sch = (ct * 2 + (g >> 1)) ^ (c & 7);
      *(f16x4*)(prow + c * 64 + sch * 8 + (g & 1) * 4) = pack4(p0, p1, p2, p3);
    }

    // PV + lsum
    __builtin_amdgcn_s_setprio(1);
#pragma unroll
    for (int ks = 0; ks < 2; ++ks) {
      const int sp = (ks * 4 + g) ^ (c & 7);
      f16x8 pa = *(const f16x8*)(prow + c * 64 + sp * 8);
#pragma unroll
      for (int dt = 0; dt < 4; ++dt) {
        const int d = dt * 16 + c;
        f16x8 vb = *(const f16x8*)(Vs + d * 64 + sp * 8);
        o[dt] = __builtin_amdgcn_mfma_f32_16x16x32_f16(pa, vb, o[dt], 0, 0, 0);
      }
      osum = __builtin_amdgcn_mfma_f32_16x16x32_f16(pa, vones, osum, 0, 0, 0);
    }
    __builtin_amdgcn_s_setprio(0);
  }

  // -------- tail tile: t0 = 768, only 16 valid KV rows --------
  {
    const int t0 = 768;
    __syncthreads();
    {
      int kv0 = t0 + tid8; if (kv0 > NKV - 1) kv0 = NKV - 1;     // rows 16..31 clamped (unused)
      __builtin_amdgcn_global_load_lds(
          (const __attribute__((address_space(1))) void*)(kbase + (size_t)kv0 * 384 + lch * 8),
          (__attribute__((address_space(3))) void*)(Ks + wave * 512), 16, 0, 0);
      int col = t0 + lch * 8; if (col > NKV - 8) col = NKV - 8;  // chunks >=2 clamped (P=0 there)
      __builtin_amdgcn_global_load_lds(
          (const __attribute__((address_space(1))) void*)(vbase + (size_t)tid8 * NKV + col),
          (__attribute__((address_space(3))) void*)(Vs + wave * 512), 16, 0, 0);
      __builtin_amdgcn_global_load_lds(
          (const __attribute__((address_space(1))) void*)(vbase + (size_t)(32 + tid8) * NKV + col),
          (__attribute__((address_space(3))) void*)(Vs + 2048 + wave * 512), 16, 0, 0);
    }
    __syncthreads();

    // S^T: only ct=0 (kv 768+c, all valid since c<16)
    f32x4 s0 = {};
    __builtin_amdgcn_s_setprio(1);
#pragma unroll
    for (int kh = 0; kh < 2; ++kh) {
      const int sch = (kh * 4 + g) ^ (c & 7);
      f16x8 kb = *(const f16x8*)(Ks + c * 64 + sch * 8);
      s0 = __builtin_amdgcn_mfma_f32_16x16x32_f16(kb, qa[kh], s0, 0, 0, 0);
    }
    __builtin_amdgcn_s_setprio(0);

    float mt = fmaxf(fmaxf(s0[0], s0[1]), fmaxf(s0[2], s0[3]));
    mt = fmaxf(mt, __shfl_xor(mt, 16));
    mt = fmaxf(mt, __shfl_xor(mt, 32));
    if (__ballot(mt > mrun + 8.0f)) {
      const float mnew = fmaxf(mrun, mt);
      const float corr = fast_exp2(mrun - mnew);
      mrun = mnew;
#pragma unroll
      for (int r = 0; r < 4; ++r) {
        const float co = __shfl(corr, g * 4 + r);
#pragma unroll
        for (int dt = 0; dt < 4; ++dt) o[dt][r] *= co;
        osum[r] *= co;
      }
    }

    // P for local kv 0..15 (ct=0); zeros for 16..31 (ct=1)
    {
      const float p0 = fast_exp2(s0[0] - mrun);
      const float p1 = fast_exp2(s0[1] - mrun);
      const float p2 = fast_exp2(s0[2] - mrun);
      const float p3 = fast_exp2(s0[3] - mrun);
      const int sch0 = (0 + (g >> 1)) ^ (c & 7);
      *(f16x4*)(prow + c * 64 + sch0 * 8 + (g & 1) * 4) = pack4(p0, p1, p2, p3);
      const int sch1 = (2 + (g >> 1)) ^ (c & 7);
      f16x4 z = {};
      *(f16x4*)(prow + c * 64 + sch1 * 8 + (g & 1) * 4) = z;
    }

    // PV ks=0 only (local kv 0..31; 16..31 have P=0)
    __builtin_amdgcn_s_setprio(1);
    {
      const int sp = g ^ (c & 7);
      f16x8 pa = *(const f16x8*)(prow + c * 64 + sp * 8);
#pragma unroll
      for (int dt = 0; dt < 4; ++dt) {
        const int d = dt * 16 + c;
        f16x8 vb = *(const f16x8*)(Vs + d * 64 + sp * 8);
        o[dt] = __builtin_amdgcn_mfma_f32_16x16x32_f16(pa, vb, o[dt], 0, 0, 0);
      }
      osum = __builtin_amdgcn_mfma_f32_16x16x32_f16(pa, vones, osum, 0, 0, 0);
    }
    __builtin_amdgcn_s_setprio(0);
  }

  // epilogue: osum already in q=g*4+r row layout -> no shuffles
  f16* obase = op + ((size_t)(b * NQ + qt * 64 + wave * 16)) * 384 + h * 64;
#pragma unroll
  for (int r = 0; r < 4; ++r) {
    const float iv = 1.0f / osum[r];
#pragma unroll
    for (int dt = 0; dt < 4; ++dt)
      obase[(size_t)(g * 4 + r) * 384 + dt * 16 + c] = (f16)(o[dt][r] * iv);
  }
}

extern "C" void kernel_launch(void* const* d_in, const int* in_sizes, int n_in,
                              void* d_out, int out_size, void* d_ws, size_t ws_size,
                              hipStream_t stream) {
  const float* inputs_q  = (const float*)d_in[0];
  const float* inputs_kv = (const float*)d_in[1];
  const float* out_kern  = (const float*)d_in[2];
  const float* q_dwk = (const float*)d_in[3];
  const float* q_bs  = (const float*)d_in[4];
  const float* q_bb  = (const float*)d_in[5];
  const float* q_bm  = (const float*)d_in[6];
  const float* q_bv  = (const float*)d_in[7];
  const float* q_pwk = (const float*)d_in[8];
  const float* k_dwk = (const float*)d_in[9];
  const float* k_bs  = (const float*)d_in[10];
  const float* k_bb  = (const float*)d_in[11];
  const float* k_bm  = (const float*)d_in[12];
  const float* k_bv  = (const float*)d_in[13];
  const float* k_pwk = (const float*)d_in[14];
  const float* v_dwk = (const float*)d_in[15];
  const float* v_bs  = (const float*)d_in[16];
  const float* v_bb  = (const float*)d_in[17];
  const float* v_bm  = (const float*)d_in[18];
  const float* v_bv  = (const float*)d_in[19];
  const float* v_pwk = (const float*)d_in[20];

  char* wsb = (char*)d_ws;
  f16* qdw = (f16*)(wsb + 0);             // 25088*384 f16
  f16* kdw = (f16*)(wsb + 19267584);      // 6272*384 f16
  f16* vdw = (f16*)(wsb + 24084480);      // 6272*384 f16
  f16* qf  = (f16*)(wsb + 28901376);      // 25088*384 f16
  f16* kf  = (f16*)(wsb + 48168960);      // 6272*384 f16
  f16* vtp = (f16*)(wsb + 57802752);      // 8*384*784 f16
  f16* of  = (f16*)(wsb + 62619648);      // 25088*384 f16
  f16* wqt = (f16*)(wsb + 81887232);      // 384*384 f16 x4
  f16* wkt = (f16*)(wsb + 82182144);
  f16* wvt = (f16*)(wsb + 82477056);
  f16* wot = (f16*)(wsb + 82771968);

  // 1. fused preprocess: dw+BN (q, k&v) + weight transpose-convert
  preprocess<<<7632, 256, 0, stream>>>(
      inputs_q, inputs_kv,
      q_dwk, q_bs, q_bb, q_bm, q_bv,
      k_dwk, k_bs, k_bb, k_bm, k_bv,
      v_dwk, v_bs, v_bb, v_bm, v_bv,
      q_pwk, k_pwk, v_pwk, out_kern, wqt, wkt, wvt, wot,
      qdw, kdw, vdw);
  // 2. fused q/k/v pointwise GEMMs (V written transposed; q folded with 1/8*log2e)
  gemm_qkv<<<882, 256, 0, stream>>>(qdw, wqt, qf, 0.125f * LOG2E,
                                    kdw, wkt, kf, vdw, wvt, vtp);
  // 3. MFMA attention (KVT=64, XCD-chunked, specialized tail) -> f16 O
  attn_mfma<<<BB * NHD * 49, 256, 0, stream>>>(qf, kf, vtp, of);
  // 4. output projection (MFMA, fp32 out)
  gemm_mfma<0><<<dim3(196, 3), 256, 0, stream>>>(of, wot, (float*)d_out, nullptr, 1.0f);
}

// Round 16
// 148.785 us; speedup vs baseline: 1.3718x; 1.0095x over previous
//
#include <hip/hip_runtime.h>
#include <hip/hip_bf16.h>
#include <hip/hip_fp16.h>

// Problem constants
#define BB 8
#define HH 56
#define WW 56
#define CC 384
#define NHD 6
#define DD 64
#define HK 28
#define WK 28
#define NQ (HH*WW)       // 3136
#define NKV (HK*WK)      // 784
#define NTOK (BB*NQ)     // 25088
#define NTOKKV (BB*NKV)  // 6272
#define BN_EPS 1e-5f
#define LOG2E 1.44269504f

typedef _Float16 f16;
typedef _Float16 f16x2 __attribute__((ext_vector_type(2)));
typedef _Float16 f16x4 __attribute__((ext_vector_type(4)));
typedef _Float16 f16x8 __attribute__((ext_vector_type(8)));
typedef float f32x4 __attribute__((ext_vector_type(4)));

__device__ __forceinline__ float fast_exp2(float x) {
#if __has_builtin(__builtin_amdgcn_exp2f)
  return __builtin_amdgcn_exp2f(x);   // v_exp_f32 (2^x)
#else
  return __expf(x * 0.69314718056f);
#endif
}

__device__ __forceinline__ f16x4 pack4(float p0, float p1, float p2, float p3) {
#if __has_builtin(__builtin_amdgcn_cvt_pkrtz)
  f16x2 a = __builtin_bit_cast(f16x2, __builtin_amdgcn_cvt_pkrtz(p0, p1));
  f16x2 b = __builtin_bit_cast(f16x2, __builtin_amdgcn_cvt_pkrtz(p2, p3));
  return __builtin_shufflevector(a, b, 0, 1, 2, 3);
#else
  f16x4 r; r[0] = (f16)p0; r[1] = (f16)p1; r[2] = (f16)p2; r[3] = (f16)p3;
  return r;
#endif
}

// ---------------- dw conv + BN bodies (called from fused preprocess) ----------------
__device__ __forceinline__ void dw_s1_body(
    int blk, int tid, const float* __restrict__ in, const float* __restrict__ w,
    const float* __restrict__ bns, const float* __restrict__ bnb,
    const float* __restrict__ bnm, const float* __restrict__ bnv,
    f16* __restrict__ out) {
  int idx = blk * 256 + tid;                     // < (NTOK/2)*96 = 1204224
  int pp = idx / 96;
  int c = (idx % 96) * 4;
  int b = pp / (HH * WK);
  int rem = pp % (HH * WK);
  int y = rem / WK, xh = rem % WK;
  int x0 = xh * 2;
  float a0x = 0, a0y = 0, a0z = 0, a0w = 0;
  float a1x = 0, a1y = 0, a1z = 0, a1w = 0;
#pragma unroll
  for (int kh = 0; kh < 3; ++kh) {
    int iy = y + kh - 1;
    if ((unsigned)iy >= (unsigned)HH) continue;
    const float* rp = in + ((size_t)(b * HH + iy) * WW) * CC + c;
    const float4 z4 = {0.f, 0.f, 0.f, 0.f};
    const float4 v0 = (x0 > 0) ? *(const float4*)(rp + (size_t)(x0 - 1) * CC) : z4;
    const float4 v1 = *(const float4*)(rp + (size_t)x0 * CC);
    const float4 v2 = *(const float4*)(rp + (size_t)(x0 + 1) * CC);
    const float4 v3 = (x0 < 54) ? *(const float4*)(rp + (size_t)(x0 + 2) * CC) : z4;
    const float4 w0 = *(const float4*)(w + (kh * 3 + 0) * CC + c);
    const float4 w1 = *(const float4*)(w + (kh * 3 + 1) * CC + c);
    const float4 w2 = *(const float4*)(w + (kh * 3 + 2) * CC + c);
    a0x = fmaf(v0.x, w0.x, fmaf(v1.x, w1.x, fmaf(v2.x, w2.x, a0x)));
    a0y = fmaf(v0.y, w0.y, fmaf(v1.y, w1.y, fmaf(v2.y, w2.y, a0y)));
    a0z = fmaf(v0.z, w0.z, fmaf(v1.z, w1.z, fmaf(v2.z, w2.z, a0z)));
    a0w = fmaf(v0.w, w0.w, fmaf(v1.w, w1.w, fmaf(v2.w, w2.w, a0w)));
    a1x = fmaf(v1.x, w0.x, fmaf(v2.x, w1.x, fmaf(v3.x, w2.x, a1x)));
    a1y = fmaf(v1.y, w0.y, fmaf(v2.y, w1.y, fmaf(v3.y, w2.y, a1y)));
    a1z = fmaf(v1.z, w0.z, fmaf(v2.z, w1.z, fmaf(v3.z, w2.z, a1z)));
    a1w = fmaf(v1.w, w0.w, fmaf(v2.w, w1.w, fmaf(v3.w, w2.w, a1w)));
  }
  const float4 s = *(const float4*)(bns + c);
  const float4 bi = *(const float4*)(bnb + c);
  const float4 m = *(const float4*)(bnm + c);
  const float4 va = *(const float4*)(bnv + c);
  f16x4 r0, r1;
  float g;
  g = s.x * rsqrtf(va.x + BN_EPS); r0[0] = (f16)fmaf(a0x - m.x, g, bi.x); r1[0] = (f16)fmaf(a1x - m.x, g, bi.x);
  g = s.y * rsqrtf(va.y + BN_EPS); r0[1] = (f16)fmaf(a0y - m.y, g, bi.y); r1[1] = (f16)fmaf(a1y - m.y, g, bi.y);
  g = s.z * rsqrtf(va.z + BN_EPS); r0[2] = (f16)fmaf(a0z - m.z, g, bi.z); r1[2] = (f16)fmaf(a1z - m.z, g, bi.z);
  g = s.w * rsqrtf(va.w + BN_EPS); r0[3] = (f16)fmaf(a0w - m.w, g, bi.w); r1[3] = (f16)fmaf(a1w - m.w, g, bi.w);
  const size_t pix0 = (size_t)b * NQ + y * WW + x0;
  *(f16x4*)(out + pix0 * CC + c) = r0;
  *(f16x4*)(out + (pix0 + 1) * CC + c) = r1;
}

__device__ __forceinline__ void dw_s2_body(
    int blk, int tid, const float* __restrict__ in,
    const float* __restrict__ wk_, const float* __restrict__ kbs, const float* __restrict__ kbb,
    const float* __restrict__ kbm, const float* __restrict__ kbv,
    const float* __restrict__ wv_, const float* __restrict__ vbs, const float* __restrict__ vbb,
    const float* __restrict__ vbm, const float* __restrict__ vbv,
    f16* __restrict__ outk, f16* __restrict__ outv) {
  int idx = blk * 256 + tid;                     // < NTOKKV*96
  int pix = idx / 96;
  int c = (idx % 96) * 4;
  int b = pix / (HK * WK);
  int p = pix % (HK * WK);
  int oy = p / WK, ox = p % WK;
  float kx = 0, ky = 0, kz = 0, kw4 = 0;
  float vx = 0, vy = 0, vz = 0, vw4 = 0;
#pragma unroll
  for (int kh = 0; kh < 3; ++kh) {
    int iy = oy * 2 + kh;
    if (iy >= HH) continue;
#pragma unroll
    for (int kwi = 0; kwi < 3; ++kwi) {
      int ix = ox * 2 + kwi;
      if (ix >= WW) continue;
      const float4 v = *(const float4*)(in + (((size_t)(b * HH + iy) * WW + ix) * CC + c));
      const float4 a = *(const float4*)(wk_ + ((kh * 3 + kwi) * CC + c));
      const float4 bq = *(const float4*)(wv_ + ((kh * 3 + kwi) * CC + c));
      kx = fmaf(v.x, a.x, kx); ky = fmaf(v.y, a.y, ky);
      kz = fmaf(v.z, a.z, kz); kw4 = fmaf(v.w, a.w, kw4);
      vx = fmaf(v.x, bq.x, vx); vy = fmaf(v.y, bq.y, vy);
      vz = fmaf(v.z, bq.z, vz); vw4 = fmaf(v.w, bq.w, vw4);
    }
  }
  {
    const float4 s = *(const float4*)(kbs + c);
    const float4 bi = *(const float4*)(kbb + c);
    const float4 m = *(const float4*)(kbm + c);
    const float4 va = *(const float4*)(kbv + c);
    f16x4 r; float g;
    g = s.x * rsqrtf(va.x + BN_EPS); r[0] = (f16)fmaf(kx - m.x, g, bi.x);
    g = s.y * rsqrtf(va.y + BN_EPS); r[1] = (f16)fmaf(ky - m.y, g, bi.y);
    g = s.z * rsqrtf(va.z + BN_EPS); r[2] = (f16)fmaf(kz - m.z, g, bi.z);
    g = s.w * rsqrtf(va.w + BN_EPS); r[3] = (f16)fmaf(kw4 - m.w, g, bi.w);
    *(f16x4*)(outk + (size_t)pix * CC + c) = r;
  }
  {
    const float4 s = *(const float4*)(vbs + c);
    const float4 bi = *(const float4*)(vbb + c);
    const float4 m = *(const float4*)(vbm + c);
    const float4 va = *(const float4*)(vbv + c);
    f16x4 r; float g;
    g = s.x * rsqrtf(va.x + BN_EPS); r[0] = (f16)fmaf(vx - m.x, g, bi.x);
    g = s.y * rsqrtf(va.y + BN_EPS); r[1] = (f16)fmaf(vy - m.y, g, bi.y);
    g = s.z * rsqrtf(va.z + BN_EPS); r[2] = (f16)fmaf(vz - m.z, g, bi.z);
    g = s.w * rsqrtf(va.w + BN_EPS); r[3] = (f16)fmaf(vw4 - m.w, g, bi.w);
    *(f16x4*)(outv + (size_t)pix * CC + c) = r;
  }
}

// ---- fused preprocess: dw_s1 (4704 blocks) + dw_s2_kv (2352) + convert_w (576) ----
__global__ __launch_bounds__(256) void preprocess(
    const float* __restrict__ inputs_q, const float* __restrict__ inputs_kv,
    const float* __restrict__ q_dwk, const float* __restrict__ q_bs,
    const float* __restrict__ q_bb, const float* __restrict__ q_bm,
    const float* __restrict__ q_bv,
    const float* __restrict__ k_dwk, const float* __restrict__ k_bs,
    const float* __restrict__ k_bb, const float* __restrict__ k_bm,
    const float* __restrict__ k_bv,
    const float* __restrict__ v_dwk, const float* __restrict__ v_bs,
    const float* __restrict__ v_bb, const float* __restrict__ v_bm,
    const float* __restrict__ v_bv,
    const float* __restrict__ w0, const float* __restrict__ w1,
    const float* __restrict__ w2, const float* __restrict__ w3,
    f16* __restrict__ o0, f16* __restrict__ o1,
    f16* __restrict__ o2, f16* __restrict__ o3,
    f16* __restrict__ qdw, f16* __restrict__ kdw, f16* __restrict__ vdw) {
  __shared__ float t[32][33];
  const int blk = blockIdx.x;
  const int tid = threadIdx.x;
  if (blk < 4704) {
    dw_s1_body(blk, tid, inputs_q, q_dwk, q_bs, q_bb, q_bm, q_bv, qdw);
  } else if (blk < 7056) {
    dw_s2_body(blk - 4704, tid, inputs_kv,
               k_dwk, k_bs, k_bb, k_bm, k_bv,
               v_dwk, v_bs, v_bb, v_bm, v_bv, kdw, vdw);
  } else {
    const int r = blk - 7056;                 // 0..575  (12 x 12 x 4)
    const int z = r / 144, rem = r % 144;
    const int bx = rem % 12, by = rem / 12;
    const float* src = z == 0 ? w0 : z == 1 ? w1 : z == 2 ? w2 : w3;
    f16* dst = z == 0 ? o0 : z == 1 ? o1 : z == 2 ? o2 : o3;
    const int k0 = bx * 32, n0 = by * 32;
    const int x = tid & 31, y = tid >> 5;
#pragma unroll
    for (int i = 0; i < 4; ++i) t[y + i * 8][x] = src[(size_t)(k0 + y + i * 8) * 384 + n0 + x];
    __syncthreads();
#pragma unroll
    for (int i = 0; i < 4; ++i)
      dst[(size_t)(n0 + y + i * 8) * 384 + k0 + x] = (f16)t[x][y + i * 8];
  }
}

// ------------- f16 MFMA GEMM body (128x128 tile, BK=64, 4 waves, 4x4 frags) -------------
// MODE 0: fp32 row-major; MODE 1: f16 row-major; MODE 2: f16 V^T (vtp [b*384+d][784])
template <int MODE>
__device__ __forceinline__ void gemm_body(
    const f16* __restrict__ A, const f16* __restrict__ Bt,
    float* __restrict__ Cf, f16* __restrict__ Ch, float scale,
    int row0, int col0) {
  __shared__ f16 As[128 * 64];   // [row][k], 128 B per row
  __shared__ f16 Bs[128 * 64];   // [col][k], 128 B per col
  const int tid = threadIdx.x;
  const int wave = tid >> 6, lane = tid & 63;
  const int c = lane & 15, g = lane >> 4;
  const int wr = wave >> 1, wc = wave & 1;     // 2x2 waves, each 64x64

  const int s_base = wave * 64 + lane;
  f32x4 acc[4][4] = {};

  for (int k0 = 0; k0 < 384; k0 += 64) {
    __syncthreads();
#pragma unroll
    for (int j = 0; j < 4; ++j) {
      const int s = j * 256 + s_base;
      const int row = s >> 3, sch = s & 7;
      const int lch = sch ^ (row & 7);         // logical k-chunk fetched
      const f16* sa = A + (size_t)(row0 + row) * 384 + k0 + lch * 8;
      __builtin_amdgcn_global_load_lds(
          (const __attribute__((address_space(1))) void*)sa,
          (__attribute__((address_space(3))) void*)(As + j * 2048 + wave * 512), 16, 0, 0);
      const f16* sb = Bt + (size_t)(col0 + row) * 384 + k0 + lch * 8;
      __builtin_amdgcn_global_load_lds(
          (const __attribute__((address_space(1))) void*)sb,
          (__attribute__((address_space(3))) void*)(Bs + j * 2048 + wave * 512), 16, 0, 0);
    }
    __syncthreads();

#pragma unroll
    for (int kh = 0; kh < 2; ++kh) {
      f16x8 bf[4];
#pragma unroll
      for (int n = 0; n < 4; ++n) {
        const int row = wc * 64 + n * 16 + c;
        bf[n] = *(const f16x8*)(Bs + (size_t)row * 64 + ((kh * 4 + g) ^ (row & 7)) * 8);
      }
#pragma unroll
      for (int m = 0; m < 4; ++m) {
        const int row = wr * 64 + m * 16 + c;
        f16x8 af = *(const f16x8*)(As + (size_t)row * 64 + ((kh * 4 + g) ^ (row & 7)) * 8);
#pragma unroll
        for (int n = 0; n < 4; ++n)
          acc[m][n] = __builtin_amdgcn_mfma_f32_16x16x32_f16(af, bf[n], acc[m][n], 0, 0, 0);
      }
    }
  }

  if (MODE == 2) {
#pragma unroll
    for (int m = 0; m < 4; ++m)
#pragma unroll
      for (int n = 0; n < 4; ++n) {
        const int gr = row0 + wr * 64 + m * 16 + g * 4;
        const int col = col0 + wc * 64 + n * 16 + c;
        const int bb = gr / NKV;
        const int kv = gr - bb * NKV;           // 4-pack cannot cross batch (784%4==0, gr%4==0)
        f16x4 pk;
#pragma unroll
        for (int r = 0; r < 4; ++r) pk[r] = (f16)(acc[m][n][r] * scale);
        *(f16x4*)(Ch + ((size_t)bb * 384 + col) * NKV + kv) = pk;
      }
  } else {
#pragma unroll
    for (int m = 0; m < 4; ++m)
#pragma unroll
      for (int n = 0; n < 4; ++n)
#pragma unroll
        for (int r = 0; r < 4; ++r) {
          const size_t row = row0 + wr * 64 + m * 16 + g * 4 + r;
          const size_t col = col0 + wc * 64 + n * 16 + c;
          if (MODE == 1) Ch[row * 384 + col] = (f16)(acc[m][n][r] * scale);
          else           Cf[row * 384 + col] = acc[m][n][r] * scale;
        }
  }
}

// fused q/k/v pointwise GEMMs: 882 flat blocks = q(196x3) + k(49x3) + v(49x3)
__global__ __launch_bounds__(256) void gemm_qkv(
    const f16* __restrict__ qdw, const f16* __restrict__ wqt, f16* __restrict__ qf, float qscale,
    const f16* __restrict__ kdw, const f16* __restrict__ wkt, f16* __restrict__ kf,
    const f16* __restrict__ vdw, const f16* __restrict__ wvt, f16* __restrict__ vtp) {
  const int blk = blockIdx.x;
  if (blk < 588) {
    gemm_body<1>(qdw, wqt, nullptr, qf, qscale, (blk % 196) * 128, (blk / 196) * 128);
  } else if (blk < 735) {
    const int r = blk - 588;
    gemm_body<1>(kdw, wkt, nullptr, kf, 1.0f, (r % 49) * 128, (r / 49) * 128);
  } else {
    const int r = blk - 735;
    gemm_body<2>(vdw, wvt, nullptr, vtp, 1.0f, (r % 49) * 128, (r / 49) * 128);
  }
}

template <int MODE>
__global__ __launch_bounds__(256) void gemm_mfma(
    const f16* __restrict__ A, const f16* __restrict__ Bt,
    float* __restrict__ Cf, f16* __restrict__ Ch, float scale) {
  gemm_body<MODE>(A, Bt, Cf, Ch, scale, blockIdx.x * 128, blockIdx.y * 128);
}

// ------------- f16 MFMA flash attention, swapped-QK^T, KVT=64, XCD-chunked, T14 -------------
// grid = 2352; lb = (bid&7)*294 + (bid>>3): each XCD owns 6 complete (b,h) pairs.
// T14 async-STAGE: K/V chunks loaded into REGISTERS during the previous tile's
// compute; after the barrier only ds_write_b128 x4 + barrier (global latency hidden).
// Thread tid owns LDS slot tid (byte tid*16) - identical layout to global_load_lds dest.
// 12 full tiles + specialized 16-row tail tile.
__global__ __launch_bounds__(256) void attn_mfma(
    const f16* __restrict__ qp, const f16* __restrict__ kp,
    const f16* __restrict__ vt, f16* __restrict__ op) {
  __shared__ f16 Ks[64 * 64];      // [kv][d], chunk ch at ch^(kv&7)
  __shared__ f16 Vs[64 * 64];      // [d][kv], chunk ch at ch^(d&7)
  __shared__ f16 Ps[4][16 * 64];   // per-wave [q][kv], ch^(q&7)
  const int bid0 = blockIdx.x;
  const int lb = (bid0 & 7) * 294 + (bid0 >> 3);   // bijective (2352 = 8*294)
  const int qt = lb % 49;
  const int bh = lb / 49;
  const int h = bh % NHD, b = bh / NHD;
  const int tid = threadIdx.x;
  const int wave = tid >> 6, lane = tid & 63;
  const int c = lane & 15, g = lane >> 4;

  const size_t qrow = (size_t)b * NQ + qt * 64 + wave * 16 + c;
  f16x8 qa[2];
  qa[0] = *(const f16x8*)(qp + qrow * 384 + h * 64 + g * 8);
  qa[1] = *(const f16x8*)(qp + qrow * 384 + h * 64 + 32 + g * 8);

  f16x8 vones;
#pragma unroll
  for (int j = 0; j < 8; ++j) vones[j] = (f16)1.0f;

  const int tid8 = tid >> 3, tch = tid & 7;
  const int lch = tch ^ (tid8 & 7);            // logical chunk fetched

  const f16* kbase = kp + ((size_t)b * NKV) * 384 + h * 64;
  const f16* vbase = vt + ((size_t)(b * 384 + h * 64)) * NKV;

  float mrun = -1e30f;                // for q = c (redundant across g)
  f32x4 o[4] = {};                    // O[q=g*4+r][d=dt*16+c]
  f32x4 osum = {};                    // lsum[q=g*4+r]
  f16* prow = &Ps[wave][0];

  // T14 staging registers + preload tile 0 (all indices in-bounds at t0=0)
  f16x8 kr0, kr1, vr0, vr1;
  kr0 = *(const f16x8*)(kbase + (size_t)tid8 * 384 + lch * 8);
  kr1 = *(const f16x8*)(kbase + (size_t)(32 + tid8) * 384 + lch * 8);
  vr0 = *(const f16x8*)(vbase + (size_t)tid8 * NKV + lch * 8);
  vr1 = *(const f16x8*)(vbase + (size_t)(32 + tid8) * NKV + lch * 8);

  for (int ti = 0; ti < 13; ++ti) {
    __syncthreads();                  // all waves done reading LDS (prev tile)
    // write staged regs -> LDS (slot tid, same layout as global_load_lds dest)
    *(f16x8*)(Ks + tid * 8) = kr0;
    *(f16x8*)(Ks + 2048 + tid * 8) = kr1;
    *(f16x8*)(Vs + tid * 8) = vr0;
    *(f16x8*)(Vs + 2048 + tid * 8) = vr1;
    // issue next tile's loads into regs (fly during this tile's compute)
    if (ti + 1 < 13) {
      const int t0n = (ti + 1) * 64;
      int kvA = t0n + tid8;        if (kvA > NKV - 1) kvA = NKV - 1;
      int kvB = t0n + 32 + tid8;   if (kvB > NKV - 1) kvB = NKV - 1;
      int colc = t0n + lch * 8;    if (colc > NKV - 8) colc = NKV - 8;
      kr0 = *(const f16x8*)(kbase + (size_t)kvA * 384 + lch * 8);
      kr1 = *(const f16x8*)(kbase + (size_t)kvB * 384 + lch * 8);
      vr0 = *(const f16x8*)(vbase + (size_t)tid8 * NKV + colc);
      vr1 = *(const f16x8*)(vbase + (size_t)(32 + tid8) * NKV + colc);
    }
    __syncthreads();                  // LDS writes visible to all waves

    if (ti < 12) {
      // -------- full tile --------
      f32x4 s[4] = {};
      __builtin_amdgcn_s_setprio(1);
#pragma unroll
      for (int kh = 0; kh < 2; ++kh) {
#pragma unroll
        for (int ct = 0; ct < 4; ++ct) {
          const int row = ct * 16 + c;
          const int sch = (kh * 4 + g) ^ (row & 7);
          f16x8 kb = *(const f16x8*)(Ks + row * 64 + sch * 8);
          s[ct] = __builtin_amdgcn_mfma_f32_16x16x32_f16(kb, qa[kh], s[ct], 0, 0, 0);
        }
      }
      __builtin_amdgcn_s_setprio(0);

      float mt = s[0][0];
#pragma unroll
      for (int ct = 0; ct < 4; ++ct)
#pragma unroll
        for (int r = 0; r < 4; ++r) mt = fmaxf(mt, s[ct][r]);
      mt = fmaxf(mt, __shfl_xor(mt, 16));
      mt = fmaxf(mt, __shfl_xor(mt, 32));

      if (__ballot(mt > mrun + 8.0f)) {   // defer-max: P bounded by 2^8
        const float mnew = fmaxf(mrun, mt);
        const float corr = fast_exp2(mrun - mnew);
        mrun = mnew;
#pragma unroll
        for (int r = 0; r < 4; ++r) {
          const float co = __shfl(corr, g * 4 + r);
#pragma unroll
          for (int dt = 0; dt < 4; ++dt) o[dt][r] *= co;
          osum[r] *= co;
        }
      }

#pragma unroll
      for (int ct = 0; ct < 4; ++ct) {
        const float p0 = fast_exp2(s[ct][0] - mrun);
        const float p1 = fast_exp2(s[ct][1] - mrun);
        const float p2 = fast_exp2(s[ct][2] - mrun);
        const float p3 = fast_exp2(s[ct][3] - mrun);
        const int sch = (ct * 2 + (g >> 1)) ^ (c & 7);
        *(f16x4*)(prow + c * 64 + sch * 8 + (g & 1) * 4) = pack4(p0, p1, p2, p3);
      }

      __builtin_amdgcn_s_setprio(1);
#pragma unroll
      for (int ks = 0; ks < 2; ++ks) {
        const int sp = (ks * 4 + g) ^ (c & 7);
        f16x8 pa = *(const f16x8*)(prow + c * 64 + sp * 8);
#pragma unroll
        for (int dt = 0; dt < 4; ++dt) {
          const int d = dt * 16 + c;
          f16x8 vb = *(const f16x8*)(Vs + d * 64 + sp * 8);
          o[dt] = __builtin_amdgcn_mfma_f32_16x16x32_f16(pa, vb, o[dt], 0, 0, 0);
        }
        osum = __builtin_amdgcn_mfma_f32_16x16x32_f16(pa, vones, osum, 0, 0, 0);
      }
      __builtin_amdgcn_s_setprio(0);
    } else {
      // -------- tail tile: t0 = 768, only 16 valid KV rows --------
      f32x4 s0 = {};
      __builtin_amdgcn_s_setprio(1);
#pragma unroll
      for (int kh = 0; kh < 2; ++kh) {
        const int sch = (kh * 4 + g) ^ (c & 7);
        f16x8 kb = *(const f16x8*)(Ks + c * 64 + sch * 8);
        s0 = __builtin_amdgcn_mfma_f32_16x16x32_f16(kb, qa[kh], s0, 0, 0, 0);
      }
      __builtin_amdgcn_s_setprio(0);

      float mt = fmaxf(fmaxf(s0[0], s0[1]), fmaxf(s0[2], s0[3]));
      mt = fmaxf(mt, __shfl_xor(mt, 16));
      mt = fmaxf(mt, __shfl_xor(mt, 32));
      if (__ballot(mt > mrun + 8.0f)) {
        const float mnew = fmaxf(mrun, mt);
        const float corr = fast_exp2(mrun - mnew);
        mrun = mnew;
#pragma unroll
        for (int r = 0; r < 4; ++r) {
          const float co = __shfl(corr, g * 4 + r);
#pragma unroll
          for (int dt = 0; dt < 4; ++dt) o[dt][r] *= co;
          osum[r] *= co;
        }
      }

      {
        const float p0 = fast_exp2(s0[0] - mrun);
        const float p1 = fast_exp2(s0[1] - mrun);
        const float p2 = fast_exp2(s0[2] - mrun);
        const float p3 = fast_exp2(s0[3] - mrun);
        const int sch0 = (0 + (g >> 1)) ^ (c & 7);
        *(f16x4*)(prow + c * 64 + sch0 * 8 + (g & 1) * 4) = pack4(p0, p1, p2, p3);
        const int sch1 = (2 + (g >> 1)) ^ (c & 7);
        f16x4 z = {};
        *(f16x4*)(prow + c * 64 + sch1 * 8 + (g & 1) * 4) = z;
      }

      __builtin_amdgcn_s_setprio(1);
      {
        const int sp = g ^ (c & 7);
        f16x8 pa = *(const f16x8*)(prow + c * 64 + sp * 8);
#pragma unroll
        for (int dt = 0; dt < 4; ++dt) {
          const int d = dt * 16 + c;
          f16x8 vb = *(const f16x8*)(Vs + d * 64 + sp * 8);
          o[dt] = __builtin_amdgcn_mfma_f32_16x16x32_f16(pa, vb, o[dt], 0, 0, 0);
        }
        osum = __builtin_amdgcn_mfma_f32_16x16x32_f16(pa, vones, osum, 0, 0, 0);
      }
      __builtin_amdgcn_s_setprio(0);
    }
  }

  // epilogue: osum already in q=g*4+r row layout -> no shuffles
  f16* obase = op + ((size_t)(b * NQ + qt * 64 + wave * 16)) * 384 + h * 64;
#pragma unroll
  for (int r = 0; r < 4; ++r) {
    const float iv = 1.0f / osum[r];
#pragma unroll
    for (int dt = 0; dt < 4; ++dt)
      obase[(size_t)(g * 4 + r) * 384 + dt * 16 + c] = (f16)(o[dt][r] * iv);
  }
}

extern "C" void kernel_launch(void* const* d_in, const int* in_sizes, int n_in,
                              void* d_out, int out_size, void* d_ws, size_t ws_size,
                              hipStream_t stream) {
  const float* inputs_q  = (const float*)d_in[0];
  const float* inputs_kv = (const float*)d_in[1];
  const float* out_kern  = (const float*)d_in[2];
  const float* q_dwk = (const float*)d_in[3];
  const float* q_bs  = (const float*)d_in[4];
  const float* q_bb  = (const float*)d_in[5];
  const float* q_bm  = (const float*)d_in[6];
  const float* q_bv  = (const float*)d_in[7];
  const float* q_pwk = (const float*)d_in[8];
  const float* k_dwk = (const float*)d_in[9];
  const float* k_bs  = (const float*)d_in[10];
  const float* k_bb  = (const float*)d_in[11];
  const float* k_bm  = (const float*)d_in[12];
  const float* k_bv  = (const float*)d_in[13];
  const float* k_pwk = (const float*)d_in[14];
  const float* v_dwk = (const float*)d_in[15];
  const float* v_bs  = (const float*)d_in[16];
  const float* v_bb  = (const float*)d_in[17];
  const float* v_bm  = (const float*)d_in[18];
  const float* v_bv  = (const float*)d_in[19];
  const float* v_pwk = (const float*)d_in[20];

  char* wsb = (char*)d_ws;
  f16* qdw = (f16*)(wsb + 0);             // 25088*384 f16
  f16* kdw = (f16*)(wsb + 19267584);      // 6272*384 f16
  f16* vdw = (f16*)(wsb + 24084480);      // 6272*384 f16
  f16* qf  = (f16*)(wsb + 28901376);      // 25088*384 f16
  f16* kf  = (f16*)(wsb + 48168960);      // 6272*384 f16
  f16* vtp = (f16*)(wsb + 57802752);      // 8*384*784 f16
  f16* of  = (f16*)(wsb + 62619648);      // 25088*384 f16
  f16* wqt = (f16*)(wsb + 81887232);      // 384*384 f16 x4
  f16* wkt = (f16*)(wsb + 82182144);
  f16* wvt = (f16*)(wsb + 82477056);
  f16* wot = (f16*)(wsb + 82771968);

  // 1. fused preprocess: dw+BN (q, k&v) + weight transpose-convert
  preprocess<<<7632, 256, 0, stream>>>(
      inputs_q, inputs_kv,
      q_dwk, q_bs, q_bb, q_bm, q_bv,
      k_dwk, k_bs, k_bb, k_bm, k_bv,
      v_dwk, v_bs, v_bb, v_bm, v_bv,
      q_pwk, k_pwk, v_pwk, out_kern, wqt, wkt, wvt, wot,
      qdw, kdw, vdw);
  // 2. fused q/k/v pointwise GEMMs (V written transposed; q folded with 1/8*log2e)
  gemm_qkv<<<882, 256, 0, stream>>>(qdw, wqt, qf, 0.125f * LOG2E,
                                    kdw, wkt, kf, vdw, wvt, vtp);
  // 3. MFMA attention (KVT=64, XCD-chunked, T14 async-STAGE, specialized tail) -> f16 O
  attn_mfma<<<BB * NHD * 49, 256, 0, stream>>>(qf, kf, vtp, of);
  // 4. output projection (MFMA, fp32 out)
  gemm_mfma<0><<<dim3(196, 3), 256, 0, stream>>>(of, wot, (float*)d_out, nullptr, 1.0f);
}

// Round 17
// 147.238 us; speedup vs baseline: 1.3862x; 1.0105x over previous
//
#include <hip/hip_runtime.h>
#include <hip/hip_bf16.h>
#include <hip/hip_fp16.h>

// Problem constants
#define BB 8
#define HH 56
#define WW 56
#define CC 384
#define NHD 6
#define DD 64
#define HK 28
#define WK 28
#define NQ (HH*WW)       // 3136
#define NKV (HK*WK)      // 784
#define NTOK (BB*NQ)     // 25088
#define NTOKKV (BB*NKV)  // 6272
#define BN_EPS 1e-5f
#define LOG2E 1.44269504f

typedef _Float16 f16;
typedef _Float16 f16x2 __attribute__((ext_vector_type(2)));
typedef _Float16 f16x4 __attribute__((ext_vector_type(4)));
typedef _Float16 f16x8 __attribute__((ext_vector_type(8)));
typedef float f32x4 __attribute__((ext_vector_type(4)));

__device__ __forceinline__ float fast_exp2(float x) {
#if __has_builtin(__builtin_amdgcn_exp2f)
  return __builtin_amdgcn_exp2f(x);   // v_exp_f32 (2^x)
#else
  return __expf(x * 0.69314718056f);
#endif
}

__device__ __forceinline__ f16x4 pack4(float p0, float p1, float p2, float p3) {
#if __has_builtin(__builtin_amdgcn_cvt_pkrtz)
  f16x2 a = __builtin_bit_cast(f16x2, __builtin_amdgcn_cvt_pkrtz(p0, p1));
  f16x2 b = __builtin_bit_cast(f16x2, __builtin_amdgcn_cvt_pkrtz(p2, p3));
  return __builtin_shufflevector(a, b, 0, 1, 2, 3);
#else
  f16x4 r; r[0] = (f16)p0; r[1] = (f16)p1; r[2] = (f16)p2; r[3] = (f16)p3;
  return r;
#endif
}

// ---------------- dw conv + BN bodies (called from fused preprocess) ----------------
__device__ __forceinline__ void dw_s1_body(
    int blk, int tid, const float* __restrict__ in, const float* __restrict__ w,
    const float* __restrict__ bns, const float* __restrict__ bnb,
    const float* __restrict__ bnm, const float* __restrict__ bnv,
    f16* __restrict__ out) {
  int idx = blk * 256 + tid;                     // < (NTOK/2)*96 = 1204224
  int pp = idx / 96;
  int c = (idx % 96) * 4;
  int b = pp / (HH * WK);
  int rem = pp % (HH * WK);
  int y = rem / WK, xh = rem % WK;
  int x0 = xh * 2;
  float a0x = 0, a0y = 0, a0z = 0, a0w = 0;
  float a1x = 0, a1y = 0, a1z = 0, a1w = 0;
#pragma unroll
  for (int kh = 0; kh < 3; ++kh) {
    int iy = y + kh - 1;
    if ((unsigned)iy >= (unsigned)HH) continue;
    const float* rp = in + ((size_t)(b * HH + iy) * WW) * CC + c;
    const float4 z4 = {0.f, 0.f, 0.f, 0.f};
    const float4 v0 = (x0 > 0) ? *(const float4*)(rp + (size_t)(x0 - 1) * CC) : z4;
    const float4 v1 = *(const float4*)(rp + (size_t)x0 * CC);
    const float4 v2 = *(const float4*)(rp + (size_t)(x0 + 1) * CC);
    const float4 v3 = (x0 < 54) ? *(const float4*)(rp + (size_t)(x0 + 2) * CC) : z4;
    const float4 w0 = *(const float4*)(w + (kh * 3 + 0) * CC + c);
    const float4 w1 = *(const float4*)(w + (kh * 3 + 1) * CC + c);
    const float4 w2 = *(const float4*)(w + (kh * 3 + 2) * CC + c);
    a0x = fmaf(v0.x, w0.x, fmaf(v1.x, w1.x, fmaf(v2.x, w2.x, a0x)));
    a0y = fmaf(v0.y, w0.y, fmaf(v1.y, w1.y, fmaf(v2.y, w2.y, a0y)));
    a0z = fmaf(v0.z, w0.z, fmaf(v1.z, w1.z, fmaf(v2.z, w2.z, a0z)));
    a0w = fmaf(v0.w, w0.w, fmaf(v1.w, w1.w, fmaf(v2.w, w2.w, a0w)));
    a1x = fmaf(v1.x, w0.x, fmaf(v2.x, w1.x, fmaf(v3.x, w2.x, a1x)));
    a1y = fmaf(v1.y, w0.y, fmaf(v2.y, w1.y, fmaf(v3.y, w2.y, a1y)));
    a1z = fmaf(v1.z, w0.z, fmaf(v2.z, w1.z, fmaf(v3.z, w2.z, a1z)));
    a1w = fmaf(v1.w, w0.w, fmaf(v2.w, w1.w, fmaf(v3.w, w2.w, a1w)));
  }
  const float4 s = *(const float4*)(bns + c);
  const float4 bi = *(const float4*)(bnb + c);
  const float4 m = *(const float4*)(bnm + c);
  const float4 va = *(const float4*)(bnv + c);
  f16x4 r0, r1;
  float g;
  g = s.x * rsqrtf(va.x + BN_EPS); r0[0] = (f16)fmaf(a0x - m.x, g, bi.x); r1[0] = (f16)fmaf(a1x - m.x, g, bi.x);
  g = s.y * rsqrtf(va.y + BN_EPS); r0[1] = (f16)fmaf(a0y - m.y, g, bi.y); r1[1] = (f16)fmaf(a1y - m.y, g, bi.y);
  g = s.z * rsqrtf(va.z + BN_EPS); r0[2] = (f16)fmaf(a0z - m.z, g, bi.z); r1[2] = (f16)fmaf(a1z - m.z, g, bi.z);
  g = s.w * rsqrtf(va.w + BN_EPS); r0[3] = (f16)fmaf(a0w - m.w, g, bi.w); r1[3] = (f16)fmaf(a1w - m.w, g, bi.w);
  const size_t pix0 = (size_t)b * NQ + y * WW + x0;
  *(f16x4*)(out + pix0 * CC + c) = r0;
  *(f16x4*)(out + (pix0 + 1) * CC + c) = r1;
}

__device__ __forceinline__ void dw_s2_body(
    int blk, int tid, const float* __restrict__ in,
    const float* __restrict__ wk_, const float* __restrict__ kbs, const float* __restrict__ kbb,
    const float* __restrict__ kbm, const float* __restrict__ kbv,
    const float* __restrict__ wv_, const float* __restrict__ vbs, const float* __restrict__ vbb,
    const float* __restrict__ vbm, const float* __restrict__ vbv,
    f16* __restrict__ outk, f16* __restrict__ outv) {
  int idx = blk * 256 + tid;                     // < NTOKKV*96
  int pix = idx / 96;
  int c = (idx % 96) * 4;
  int b = pix / (HK * WK);
  int p = pix % (HK * WK);
  int oy = p / WK, ox = p % WK;
  float kx = 0, ky = 0, kz = 0, kw4 = 0;
  float vx = 0, vy = 0, vz = 0, vw4 = 0;
#pragma unroll
  for (int kh = 0; kh < 3; ++kh) {
    int iy = oy * 2 + kh;
    if (iy >= HH) continue;
#pragma unroll
    for (int kwi = 0; kwi < 3; ++kwi) {
      int ix = ox * 2 + kwi;
      if (ix >= WW) continue;
      const float4 v = *(const float4*)(in + (((size_t)(b * HH + iy) * WW + ix) * CC + c));
      const float4 a = *(const float4*)(wk_ + ((kh * 3 + kwi) * CC + c));
      const float4 bq = *(const float4*)(wv_ + ((kh * 3 + kwi) * CC + c));
      kx = fmaf(v.x, a.x, kx); ky = fmaf(v.y, a.y, ky);
      kz = fmaf(v.z, a.z, kz); kw4 = fmaf(v.w, a.w, kw4);
      vx = fmaf(v.x, bq.x, vx); vy = fmaf(v.y, bq.y, vy);
      vz = fmaf(v.z, bq.z, vz); vw4 = fmaf(v.w, bq.w, vw4);
    }
  }
  {
    const float4 s = *(const float4*)(kbs + c);
    const float4 bi = *(const float4*)(kbb + c);
    const float4 m = *(const float4*)(kbm + c);
    const float4 va = *(const float4*)(kbv + c);
    f16x4 r; float g;
    g = s.x * rsqrtf(va.x + BN_EPS); r[0] = (f16)fmaf(kx - m.x, g, bi.x);
    g = s.y * rsqrtf(va.y + BN_EPS); r[1] = (f16)fmaf(ky - m.y, g, bi.y);
    g = s.z * rsqrtf(va.z + BN_EPS); r[2] = (f16)fmaf(kz - m.z, g, bi.z);
    g = s.w * rsqrtf(va.w + BN_EPS); r[3] = (f16)fmaf(kw4 - m.w, g, bi.w);
    *(f16x4*)(outk + (size_t)pix * CC + c) = r;
  }
  {
    const float4 s = *(const float4*)(vbs + c);
    const float4 bi = *(const float4*)(vbb + c);
    const float4 m = *(const float4*)(vbm + c);
    const float4 va = *(const float4*)(vbv + c);
    f16x4 r; float g;
    g = s.x * rsqrtf(va.x + BN_EPS); r[0] = (f16)fmaf(vx - m.x, g, bi.x);
    g = s.y * rsqrtf(va.y + BN_EPS); r[1] = (f16)fmaf(vy - m.y, g, bi.y);
    g = s.z * rsqrtf(va.z + BN_EPS); r[2] = (f16)fmaf(vz - m.z, g, bi.z);
    g = s.w * rsqrtf(va.w + BN_EPS); r[3] = (f16)fmaf(vw4 - m.w, g, bi.w);
    *(f16x4*)(outv + (size_t)pix * CC + c) = r;
  }
}

// ---- fused preprocess: dw_s1 (4704) + dw_s2_kv (2352) + convert_w (576) ----
// XCD-chunked per segment: default dispatch round-robins blocks across the 8 XCDs,
// so y+-1 row reuse landed on different L2s (45% HBM overfetch). Remap so each XCD
// owns a contiguous pixel span (= exactly one image per XCD per segment).
__global__ __launch_bounds__(256) void preprocess(
    const float* __restrict__ inputs_q, const float* __restrict__ inputs_kv,
    const float* __restrict__ q_dwk, const float* __restrict__ q_bs,
    const float* __restrict__ q_bb, const float* __restrict__ q_bm,
    const float* __restrict__ q_bv,
    const float* __restrict__ k_dwk, const float* __restrict__ k_bs,
    const float* __restrict__ k_bb, const float* __restrict__ k_bm,
    const float* __restrict__ k_bv,
    const float* __restrict__ v_dwk, const float* __restrict__ v_bs,
    const float* __restrict__ v_bb, const float* __restrict__ v_bm,
    const float* __restrict__ v_bv,
    const float* __restrict__ w0, const float* __restrict__ w1,
    const float* __restrict__ w2, const float* __restrict__ w3,
    f16* __restrict__ o0, f16* __restrict__ o1,
    f16* __restrict__ o2, f16* __restrict__ o3,
    f16* __restrict__ qdw, f16* __restrict__ kdw, f16* __restrict__ vdw) {
  __shared__ float t[32][33];
  const int bid = blockIdx.x;
  const int tid = threadIdx.x;
  if (bid < 4704) {
    const int lb = (bid & 7) * 588 + (bid >> 3);        // 4704 = 8*588, bijective
    dw_s1_body(lb, tid, inputs_q, q_dwk, q_bs, q_bb, q_bm, q_bv, qdw);
  } else if (bid < 7056) {
    const int r = bid - 4704;                           // 4704 % 8 == 0 -> (r&7) == XCD
    const int lb = (r & 7) * 294 + (r >> 3);            // 2352 = 8*294, bijective
    dw_s2_body(lb, tid, inputs_kv,
               k_dwk, k_bs, k_bb, k_bm, k_bv,
               v_dwk, v_bs, v_bb, v_bm, v_bv, kdw, vdw);
  } else {
    const int r = bid - 7056;                 // 0..575  (12 x 12 x 4)
    const int z = r / 144, rem = r % 144;
    const int bx = rem % 12, by = rem / 12;
    const float* src = z == 0 ? w0 : z == 1 ? w1 : z == 2 ? w2 : w3;
    f16* dst = z == 0 ? o0 : z == 1 ? o1 : z == 2 ? o2 : o3;
    const int k0 = bx * 32, n0 = by * 32;
    const int x = tid & 31, y = tid >> 5;
#pragma unroll
    for (int i = 0; i < 4; ++i) t[y + i * 8][x] = src[(size_t)(k0 + y + i * 8) * 384 + n0 + x];
    __syncthreads();
#pragma unroll
    for (int i = 0; i < 4; ++i)
      dst[(size_t)(n0 + y + i * 8) * 384 + k0 + x] = (f16)t[x][y + i * 8];
  }
}

// ------------- f16 MFMA GEMM body (128x128 tile, BK=64, 4 waves, 4x4 frags) -------------
// MODE 0: fp32 row-major; MODE 1: f16 row-major; MODE 2: f16 V^T (vtp [b*384+d][784])
template <int MODE>
__device__ __forceinline__ void gemm_body(
    const f16* __restrict__ A, const f16* __restrict__ Bt,
    float* __restrict__ Cf, f16* __restrict__ Ch, float scale,
    int row0, int col0) {
  __shared__ f16 As[128 * 64];   // [row][k], 128 B per row
  __shared__ f16 Bs[128 * 64];   // [col][k], 128 B per col
  const int tid = threadIdx.x;
  const int wave = tid >> 6, lane = tid & 63;
  const int c = lane & 15, g = lane >> 4;
  const int wr = wave >> 1, wc = wave & 1;     // 2x2 waves, each 64x64

  const int s_base = wave * 64 + lane;
  f32x4 acc[4][4] = {};

  for (int k0 = 0; k0 < 384; k0 += 64) {
    __syncthreads();
#pragma unroll
    for (int j = 0; j < 4; ++j) {
      const int s = j * 256 + s_base;
      const int row = s >> 3, sch = s & 7;
      const int lch = sch ^ (row & 7);         // logical k-chunk fetched
      const f16* sa = A + (size_t)(row0 + row) * 384 + k0 + lch * 8;
      __builtin_amdgcn_global_load_lds(
          (const __attribute__((address_space(1))) void*)sa,
          (__attribute__((address_space(3))) void*)(As + j * 2048 + wave * 512), 16, 0, 0);
      const f16* sb = Bt + (size_t)(col0 + row) * 384 + k0 + lch * 8;
      __builtin_amdgcn_global_load_lds(
          (const __attribute__((address_space(1))) void*)sb,
          (__attribute__((address_space(3))) void*)(Bs + j * 2048 + wave * 512), 16, 0, 0);
    }
    __syncthreads();

#pragma unroll
    for (int kh = 0; kh < 2; ++kh) {
      f16x8 bf[4];
#pragma unroll
      for (int n = 0; n < 4; ++n) {
        const int row = wc * 64 + n * 16 + c;
        bf[n] = *(const f16x8*)(Bs + (size_t)row * 64 + ((kh * 4 + g) ^ (row & 7)) * 8);
      }
#pragma unroll
      for (int m = 0; m < 4; ++m) {
        const int row = wr * 64 + m * 16 + c;
        f16x8 af = *(const f16x8*)(As + (size_t)row * 64 + ((kh * 4 + g) ^ (row & 7)) * 8);
#pragma unroll
        for (int n = 0; n < 4; ++n)
          acc[m][n] = __builtin_amdgcn_mfma_f32_16x16x32_f16(af, bf[n], acc[m][n], 0, 0, 0);
      }
    }
  }

  if (MODE == 2) {
#pragma unroll
    for (int m = 0; m < 4; ++m)
#pragma unroll
      for (int n = 0; n < 4; ++n) {
        const int gr = row0 + wr * 64 + m * 16 + g * 4;
        const int col = col0 + wc * 64 + n * 16 + c;
        const int bb = gr / NKV;
        const int kv = gr - bb * NKV;           // 4-pack cannot cross batch (784%4==0, gr%4==0)
        f16x4 pk;
#pragma unroll
        for (int r = 0; r < 4; ++r) pk[r] = (f16)(acc[m][n][r] * scale);
        *(f16x4*)(Ch + ((size_t)bb * 384 + col) * NKV + kv) = pk;
      }
  } else {
#pragma unroll
    for (int m = 0; m < 4; ++m)
#pragma unroll
      for (int n = 0; n < 4; ++n)
#pragma unroll
        for (int r = 0; r < 4; ++r) {
          const size_t row = row0 + wr * 64 + m * 16 + g * 4 + r;
          const size_t col = col0 + wc * 64 + n * 16 + c;
          if (MODE == 1) Ch[row * 384 + col] = (f16)(acc[m][n][r] * scale);
          else           Cf[row * 384 + col] = acc[m][n][r] * scale;
        }
  }
}

// fused q/k/v pointwise GEMMs: 882 flat blocks = q(196x3) + k(49x3) + v(49x3)
__global__ __launch_bounds__(256) void gemm_qkv(
    const f16* __restrict__ qdw, const f16* __restrict__ wqt, f16* __restrict__ qf, float qscale,
    const f16* __restrict__ kdw, const f16* __restrict__ wkt, f16* __restrict__ kf,
    const f16* __restrict__ vdw, const f16* __restrict__ wvt, f16* __restrict__ vtp) {
  const int blk = blockIdx.x;
  if (blk < 588) {
    gemm_body<1>(qdw, wqt, nullptr, qf, qscale, (blk % 196) * 128, (blk / 196) * 128);
  } else if (blk < 735) {
    const int r = blk - 588;
    gemm_body<1>(kdw, wkt, nullptr, kf, 1.0f, (r % 49) * 128, (r / 49) * 128);
  } else {
    const int r = blk - 735;
    gemm_body<2>(vdw, wvt, nullptr, vtp, 1.0f, (r % 49) * 128, (r / 49) * 128);
  }
}

template <int MODE>
__global__ __launch_bounds__(256) void gemm_mfma(
    const f16* __restrict__ A, const f16* __restrict__ Bt,
    float* __restrict__ Cf, f16* __restrict__ Ch, float scale) {
  gemm_body<MODE>(A, Bt, Cf, Ch, scale, blockIdx.x * 128, blockIdx.y * 128);
}

// ------------- f16 MFMA flash attention, swapped-QK^T, KVT=64, XCD-chunked, T14 -------------
// grid = 2352; lb = (bid&7)*294 + (bid>>3): each XCD owns 6 complete (b,h) pairs.
// T14 async-STAGE: K/V loaded into REGISTERS during previous tile's compute;
// after barrier only ds_write_b128 x4 + barrier. 12 full tiles + specialized tail.
__global__ __launch_bounds__(256) void attn_mfma(
    const f16* __restrict__ qp, const f16* __restrict__ kp,
    const f16* __restrict__ vt, f16* __restrict__ op) {
  __shared__ f16 Ks[64 * 64];      // [kv][d], chunk ch at ch^(kv&7)
  __shared__ f16 Vs[64 * 64];      // [d][kv], chunk ch at ch^(d&7)
  __shared__ f16 Ps[4][16 * 64];   // per-wave [q][kv], ch^(q&7)
  const int bid0 = blockIdx.x;
  const int lb = (bid0 & 7) * 294 + (bid0 >> 3);   // bijective (2352 = 8*294)
  const int qt = lb % 49;
  const int bh = lb / 49;
  const int h = bh % NHD, b = bh / NHD;
  const int tid = threadIdx.x;
  const int wave = tid >> 6, lane = tid & 63;
  const int c = lane & 15, g = lane >> 4;

  const size_t qrow = (size_t)b * NQ + qt * 64 + wave * 16 + c;
  f16x8 qa[2];
  qa[0] = *(const f16x8*)(qp + qrow * 384 + h * 64 + g * 8);
  qa[1] = *(const f16x8*)(qp + qrow * 384 + h * 64 + 32 + g * 8);

  f16x8 vones;
#pragma unroll
  for (int j = 0; j < 8; ++j) vones[j] = (f16)1.0f;

  const int tid8 = tid >> 3, tch = tid & 7;
  const int lch = tch ^ (tid8 & 7);            // logical chunk fetched

  const f16* kbase = kp + ((size_t)b * NKV) * 384 + h * 64;
  const f16* vbase = vt + ((size_t)(b * 384 + h * 64)) * NKV;

  float mrun = -1e30f;                // for q = c (redundant across g)
  f32x4 o[4] = {};                    // O[q=g*4+r][d=dt*16+c]
  f32x4 osum = {};                    // lsum[q=g*4+r]
  f16* prow = &Ps[wave][0];

  // T14 staging registers + preload tile 0 (all indices in-bounds at t0=0)
  f16x8 kr0, kr1, vr0, vr1;
  kr0 = *(const f16x8*)(kbase + (size_t)tid8 * 384 + lch * 8);
  kr1 = *(const f16x8*)(kbase + (size_t)(32 + tid8) * 384 + lch * 8);
  vr0 = *(const f16x8*)(vbase + (size_t)tid8 * NKV + lch * 8);
  vr1 = *(const f16x8*)(vbase + (size_t)(32 + tid8) * NKV + lch * 8);

  for (int ti = 0; ti < 13; ++ti) {
    __syncthreads();                  // all waves done reading LDS (prev tile)
    *(f16x8*)(Ks + tid * 8) = kr0;
    *(f16x8*)(Ks + 2048 + tid * 8) = kr1;
    *(f16x8*)(Vs + tid * 8) = vr0;
    *(f16x8*)(Vs + 2048 + tid * 8) = vr1;
    if (ti + 1 < 13) {
      const int t0n = (ti + 1) * 64;
      int kvA = t0n + tid8;        if (kvA > NKV - 1) kvA = NKV - 1;
      int kvB = t0n + 32 + tid8;   if (kvB > NKV - 1) kvB = NKV - 1;
      int colc = t0n + lch * 8;    if (colc > NKV - 8) colc = NKV - 8;
      kr0 = *(const f16x8*)(kbase + (size_t)kvA * 384 + lch * 8);
      kr1 = *(const f16x8*)(kbase + (size_t)kvB * 384 + lch * 8);
      vr0 = *(const f16x8*)(vbase + (size_t)tid8 * NKV + colc);
      vr1 = *(const f16x8*)(vbase + (size_t)(32 + tid8) * NKV + colc);
    }
    __syncthreads();                  // LDS writes visible to all waves

    if (ti < 12) {
      // -------- full tile --------
      f32x4 s[4] = {};
      __builtin_amdgcn_s_setprio(1);
#pragma unroll
      for (int kh = 0; kh < 2; ++kh) {
#pragma unroll
        for (int ct = 0; ct < 4; ++ct) {
          const int row = ct * 16 + c;
          const int sch = (kh * 4 + g) ^ (row & 7);
          f16x8 kb = *(const f16x8*)(Ks + row * 64 + sch * 8);
          s[ct] = __builtin_amdgcn_mfma_f32_16x16x32_f16(kb, qa[kh], s[ct], 0, 0, 0);
        }
      }
      __builtin_amdgcn_s_setprio(0);

      float mt = s[0][0];
#pragma unroll
      for (int ct = 0; ct < 4; ++ct)
#pragma unroll
        for (int r = 0; r < 4; ++r) mt = fmaxf(mt, s[ct][r]);
      mt = fmaxf(mt, __shfl_xor(mt, 16));
      mt = fmaxf(mt, __shfl_xor(mt, 32));

      if (__ballot(mt > mrun + 8.0f)) {   // defer-max: P bounded by 2^8
        const float mnew = fmaxf(mrun, mt);
        const float corr = fast_exp2(mrun - mnew);
        mrun = mnew;
#pragma unroll
        for (int r = 0; r < 4; ++r) {
          const float co = __shfl(corr, g * 4 + r);
#pragma unroll
          for (int dt = 0; dt < 4; ++dt) o[dt][r] *= co;
          osum[r] *= co;
        }
      }

#pragma unroll
      for (int ct = 0; ct < 4; ++ct) {
        const float p0 = fast_exp2(s[ct][0] - mrun);
        const float p1 = fast_exp2(s[ct][1] - mrun);
        const float p2 = fast_exp2(s[ct][2] - mrun);
        const float p3 = fast_exp2(s[ct][3] - mrun);
        const int sch = (ct * 2 + (g >> 1)) ^ (c & 7);
        *(f16x4*)(prow + c * 64 + sch * 8 + (g & 1) * 4) = pack4(p0, p1, p2, p3);
      }

      __builtin_amdgcn_s_setprio(1);
#pragma unroll
      for (int ks = 0; ks < 2; ++ks) {
        const int sp = (ks * 4 + g) ^ (c & 7);
        f16x8 pa = *(const f16x8*)(prow + c * 64 + sp * 8);
#pragma unroll
        for (int dt = 0; dt < 4; ++dt) {
          const int d = dt * 16 + c;
          f16x8 vb = *(const f16x8*)(Vs + d * 64 + sp * 8);
          o[dt] = __builtin_amdgcn_mfma_f32_16x16x32_f16(pa, vb, o[dt], 0, 0, 0);
        }
        osum = __builtin_amdgcn_mfma_f32_16x16x32_f16(pa, vones, osum, 0, 0, 0);
      }
      __builtin_amdgcn_s_setprio(0);
    } else {
      // -------- tail tile: t0 = 768, only 16 valid KV rows --------
      f32x4 s0 = {};
      __builtin_amdgcn_s_setprio(1);
#pragma unroll
      for (int kh = 0; kh < 2; ++kh) {
        const int sch = (kh * 4 + g) ^ (c & 7);
        f16x8 kb = *(const f16x8*)(Ks + c * 64 + sch * 8);
        s0 = __builtin_amdgcn_mfma_f32_16x16x32_f16(kb, qa[kh], s0, 0, 0, 0);
      }
      __builtin_amdgcn_s_setprio(0);

      float mt = fmaxf(fmaxf(s0[0], s0[1]), fmaxf(s0[2], s0[3]));
      mt = fmaxf(mt, __shfl_xor(mt, 16));
      mt = fmaxf(mt, __shfl_xor(mt, 32));
      if (__ballot(mt > mrun + 8.0f)) {
        const float mnew = fmaxf(mrun, mt);
        const float corr = fast_exp2(mrun - mnew);
        mrun = mnew;
#pragma unroll
        for (int r = 0; r < 4; ++r) {
          const float co = __shfl(corr, g * 4 + r);
#pragma unroll
          for (int dt = 0; dt < 4; ++dt) o[dt][r] *= co;
          osum[r] *= co;
        }
      }

      {
        const float p0 = fast_exp2(s0[0] - mrun);
        const float p1 = fast_exp2(s0[1] - mrun);
        const float p2 = fast_exp2(s0[2] - mrun);
        const float p3 = fast_exp2(s0[3] - mrun);
        const int sch0 = (0 + (g >> 1)) ^ (c & 7);
        *(f16x4*)(prow + c * 64 + sch0 * 8 + (g & 1) * 4) = pack4(p0, p1, p2, p3);
        const int sch1 = (2 + (g >> 1)) ^ (c & 7);
        f16x4 z = {};
        *(f16x4*)(prow + c * 64 + sch1 * 8 + (g & 1) * 4) = z;
      }

      __builtin_amdgcn_s_setprio(1);
      {
        const int sp = g ^ (c & 7);
        f16x8 pa = *(const f16x8*)(prow + c * 64 + sp * 8);
#pragma unroll
        for (int dt = 0; dt < 4; ++dt) {
          const int d = dt * 16 + c;
          f16x8 vb = *(const f16x8*)(Vs + d * 64 + sp * 8);
          o[dt] = __builtin_amdgcn_mfma_f32_16x16x32_f16(pa, vb, o[dt], 0, 0, 0);
        }
        osum = __builtin_amdgcn_mfma_f32_16x16x32_f16(pa, vones, osum, 0, 0, 0);
      }
      __builtin_amdgcn_s_setprio(0);
    }
  }

  // epilogue: osum already in q=g*4+r row layout -> no shuffles
  f16* obase = op + ((size_t)(b * NQ + qt * 64 + wave * 16)) * 384 + h * 64;
#pragma unroll
  for (int r = 0; r < 4; ++r) {
    const float iv = 1.0f / osum[r];
#pragma unroll
    for (int dt = 0; dt < 4; ++dt)
      obase[(size_t)(g * 4 + r) * 384 + dt * 16 + c] = (f16)(o[dt][r] * iv);
  }
}

extern "C" void kernel_launch(void* const* d_in, const int* in_sizes, int n_in,
                              void* d_out, int out_size, void* d_ws, size_t ws_size,
                              hipStream_t stream) {
  const float* inputs_q  = (const float*)d_in[0];
  const float* inputs_kv = (const float*)d_in[1];
  const float* out_kern  = (const float*)d_in[2];
  const float* q_dwk = (const float*)d_in[3];
  const float* q_bs  = (const float*)d_in[4];
  const float* q_bb  = (const float*)d_in[5];
  const float* q_bm  = (const float*)d_in[6];
  const float* q_bv  = (const float*)d_in[7];
  const float* q_pwk = (const float*)d_in[8];
  const float* k_dwk = (const float*)d_in[9];
  const float* k_bs  = (const float*)d_in[10];
  const float* k_bb  = (const float*)d_in[11];
  const float* k_bm  = (const float*)d_in[12];
  const float* k_bv  = (const float*)d_in[13];
  const float* k_pwk = (const float*)d_in[14];
  const float* v_dwk = (const float*)d_in[15];
  const float* v_bs  = (const float*)d_in[16];
  const float* v_bb  = (const float*)d_in[17];
  const float* v_bm  = (const float*)d_in[18];
  const float* v_bv  = (const float*)d_in[19];
  const float* v_pwk = (const float*)d_in[20];

  char* wsb = (char*)d_ws;
  f16* qdw = (f16*)(wsb + 0);             // 25088*384 f16
  f16* kdw = (f16*)(wsb + 19267584);      // 6272*384 f16
  f16* vdw = (f16*)(wsb + 24084480);      // 6272*384 f16
  f16* qf  = (f16*)(wsb + 28901376);      // 25088*384 f16
  f16* kf  = (f16*)(wsb + 48168960);      // 6272*384 f16
  f16* vtp = (f16*)(wsb + 57802752);      // 8*384*784 f16
  f16* of  = (f16*)(wsb + 62619648);      // 25088*384 f16
  f16* wqt = (f16*)(wsb + 81887232);      // 384*384 f16 x4
  f16* wkt = (f16*)(wsb + 82182144);
  f16* wvt = (f16*)(wsb + 82477056);
  f16* wot = (f16*)(wsb + 82771968);

  // 1. fused preprocess (XCD-chunked segments)
  preprocess<<<7632, 256, 0, stream>>>(
      inputs_q, inputs_kv,
      q_dwk, q_bs, q_bb, q_bm, q_bv,
      k_dwk, k_bs, k_bb, k_bm, k_bv,
      v_dwk, v_bs, v_bb, v_bm, v_bv,
      q_pwk, k_pwk, v_pwk, out_kern, wqt, wkt, wvt, wot,
      qdw, kdw, vdw);
  // 2. fused q/k/v pointwise GEMMs (V written transposed; q folded with 1/8*log2e)
  gemm_qkv<<<882, 256, 0, stream>>>(qdw, wqt, qf, 0.125f * LOG2E,
                                    kdw, wkt, kf, vdw, wvt, vtp);
  // 3. MFMA attention (KVT=64, XCD-chunked, T14 async-STAGE, specialized tail) -> f16 O
  attn_mfma<<<BB * NHD * 49, 256, 0, stream>>>(qf, kf, vtp, of);
  // 4. output projection (MFMA, fp32 out)
  gemm_mfma<0><<<dim3(196, 3), 256, 0, stream>>>(of, wot, (float*)d_out, nullptr, 1.0f);
}

// Round 18
// 137.287 us; speedup vs baseline: 1.4867x; 1.0725x over previous
//
#include <hip/hip_runtime.h>
#include <hip/hip_bf16.h>
#include <hip/hip_fp16.h>

// Problem constants
#define BB 8
#define HH 56
#define WW 56
#define CC 384
#define NHD 6
#define DD 64
#define HK 28
#define WK 28
#define NQ (HH*WW)       // 3136
#define NKV (HK*WK)      // 784
#define NTOK (BB*NQ)     // 25088
#define NTOKKV (BB*NKV)  // 6272
#define BN_EPS 1e-5f
#define LOG2E 1.44269504f

typedef _Float16 f16;
typedef _Float16 f16x2 __attribute__((ext_vector_type(2)));
typedef _Float16 f16x4 __attribute__((ext_vector_type(4)));
typedef _Float16 f16x8 __attribute__((ext_vector_type(8)));
typedef float f32x4 __attribute__((ext_vector_type(4)));

__device__ __forceinline__ float fast_exp2(float x) {
#if __has_builtin(__builtin_amdgcn_exp2f)
  return __builtin_amdgcn_exp2f(x);   // v_exp_f32 (2^x)
#else
  return __expf(x * 0.69314718056f);
#endif
}

__device__ __forceinline__ f16x4 pack4(float p0, float p1, float p2, float p3) {
#if __has_builtin(__builtin_amdgcn_cvt_pkrtz)
  f16x2 a = __builtin_bit_cast(f16x2, __builtin_amdgcn_cvt_pkrtz(p0, p1));
  f16x2 b = __builtin_bit_cast(f16x2, __builtin_amdgcn_cvt_pkrtz(p2, p3));
  return __builtin_shufflevector(a, b, 0, 1, 2, 3);
#else
  f16x4 r; r[0] = (f16)p0; r[1] = (f16)p1; r[2] = (f16)p2; r[3] = (f16)p3;
  return r;
#endif
}

// ---------------- dw conv + BN bodies (high-ILP: all loads hoisted) ----------------
// dw_s1: 2x2 output quad per thread. 16 input float4 + 9 weight float4 up-front.
__device__ __forceinline__ void dw_s1_body(
    int blk, int tid, const float* __restrict__ in, const float* __restrict__ w,
    const float* __restrict__ bns, const float* __restrict__ bnb,
    const float* __restrict__ bnm, const float* __restrict__ bnv,
    f16* __restrict__ out) {
  int idx = blk * 256 + tid;                     // < 602112 = (NTOK/4)*96
  int pp = idx / 96;
  int c = (idx % 96) * 4;
  int b = pp / 784;                              // 28*28 quads per image
  int rem = pp % 784;
  int yh = rem / 28, xh = rem % 28;
  int y0 = yh * 2, x0 = xh * 2;
  const float4 z4 = {0.f, 0.f, 0.f, 0.f};

  float4 V[4][4];
#pragma unroll
  for (int ry = 0; ry < 4; ++ry) {
    const int iy = y0 - 1 + ry;
    const bool vy = (unsigned)iy < (unsigned)HH;
    const float* rp = in + ((size_t)(b * HH + (vy ? iy : 0)) * WW) * CC + c;
    V[ry][0] = (vy && x0 > 0)      ? *(const float4*)(rp + (size_t)(x0 - 1) * CC) : z4;
    V[ry][1] = vy                  ? *(const float4*)(rp + (size_t)x0 * CC)       : z4;
    V[ry][2] = vy                  ? *(const float4*)(rp + (size_t)(x0 + 1) * CC) : z4;
    V[ry][3] = (vy && x0 < WW - 2) ? *(const float4*)(rp + (size_t)(x0 + 2) * CC) : z4;
  }
  float4 W[9];
#pragma unroll
  for (int i = 0; i < 9; ++i) W[i] = *(const float4*)(w + i * CC + c);

  const float4 s = *(const float4*)(bns + c);
  const float4 bi = *(const float4*)(bnb + c);
  const float4 m = *(const float4*)(bnm + c);
  const float4 va = *(const float4*)(bnv + c);
  const float gx = s.x * rsqrtf(va.x + BN_EPS);
  const float gy = s.y * rsqrtf(va.y + BN_EPS);
  const float gz = s.z * rsqrtf(va.z + BN_EPS);
  const float gw = s.w * rsqrtf(va.w + BN_EPS);

#pragma unroll
  for (int dy = 0; dy < 2; ++dy)
#pragma unroll
    for (int dx = 0; dx < 2; ++dx) {
      float ax = 0.f, ay = 0.f, az = 0.f, aw = 0.f;
#pragma unroll
      for (int ky = 0; ky < 3; ++ky)
#pragma unroll
        for (int kx = 0; kx < 3; ++kx) {
          const float4 v = V[dy + ky][dx + kx];
          const float4 wk = W[ky * 3 + kx];
          ax = fmaf(v.x, wk.x, ax); ay = fmaf(v.y, wk.y, ay);
          az = fmaf(v.z, wk.z, az); aw = fmaf(v.w, wk.w, aw);
        }
      f16x4 r;
      r[0] = (f16)fmaf(ax - m.x, gx, bi.x);
      r[1] = (f16)fmaf(ay - m.y, gy, bi.y);
      r[2] = (f16)fmaf(az - m.z, gz, bi.z);
      r[3] = (f16)fmaf(aw - m.w, gw, bi.w);
      const size_t pix = (size_t)b * NQ + (size_t)(y0 + dy) * WW + (x0 + dx);
      *(f16x4*)(out + pix * CC + c) = r;
    }
}

// dw_s2 (stride 2): 2 adjacent output pixels per thread; 15 input float4 shared
// between both outputs AND both (k,v) weight sets.
__device__ __forceinline__ void dw_s2_body(
    int blk, int tid, const float* __restrict__ in,
    const float* __restrict__ wk_, const float* __restrict__ kbs, const float* __restrict__ kbb,
    const float* __restrict__ kbm, const float* __restrict__ kbv,
    const float* __restrict__ wv_, const float* __restrict__ vbs, const float* __restrict__ vbb,
    const float* __restrict__ vbm, const float* __restrict__ vbv,
    f16* __restrict__ outk, f16* __restrict__ outv) {
  int idx = blk * 256 + tid;                     // < 301056 = (NTOKKV/2)*96
  int pp = idx / 96;
  int c = (idx % 96) * 4;
  int b = pp / 392;                              // 28*14 pairs per image
  int rem = pp % 392;
  int oy = rem / 14, xh = rem % 14;
  int ox0 = xh * 2;
  int iy0 = oy * 2, ix0 = ox0 * 2;
  const float4 z4 = {0.f, 0.f, 0.f, 0.f};

  float4 V[3][5];
#pragma unroll
  for (int ry = 0; ry < 3; ++ry) {
    const int iy = iy0 + ry;
    const bool vy = iy < HH;                     // fails only ry=2, oy=27
    const float* rp = in + ((size_t)(b * HH + (vy ? iy : 0)) * WW) * CC + c;
#pragma unroll
    for (int cx = 0; cx < 5; ++cx) {
      const int ix = ix0 + cx;
      V[ry][cx] = (vy && ix < WW) ? *(const float4*)(rp + (size_t)ix * CC) : z4;
    }
  }

  // ---- k path ----
  {
    float4 W[9];
#pragma unroll
    for (int i = 0; i < 9; ++i) W[i] = *(const float4*)(wk_ + i * CC + c);
    const float4 s = *(const float4*)(kbs + c);
    const float4 bi = *(const float4*)(kbb + c);
    const float4 m = *(const float4*)(kbm + c);
    const float4 va = *(const float4*)(kbv + c);
    const float gx = s.x * rsqrtf(va.x + BN_EPS);
    const float gy = s.y * rsqrtf(va.y + BN_EPS);
    const float gz = s.z * rsqrtf(va.z + BN_EPS);
    const float gw = s.w * rsqrtf(va.w + BN_EPS);
#pragma unroll
    for (int dx = 0; dx < 2; ++dx) {
      float ax = 0.f, ay = 0.f, az = 0.f, aw = 0.f;
#pragma unroll
      for (int ky = 0; ky < 3; ++ky)
#pragma unroll
        for (int kx = 0; kx < 3; ++kx) {
          const float4 v = V[ky][2 * dx + kx];
          const float4 wk = W[ky * 3 + kx];
          ax = fmaf(v.x, wk.x, ax); ay = fmaf(v.y, wk.y, ay);
          az = fmaf(v.z, wk.z, az); aw = fmaf(v.w, wk.w, aw);
        }
      f16x4 r;
      r[0] = (f16)fmaf(ax - m.x, gx, bi.x);
      r[1] = (f16)fmaf(ay - m.y, gy, bi.y);
      r[2] = (f16)fmaf(az - m.z, gz, bi.z);
      r[3] = (f16)fmaf(aw - m.w, gw, bi.w);
      const size_t pix = (size_t)b * NKV + (size_t)oy * WK + (ox0 + dx);
      *(f16x4*)(outk + pix * CC + c) = r;
    }
  }
  // ---- v path (reuses V) ----
  {
    float4 W[9];
#pragma unroll
    for (int i = 0; i < 9; ++i) W[i] = *(const float4*)(wv_ + i * CC + c);
    const float4 s = *(const float4*)(vbs + c);
    const float4 bi = *(const float4*)(vbb + c);
    const float4 m = *(const float4*)(vbm + c);
    const float4 va = *(const float4*)(vbv + c);
    const float gx = s.x * rsqrtf(va.x + BN_EPS);
    const float gy = s.y * rsqrtf(va.y + BN_EPS);
    const float gz = s.z * rsqrtf(va.z + BN_EPS);
    const float gw = s.w * rsqrtf(va.w + BN_EPS);
#pragma unroll
    for (int dx = 0; dx < 2; ++dx) {
      float ax = 0.f, ay = 0.f, az = 0.f, aw = 0.f;
#pragma unroll
      for (int ky = 0; ky < 3; ++ky)
#pragma unroll
        for (int kx = 0; kx < 3; ++kx) {
          const float4 v = V[ky][2 * dx + kx];
          const float4 wk = W[ky * 3 + kx];
          ax = fmaf(v.x, wk.x, ax); ay = fmaf(v.y, wk.y, ay);
          az = fmaf(v.z, wk.z, az); aw = fmaf(v.w, wk.w, aw);
        }
      f16x4 r;
      r[0] = (f16)fmaf(ax - m.x, gx, bi.x);
      r[1] = (f16)fmaf(ay - m.y, gy, bi.y);
      r[2] = (f16)fmaf(az - m.z, gz, bi.z);
      r[3] = (f16)fmaf(aw - m.w, gw, bi.w);
      const size_t pix = (size_t)b * NKV + (size_t)oy * WK + (ox0 + dx);
      *(f16x4*)(outv + pix * CC + c) = r;
    }
  }
}

// ---- fused preprocess: dw_s1 (2352) + dw_s2_kv (1176) + convert_w (576) ----
// Segments XCD-chunked (contiguous image span per XCD).
__global__ __launch_bounds__(256) void preprocess(
    const float* __restrict__ inputs_q, const float* __restrict__ inputs_kv,
    const float* __restrict__ q_dwk, const float* __restrict__ q_bs,
    const float* __restrict__ q_bb, const float* __restrict__ q_bm,
    const float* __restrict__ q_bv,
    const float* __restrict__ k_dwk, const float* __restrict__ k_bs,
    const float* __restrict__ k_bb, const float* __restrict__ k_bm,
    const float* __restrict__ k_bv,
    const float* __restrict__ v_dwk, const float* __restrict__ v_bs,
    const float* __restrict__ v_bb, const float* __restrict__ v_bm,
    const float* __restrict__ v_bv,
    const float* __restrict__ w0, const float* __restrict__ w1,
    const float* __restrict__ w2, const float* __restrict__ w3,
    f16* __restrict__ o0, f16* __restrict__ o1,
    f16* __restrict__ o2, f16* __restrict__ o3,
    f16* __restrict__ qdw, f16* __restrict__ kdw, f16* __restrict__ vdw) {
  __shared__ float t[32][33];
  const int bid = blockIdx.x;
  const int tid = threadIdx.x;
  if (bid < 2352) {
    const int lb = (bid & 7) * 294 + (bid >> 3);        // 2352 = 8*294, bijective
    dw_s1_body(lb, tid, inputs_q, q_dwk, q_bs, q_bb, q_bm, q_bv, qdw);
  } else if (bid < 3528) {
    const int r = bid - 2352;                           // 1176 = 8*147
    const int lb = (r & 7) * 147 + (r >> 3);
    dw_s2_body(lb, tid, inputs_kv,
               k_dwk, k_bs, k_bb, k_bm, k_bv,
               v_dwk, v_bs, v_bb, v_bm, v_bv, kdw, vdw);
  } else {
    const int r = bid - 3528;                 // 0..575  (12 x 12 x 4)
    const int z = r / 144, rem = r % 144;
    const int bx = rem % 12, by = rem / 12;
    const float* src = z == 0 ? w0 : z == 1 ? w1 : z == 2 ? w2 : w3;
    f16* dst = z == 0 ? o0 : z == 1 ? o1 : z == 2 ? o2 : o3;
    const int k0 = bx * 32, n0 = by * 32;
    const int x = tid & 31, y = tid >> 5;
#pragma unroll
    for (int i = 0; i < 4; ++i) t[y + i * 8][x] = src[(size_t)(k0 + y + i * 8) * 384 + n0 + x];
    __syncthreads();
#pragma unroll
    for (int i = 0; i < 4; ++i)
      dst[(size_t)(n0 + y + i * 8) * 384 + k0 + x] = (f16)t[x][y + i * 8];
  }
}

// ------------- f16 MFMA GEMM body (128x128 tile, BK=64, 4 waves, 4x4 frags) -------------
// MODE 0: fp32 row-major; MODE 1: f16 row-major; MODE 2: f16 V^T (vtp [b*384+d][784])
template <int MODE>
__device__ __forceinline__ void gemm_body(
    const f16* __restrict__ A, const f16* __restrict__ Bt,
    float* __restrict__ Cf, f16* __restrict__ Ch, float scale,
    int row0, int col0) {
  __shared__ f16 As[128 * 64];   // [row][k], 128 B per row
  __shared__ f16 Bs[128 * 64];   // [col][k], 128 B per col
  const int tid = threadIdx.x;
  const int wave = tid >> 6, lane = tid & 63;
  const int c = lane & 15, g = lane >> 4;
  const int wr = wave >> 1, wc = wave & 1;     // 2x2 waves, each 64x64

  const int s_base = wave * 64 + lane;
  f32x4 acc[4][4] = {};

  for (int k0 = 0; k0 < 384; k0 += 64) {
    __syncthreads();
#pragma unroll
    for (int j = 0; j < 4; ++j) {
      const int s = j * 256 + s_base;
      const int row = s >> 3, sch = s & 7;
      const int lch = sch ^ (row & 7);         // logical k-chunk fetched
      const f16* sa = A + (size_t)(row0 + row) * 384 + k0 + lch * 8;
      __builtin_amdgcn_global_load_lds(
          (const __attribute__((address_space(1))) void*)sa,
          (__attribute__((address_space(3))) void*)(As + j * 2048 + wave * 512), 16, 0, 0);
      const f16* sb = Bt + (size_t)(col0 + row) * 384 + k0 + lch * 8;
      __builtin_amdgcn_global_load_lds(
          (const __attribute__((address_space(1))) void*)sb,
          (__attribute__((address_space(3))) void*)(Bs + j * 2048 + wave * 512), 16, 0, 0);
    }
    __syncthreads();

#pragma unroll
    for (int kh = 0; kh < 2; ++kh) {
      f16x8 bf[4];
#pragma unroll
      for (int n = 0; n < 4; ++n) {
        const int row = wc * 64 + n * 16 + c;
        bf[n] = *(const f16x8*)(Bs + (size_t)row * 64 + ((kh * 4 + g) ^ (row & 7)) * 8);
      }
#pragma unroll
      for (int m = 0; m < 4; ++m) {
        const int row = wr * 64 + m * 16 + c;
        f16x8 af = *(const f16x8*)(As + (size_t)row * 64 + ((kh * 4 + g) ^ (row & 7)) * 8);
#pragma unroll
        for (int n = 0; n < 4; ++n)
          acc[m][n] = __builtin_amdgcn_mfma_f32_16x16x32_f16(af, bf[n], acc[m][n], 0, 0, 0);
      }
    }
  }

  if (MODE == 2) {
#pragma unroll
    for (int m = 0; m < 4; ++m)
#pragma unroll
      for (int n = 0; n < 4; ++n) {
        const int gr = row0 + wr * 64 + m * 16 + g * 4;
        const int col = col0 + wc * 64 + n * 16 + c;
        const int bb = gr / NKV;
        const int kv = gr - bb * NKV;           // 4-pack cannot cross batch (784%4==0, gr%4==0)
        f16x4 pk;
#pragma unroll
        for (int r = 0; r < 4; ++r) pk[r] = (f16)(acc[m][n][r] * scale);
        *(f16x4*)(Ch + ((size_t)bb * 384 + col) * NKV + kv) = pk;
      }
  } else {
#pragma unroll
    for (int m = 0; m < 4; ++m)
#pragma unroll
      for (int n = 0; n < 4; ++n)
#pragma unroll
        for (int r = 0; r < 4; ++r) {
          const size_t row = row0 + wr * 64 + m * 16 + g * 4 + r;
          const size_t col = col0 + wc * 64 + n * 16 + c;
          if (MODE == 1) Ch[row * 384 + col] = (f16)(acc[m][n][r] * scale);
          else           Cf[row * 384 + col] = acc[m][n][r] * scale;
        }
  }
}

// fused q/k/v pointwise GEMMs: 882 flat blocks = q(196x3) + k(49x3) + v(49x3)
__global__ __launch_bounds__(256) void gemm_qkv(
    const f16* __restrict__ qdw, const f16* __restrict__ wqt, f16* __restrict__ qf, float qscale,
    const f16* __restrict__ kdw, const f16* __restrict__ wkt, f16* __restrict__ kf,
    const f16* __restrict__ vdw, const f16* __restrict__ wvt, f16* __restrict__ vtp) {
  const int blk = blockIdx.x;
  if (blk < 588) {
    gemm_body<1>(qdw, wqt, nullptr, qf, qscale, (blk % 196) * 128, (blk / 196) * 128);
  } else if (blk < 735) {
    const int r = blk - 588;
    gemm_body<1>(kdw, wkt, nullptr, kf, 1.0f, (r % 49) * 128, (r / 49) * 128);
  } else {
    const int r = blk - 735;
    gemm_body<2>(vdw, wvt, nullptr, vtp, 1.0f, (r % 49) * 128, (r / 49) * 128);
  }
}

template <int MODE>
__global__ __launch_bounds__(256) void gemm_mfma(
    const f16* __restrict__ A, const f16* __restrict__ Bt,
    float* __restrict__ Cf, f16* __restrict__ Ch, float scale) {
  gemm_body<MODE>(A, Bt, Cf, Ch, scale, blockIdx.x * 128, blockIdx.y * 128);
}

// ------------- f16 MFMA flash attention, swapped-QK^T, KVT=64, XCD-chunked, T14 -------------
__global__ __launch_bounds__(256) void attn_mfma(
    const f16* __restrict__ qp, const f16* __restrict__ kp,
    const f16* __restrict__ vt, f16* __restrict__ op) {
  __shared__ f16 Ks[64 * 64];      // [kv][d], chunk ch at ch^(kv&7)
  __shared__ f16 Vs[64 * 64];      // [d][kv], chunk ch at ch^(d&7)
  __shared__ f16 Ps[4][16 * 64];   // per-wave [q][kv], ch^(q&7)
  const int bid0 = blockIdx.x;
  const int lb = (bid0 & 7) * 294 + (bid0 >> 3);   // bijective (2352 = 8*294)
  const int qt = lb % 49;
  const int bh = lb / 49;
  const int h = bh % NHD, b = bh / NHD;
  const int tid = threadIdx.x;
  const int wave = tid >> 6, lane = tid & 63;
  const int c = lane & 15, g = lane >> 4;

  const size_t qrow = (size_t)b * NQ + qt * 64 + wave * 16 + c;
  f16x8 qa[2];
  qa[0] = *(const f16x8*)(qp + qrow * 384 + h * 64 + g * 8);
  qa[1] = *(const f16x8*)(qp + qrow * 384 + h * 64 + 32 + g * 8);

  f16x8 vones;
#pragma unroll
  for (int j = 0; j < 8; ++j) vones[j] = (f16)1.0f;

  const int tid8 = tid >> 3, tch = tid & 7;
  const int lch = tch ^ (tid8 & 7);            // logical chunk fetched

  const f16* kbase = kp + ((size_t)b * NKV) * 384 + h * 64;
  const f16* vbase = vt + ((size_t)(b * 384 + h * 64)) * NKV;

  float mrun = -1e30f;                // for q = c (redundant across g)
  f32x4 o[4] = {};                    // O[q=g*4+r][d=dt*16+c]
  f32x4 osum = {};                    // lsum[q=g*4+r]
  f16* prow = &Ps[wave][0];

  // T14 staging registers + preload tile 0
  f16x8 kr0, kr1, vr0, vr1;
  kr0 = *(const f16x8*)(kbase + (size_t)tid8 * 384 + lch * 8);
  kr1 = *(const f16x8*)(kbase + (size_t)(32 + tid8) * 384 + lch * 8);
  vr0 = *(const f16x8*)(vbase + (size_t)tid8 * NKV + lch * 8);
  vr1 = *(const f16x8*)(vbase + (size_t)(32 + tid8) * NKV + lch * 8);

  for (int ti = 0; ti < 13; ++ti) {
    __syncthreads();                  // all waves done reading LDS (prev tile)
    *(f16x8*)(Ks + tid * 8) = kr0;
    *(f16x8*)(Ks + 2048 + tid * 8) = kr1;
    *(f16x8*)(Vs + tid * 8) = vr0;
    *(f16x8*)(Vs + 2048 + tid * 8) = vr1;
    if (ti + 1 < 13) {
      const int t0n = (ti + 1) * 64;
      int kvA = t0n + tid8;        if (kvA > NKV - 1) kvA = NKV - 1;
      int kvB = t0n + 32 + tid8;   if (kvB > NKV - 1) kvB = NKV - 1;
      int colc = t0n + lch * 8;    if (colc > NKV - 8) colc = NKV - 8;
      kr0 = *(const f16x8*)(kbase + (size_t)kvA * 384 + lch * 8);
      kr1 = *(const f16x8*)(kbase + (size_t)kvB * 384 + lch * 8);
      vr0 = *(const f16x8*)(vbase + (size_t)tid8 * NKV + colc);
      vr1 = *(const f16x8*)(vbase + (size_t)(32 + tid8) * NKV + colc);
    }
    __syncthreads();                  // LDS writes visible to all waves

    if (ti < 12) {
      // -------- full tile --------
      f32x4 s[4] = {};
      __builtin_amdgcn_s_setprio(1);
#pragma unroll
      for (int kh = 0; kh < 2; ++kh) {
#pragma unroll
        for (int ct = 0; ct < 4; ++ct) {
          const int row = ct * 16 + c;
          const int sch = (kh * 4 + g) ^ (row & 7);
          f16x8 kb = *(const f16x8*)(Ks + row * 64 + sch * 8);
          s[ct] = __builtin_amdgcn_mfma_f32_16x16x32_f16(kb, qa[kh], s[ct], 0, 0, 0);
        }
      }
      __builtin_amdgcn_s_setprio(0);

      float mt = s[0][0];
#pragma unroll
      for (int ct = 0; ct < 4; ++ct)
#pragma unroll
        for (int r = 0; r < 4; ++r) mt = fmaxf(mt, s[ct][r]);
      mt = fmaxf(mt, __shfl_xor(mt, 16));
      mt = fmaxf(mt, __shfl_xor(mt, 32));

      if (__ballot(mt > mrun + 8.0f)) {   // defer-max: P bounded by 2^8
        const float mnew = fmaxf(mrun, mt);
        const float corr = fast_exp2(mrun - mnew);
        mrun = mnew;
#pragma unroll
        for (int r = 0; r < 4; ++r) {
          const float co = __shfl(corr, g * 4 + r);
#pragma unroll
          for (int dt = 0; dt < 4; ++dt) o[dt][r] *= co;
          osum[r] *= co;
        }
      }

#pragma unroll
      for (int ct = 0; ct < 4; ++ct) {
        const float p0 = fast_exp2(s[ct][0] - mrun);
        const float p1 = fast_exp2(s[ct][1] - mrun);
        const float p2 = fast_exp2(s[ct][2] - mrun);
        const float p3 = fast_exp2(s[ct][3] - mrun);
        const int sch = (ct * 2 + (g >> 1)) ^ (c & 7);
        *(f16x4*)(prow + c * 64 + sch * 8 + (g & 1) * 4) = pack4(p0, p1, p2, p3);
      }

      __builtin_amdgcn_s_setprio(1);
#pragma unroll
      for (int ks = 0; ks < 2; ++ks) {
        const int sp = (ks * 4 + g) ^ (c & 7);
        f16x8 pa = *(const f16x8*)(prow + c * 64 + sp * 8);
#pragma unroll
        for (int dt = 0; dt < 4; ++dt) {
          const int d = dt * 16 + c;
          f16x8 vb = *(const f16x8*)(Vs + d * 64 + sp * 8);
          o[dt] = __builtin_amdgcn_mfma_f32_16x16x32_f16(pa, vb, o[dt], 0, 0, 0);
        }
        osum = __builtin_amdgcn_mfma_f32_16x16x32_f16(pa, vones, osum, 0, 0, 0);
      }
      __builtin_amdgcn_s_setprio(0);
    } else {
      // -------- tail tile: t0 = 768, only 16 valid KV rows --------
      f32x4 s0 = {};
      __builtin_amdgcn_s_setprio(1);
#pragma unroll
      for (int kh = 0; kh < 2; ++kh) {
        const int sch = (kh * 4 + g) ^ (c & 7);
        f16x8 kb = *(const f16x8*)(Ks + c * 64 + sch * 8);
        s0 = __builtin_amdgcn_mfma_f32_16x16x32_f16(kb, qa[kh], s0, 0, 0, 0);
      }
      __builtin_amdgcn_s_setprio(0);

      float mt = fmaxf(fmaxf(s0[0], s0[1]), fmaxf(s0[2], s0[3]));
      mt = fmaxf(mt, __shfl_xor(mt, 16));
      mt = fmaxf(mt, __shfl_xor(mt, 32));
      if (__ballot(mt > mrun + 8.0f)) {
        const float mnew = fmaxf(mrun, mt);
        const float corr = fast_exp2(mrun - mnew);
        mrun = mnew;
#pragma unroll
        for (int r = 0; r < 4; ++r) {
          const float co = __shfl(corr, g * 4 + r);
#pragma unroll
          for (int dt = 0; dt < 4; ++dt) o[dt][r] *= co;
          osum[r] *= co;
        }
      }

      {
        const float p0 = fast_exp2(s0[0] - mrun);
        const float p1 = fast_exp2(s0[1] - mrun);
        const float p2 = fast_exp2(s0[2] - mrun);
        const float p3 = fast_exp2(s0[3] - mrun);
        const int sch0 = (0 + (g >> 1)) ^ (c & 7);
        *(f16x4*)(prow + c * 64 + sch0 * 8 + (g & 1) * 4) = pack4(p0, p1, p2, p3);
        const int sch1 = (2 + (g >> 1)) ^ (c & 7);
        f16x4 z = {};
        *(f16x4*)(prow + c * 64 + sch1 * 8 + (g & 1) * 4) = z;
      }

      __builtin_amdgcn_s_setprio(1);
      {
        const int sp = g ^ (c & 7);
        f16x8 pa = *(const f16x8*)(prow + c * 64 + sp * 8);
#pragma unroll
        for (int dt = 0; dt < 4; ++dt) {
          const int d = dt * 16 + c;
          f16x8 vb = *(const f16x8*)(Vs + d * 64 + sp * 8);
          o[dt] = __builtin_amdgcn_mfma_f32_16x16x32_f16(pa, vb, o[dt], 0, 0, 0);
        }
        osum = __builtin_amdgcn_mfma_f32_16x16x32_f16(pa, vones, osum, 0, 0, 0);
      }
      __builtin_amdgcn_s_setprio(0);
    }
  }

  // epilogue: osum already in q=g*4+r row layout -> no shuffles
  f16* obase = op + ((size_t)(b * NQ + qt * 64 + wave * 16)) * 384 + h * 64;
#pragma unroll
  for (int r = 0; r < 4; ++r) {
    const float iv = 1.0f / osum[r];
#pragma unroll
    for (int dt = 0; dt < 4; ++dt)
      obase[(size_t)(g * 4 + r) * 384 + dt * 16 + c] = (f16)(o[dt][r] * iv);
  }
}

extern "C" void kernel_launch(void* const* d_in, const int* in_sizes, int n_in,
                              void* d_out, int out_size, void* d_ws, size_t ws_size,
                              hipStream_t stream) {
  const float* inputs_q  = (const float*)d_in[0];
  const float* inputs_kv = (const float*)d_in[1];
  const float* out_kern  = (const float*)d_in[2];
  const float* q_dwk = (const float*)d_in[3];
  const float* q_bs  = (const float*)d_in[4];
  const float* q_bb  = (const float*)d_in[5];
  const float* q_bm  = (const float*)d_in[6];
  const float* q_bv  = (const float*)d_in[7];
  const float* q_pwk = (const float*)d_in[8];
  const float* k_dwk = (const float*)d_in[9];
  const float* k_bs  = (const float*)d_in[10];
  const float* k_bb  = (const float*)d_in[11];
  const float* k_bm  = (const float*)d_in[12];
  const float* k_bv  = (const float*)d_in[13];
  const float* k_pwk = (const float*)d_in[14];
  const float* v_dwk = (const float*)d_in[15];
  const float* v_bs  = (const float*)d_in[16];
  const float* v_bb  = (const float*)d_in[17];
  const float* v_bm  = (const float*)d_in[18];
  const float* v_bv  = (const float*)d_in[19];
  const float* v_pwk = (const float*)d_in[20];

  char* wsb = (char*)d_ws;
  f16* qdw = (f16*)(wsb + 0);             // 25088*384 f16
  f16* kdw = (f16*)(wsb + 19267584);      // 6272*384 f16
  f16* vdw = (f16*)(wsb + 24084480);      // 6272*384 f16
  f16* qf  = (f16*)(wsb + 28901376);      // 25088*384 f16
  f16* kf  = (f16*)(wsb + 48168960);      // 6272*384 f16
  f16* vtp = (f16*)(wsb + 57802752);      // 8*384*784 f16
  f16* of  = (f16*)(wsb + 62619648);      // 25088*384 f16
  f16* wqt = (f16*)(wsb + 81887232);      // 384*384 f16 x4
  f16* wkt = (f16*)(wsb + 82182144);
  f16* wvt = (f16*)(wsb + 82477056);
  f16* wot = (f16*)(wsb + 82771968);

  // 1. fused preprocess (XCD-chunked, high-ILP dw bodies)
  preprocess<<<4104, 256, 0, stream>>>(
      inputs_q, inputs_kv,
      q_dwk, q_bs, q_bb, q_bm, q_bv,
      k_dwk, k_bs, k_bb, k_bm, k_bv,
      v_dwk, v_bs, v_bb, v_bm, v_bv,
      q_pwk, k_pwk, v_pwk, out_kern, wqt, wkt, wvt, wot,
      qdw, kdw, vdw);
  // 2. fused q/k/v pointwise GEMMs (V written transposed; q folded with 1/8*log2e)
  gemm_qkv<<<882, 256, 0, stream>>>(qdw, wqt, qf, 0.125f * LOG2E,
                                    kdw, wkt, kf, vdw, wvt, vtp);
  // 3. MFMA attention (KVT=64, XCD-chunked, T14 async-STAGE, specialized tail) -> f16 O
  attn_mfma<<<BB * NHD * 49, 256, 0, stream>>>(qf, kf, vtp, of);
  // 4. output projection (MFMA, fp32 out)
  gemm_mfma<0><<<dim3(196, 3), 256, 0, stream>>>(of, wot, (float*)d_out, nullptr, 1.0f);
}

// Round 19
// 136.137 us; speedup vs baseline: 1.4993x; 1.0084x over previous
//
#include <hip/hip_runtime.h>
#include <hip/hip_bf16.h>
#include <hip/hip_fp16.h>

// Problem constants
#define BB 8
#define HH 56
#define WW 56
#define CC 384
#define NHD 6
#define DD 64
#define HK 28
#define WK 28
#define NQ (HH*WW)       // 3136
#define NKV (HK*WK)      // 784
#define NTOK (BB*NQ)     // 25088
#define NTOKKV (BB*NKV)  // 6272
#define BN_EPS 1e-5f
#define LOG2E 1.44269504f

typedef _Float16 f16;
typedef _Float16 f16x2 __attribute__((ext_vector_type(2)));
typedef _Float16 f16x4 __attribute__((ext_vector_type(4)));
typedef _Float16 f16x8 __attribute__((ext_vector_type(8)));
typedef float f32x4 __attribute__((ext_vector_type(4)));

__device__ __forceinline__ float fast_exp2(float x) {
#if __has_builtin(__builtin_amdgcn_exp2f)
  return __builtin_amdgcn_exp2f(x);   // v_exp_f32 (2^x)
#else
  return __expf(x * 0.69314718056f);
#endif
}

__device__ __forceinline__ f16x4 pack4(float p0, float p1, float p2, float p3) {
#if __has_builtin(__builtin_amdgcn_cvt_pkrtz)
  f16x2 a = __builtin_bit_cast(f16x2, __builtin_amdgcn_cvt_pkrtz(p0, p1));
  f16x2 b = __builtin_bit_cast(f16x2, __builtin_amdgcn_cvt_pkrtz(p2, p3));
  return __builtin_shufflevector(a, b, 0, 1, 2, 3);
#else
  f16x4 r; r[0] = (f16)p0; r[1] = (f16)p1; r[2] = (f16)p2; r[3] = (f16)p3;
  return r;
#endif
}

// ---------------- dw conv + BN bodies (high-ILP: all loads hoisted) ----------------
// dw_s1: 2x2 output quad per thread. 16 input float4 + 9 weight float4 up-front.
__device__ __forceinline__ void dw_s1_body(
    int blk, int tid, const float* __restrict__ in, const float* __restrict__ w,
    const float* __restrict__ bns, const float* __restrict__ bnb,
    const float* __restrict__ bnm, const float* __restrict__ bnv,
    f16* __restrict__ out) {
  int idx = blk * 256 + tid;                     // < 602112 = (NTOK/4)*96
  int pp = idx / 96;
  int c = (idx % 96) * 4;
  int b = pp / 784;                              // 28*28 quads per image
  int rem = pp % 784;
  int yh = rem / 28, xh = rem % 28;
  int y0 = yh * 2, x0 = xh * 2;
  const float4 z4 = {0.f, 0.f, 0.f, 0.f};

  float4 V[4][4];
#pragma unroll
  for (int ry = 0; ry < 4; ++ry) {
    const int iy = y0 - 1 + ry;
    const bool vy = (unsigned)iy < (unsigned)HH;
    const float* rp = in + ((size_t)(b * HH + (vy ? iy : 0)) * WW) * CC + c;
    V[ry][0] = (vy && x0 > 0)      ? *(const float4*)(rp + (size_t)(x0 - 1) * CC) : z4;
    V[ry][1] = vy                  ? *(const float4*)(rp + (size_t)x0 * CC)       : z4;
    V[ry][2] = vy                  ? *(const float4*)(rp + (size_t)(x0 + 1) * CC) : z4;
    V[ry][3] = (vy && x0 < WW - 2) ? *(const float4*)(rp + (size_t)(x0 + 2) * CC) : z4;
  }
  float4 W[9];
#pragma unroll
  for (int i = 0; i < 9; ++i) W[i] = *(const float4*)(w + i * CC + c);

  const float4 s = *(const float4*)(bns + c);
  const float4 bi = *(const float4*)(bnb + c);
  const float4 m = *(const float4*)(bnm + c);
  const float4 va = *(const float4*)(bnv + c);
  const float gx = s.x * rsqrtf(va.x + BN_EPS);
  const float gy = s.y * rsqrtf(va.y + BN_EPS);
  const float gz = s.z * rsqrtf(va.z + BN_EPS);
  const float gw = s.w * rsqrtf(va.w + BN_EPS);

#pragma unroll
  for (int dy = 0; dy < 2; ++dy)
#pragma unroll
    for (int dx = 0; dx < 2; ++dx) {
      float ax = 0.f, ay = 0.f, az = 0.f, aw = 0.f;
#pragma unroll
      for (int ky = 0; ky < 3; ++ky)
#pragma unroll
        for (int kx = 0; kx < 3; ++kx) {
          const float4 v = V[dy + ky][dx + kx];
          const float4 wk = W[ky * 3 + kx];
          ax = fmaf(v.x, wk.x, ax); ay = fmaf(v.y, wk.y, ay);
          az = fmaf(v.z, wk.z, az); aw = fmaf(v.w, wk.w, aw);
        }
      f16x4 r;
      r[0] = (f16)fmaf(ax - m.x, gx, bi.x);
      r[1] = (f16)fmaf(ay - m.y, gy, bi.y);
      r[2] = (f16)fmaf(az - m.z, gz, bi.z);
      r[3] = (f16)fmaf(aw - m.w, gw, bi.w);
      const size_t pix = (size_t)b * NQ + (size_t)(y0 + dy) * WW + (x0 + dx);
      *(f16x4*)(out + pix * CC + c) = r;
    }
}

// dw_s2 (stride 2): 2 adjacent output pixels per thread; 15 input float4 shared
// between both outputs AND both (k,v) weight sets.
__device__ __forceinline__ void dw_s2_body(
    int blk, int tid, const float* __restrict__ in,
    const float* __restrict__ wk_, const float* __restrict__ kbs, const float* __restrict__ kbb,
    const float* __restrict__ kbm, const float* __restrict__ kbv,
    const float* __restrict__ wv_, const float* __restrict__ vbs, const float* __restrict__ vbb,
    const float* __restrict__ vbm, const float* __restrict__ vbv,
    f16* __restrict__ outk, f16* __restrict__ outv) {
  int idx = blk * 256 + tid;                     // < 301056 = (NTOKKV/2)*96
  int pp = idx / 96;
  int c = (idx % 96) * 4;
  int b = pp / 392;                              // 28*14 pairs per image
  int rem = pp % 392;
  int oy = rem / 14, xh = rem % 14;
  int ox0 = xh * 2;
  int iy0 = oy * 2, ix0 = ox0 * 2;
  const float4 z4 = {0.f, 0.f, 0.f, 0.f};

  float4 V[3][5];
#pragma unroll
  for (int ry = 0; ry < 3; ++ry) {
    const int iy = iy0 + ry;
    const bool vy = iy < HH;
    const float* rp = in + ((size_t)(b * HH + (vy ? iy : 0)) * WW) * CC + c;
#pragma unroll
    for (int cx = 0; cx < 5; ++cx) {
      const int ix = ix0 + cx;
      V[ry][cx] = (vy && ix < WW) ? *(const float4*)(rp + (size_t)ix * CC) : z4;
    }
  }

  // ---- k path ----
  {
    float4 W[9];
#pragma unroll
    for (int i = 0; i < 9; ++i) W[i] = *(const float4*)(wk_ + i * CC + c);
    const float4 s = *(const float4*)(kbs + c);
    const float4 bi = *(const float4*)(kbb + c);
    const float4 m = *(const float4*)(kbm + c);
    const float4 va = *(const float4*)(kbv + c);
    const float gx = s.x * rsqrtf(va.x + BN_EPS);
    const float gy = s.y * rsqrtf(va.y + BN_EPS);
    const float gz = s.z * rsqrtf(va.z + BN_EPS);
    const float gw = s.w * rsqrtf(va.w + BN_EPS);
#pragma unroll
    for (int dx = 0; dx < 2; ++dx) {
      float ax = 0.f, ay = 0.f, az = 0.f, aw = 0.f;
#pragma unroll
      for (int ky = 0; ky < 3; ++ky)
#pragma unroll
        for (int kx = 0; kx < 3; ++kx) {
          const float4 v = V[ky][2 * dx + kx];
          const float4 wk = W[ky * 3 + kx];
          ax = fmaf(v.x, wk.x, ax); ay = fmaf(v.y, wk.y, ay);
          az = fmaf(v.z, wk.z, az); aw = fmaf(v.w, wk.w, aw);
        }
      f16x4 r;
      r[0] = (f16)fmaf(ax - m.x, gx, bi.x);
      r[1] = (f16)fmaf(ay - m.y, gy, bi.y);
      r[2] = (f16)fmaf(az - m.z, gz, bi.z);
      r[3] = (f16)fmaf(aw - m.w, gw, bi.w);
      const size_t pix = (size_t)b * NKV + (size_t)oy * WK + (ox0 + dx);
      *(f16x4*)(outk + pix * CC + c) = r;
    }
  }
  // ---- v path (reuses V) ----
  {
    float4 W[9];
#pragma unroll
    for (int i = 0; i < 9; ++i) W[i] = *(const float4*)(wv_ + i * CC + c);
    const float4 s = *(const float4*)(vbs + c);
    const float4 bi = *(const float4*)(vbb + c);
    const float4 m = *(const float4*)(vbm + c);
    const float4 va = *(const float4*)(vbv + c);
    const float gx = s.x * rsqrtf(va.x + BN_EPS);
    const float gy = s.y * rsqrtf(va.y + BN_EPS);
    const float gz = s.z * rsqrtf(va.z + BN_EPS);
    const float gw = s.w * rsqrtf(va.w + BN_EPS);
#pragma unroll
    for (int dx = 0; dx < 2; ++dx) {
      float ax = 0.f, ay = 0.f, az = 0.f, aw = 0.f;
#pragma unroll
      for (int ky = 0; ky < 3; ++ky)
#pragma unroll
        for (int kx = 0; kx < 3; ++kx) {
          const float4 v = V[ky][2 * dx + kx];
          const float4 wk = W[ky * 3 + kx];
          ax = fmaf(v.x, wk.x, ax); ay = fmaf(v.y, wk.y, ay);
          az = fmaf(v.z, wk.z, az); aw = fmaf(v.w, wk.w, aw);
        }
      f16x4 r;
      r[0] = (f16)fmaf(ax - m.x, gx, bi.x);
      r[1] = (f16)fmaf(ay - m.y, gy, bi.y);
      r[2] = (f16)fmaf(az - m.z, gz, bi.z);
      r[3] = (f16)fmaf(aw - m.w, gw, bi.w);
      const size_t pix = (size_t)b * NKV + (size_t)oy * WK + (ox0 + dx);
      *(f16x4*)(outv + pix * CC + c) = r;
    }
  }
}

// ---- fused preprocess: dw_s1 (2352) + dw_s2_kv (1176) + convert_w (576) ----
// Segments XCD-chunked (contiguous image span per XCD).
__global__ __launch_bounds__(256) void preprocess(
    const float* __restrict__ inputs_q, const float* __restrict__ inputs_kv,
    const float* __restrict__ q_dwk, const float* __restrict__ q_bs,
    const float* __restrict__ q_bb, const float* __restrict__ q_bm,
    const float* __restrict__ q_bv,
    const float* __restrict__ k_dwk, const float* __restrict__ k_bs,
    const float* __restrict__ k_bb, const float* __restrict__ k_bm,
    const float* __restrict__ k_bv,
    const float* __restrict__ v_dwk, const float* __restrict__ v_bs,
    const float* __restrict__ v_bb, const float* __restrict__ v_bm,
    const float* __restrict__ v_bv,
    const float* __restrict__ w0, const float* __restrict__ w1,
    const float* __restrict__ w2, const float* __restrict__ w3,
    f16* __restrict__ o0, f16* __restrict__ o1,
    f16* __restrict__ o2, f16* __restrict__ o3,
    f16* __restrict__ qdw, f16* __restrict__ kdw, f16* __restrict__ vdw) {
  __shared__ float t[32][33];
  const int bid = blockIdx.x;
  const int tid = threadIdx.x;
  if (bid < 2352) {
    const int lb = (bid & 7) * 294 + (bid >> 3);        // 2352 = 8*294, bijective
    dw_s1_body(lb, tid, inputs_q, q_dwk, q_bs, q_bb, q_bm, q_bv, qdw);
  } else if (bid < 3528) {
    const int r = bid - 2352;                           // 1176 = 8*147
    const int lb = (r & 7) * 147 + (r >> 3);
    dw_s2_body(lb, tid, inputs_kv,
               k_dwk, k_bs, k_bb, k_bm, k_bv,
               v_dwk, v_bs, v_bb, v_bm, v_bv, kdw, vdw);
  } else {
    const int r = bid - 3528;                 // 0..575  (12 x 12 x 4)
    const int z = r / 144, rem = r % 144;
    const int bx = rem % 12, by = rem / 12;
    const float* src = z == 0 ? w0 : z == 1 ? w1 : z == 2 ? w2 : w3;
    f16* dst = z == 0 ? o0 : z == 1 ? o1 : z == 2 ? o2 : o3;
    const int k0 = bx * 32, n0 = by * 32;
    const int x = tid & 31, y = tid >> 5;
#pragma unroll
    for (int i = 0; i < 4; ++i) t[y + i * 8][x] = src[(size_t)(k0 + y + i * 8) * 384 + n0 + x];
    __syncthreads();
#pragma unroll
    for (int i = 0; i < 4; ++i)
      dst[(size_t)(n0 + y + i * 8) * 384 + k0 + x] = (f16)t[x][y + i * 8];
  }
}

// ------------- f16 MFMA GEMM body (128x128 tile, BK=64, 4 waves, 4x4 frags) -------------
// MODE 0: fp32 row-major; MODE 1: f16 row-major; MODE 2: f16 V^T (vtp [b*384+d][784])
template <int MODE>
__device__ __forceinline__ void gemm_body(
    const f16* __restrict__ A, const f16* __restrict__ Bt,
    float* __restrict__ Cf, f16* __restrict__ Ch, float scale,
    int row0, int col0) {
  __shared__ f16 As[128 * 64];   // [row][k], 128 B per row
  __shared__ f16 Bs[128 * 64];   // [col][k], 128 B per col
  const int tid = threadIdx.x;
  const int wave = tid >> 6, lane = tid & 63;
  const int c = lane & 15, g = lane >> 4;
  const int wr = wave >> 1, wc = wave & 1;     // 2x2 waves, each 64x64

  const int s_base = wave * 64 + lane;
  f32x4 acc[4][4] = {};

  for (int k0 = 0; k0 < 384; k0 += 64) {
    __syncthreads();
#pragma unroll
    for (int j = 0; j < 4; ++j) {
      const int s = j * 256 + s_base;
      const int row = s >> 3, sch = s & 7;
      const int lch = sch ^ (row & 7);         // logical k-chunk fetched
      const f16* sa = A + (size_t)(row0 + row) * 384 + k0 + lch * 8;
      __builtin_amdgcn_global_load_lds(
          (const __attribute__((address_space(1))) void*)sa,
          (__attribute__((address_space(3))) void*)(As + j * 2048 + wave * 512), 16, 0, 0);
      const f16* sb = Bt + (size_t)(col0 + row) * 384 + k0 + lch * 8;
      __builtin_amdgcn_global_load_lds(
          (const __attribute__((address_space(1))) void*)sb,
          (__attribute__((address_space(3))) void*)(Bs + j * 2048 + wave * 512), 16, 0, 0);
    }
    __syncthreads();

#pragma unroll
    for (int kh = 0; kh < 2; ++kh) {
      f16x8 bf[4];
#pragma unroll
      for (int n = 0; n < 4; ++n) {
        const int row = wc * 64 + n * 16 + c;
        bf[n] = *(const f16x8*)(Bs + (size_t)row * 64 + ((kh * 4 + g) ^ (row & 7)) * 8);
      }
#pragma unroll
      for (int m = 0; m < 4; ++m) {
        const int row = wr * 64 + m * 16 + c;
        f16x8 af = *(const f16x8*)(As + (size_t)row * 64 + ((kh * 4 + g) ^ (row & 7)) * 8);
#pragma unroll
        for (int n = 0; n < 4; ++n)
          acc[m][n] = __builtin_amdgcn_mfma_f32_16x16x32_f16(af, bf[n], acc[m][n], 0, 0, 0);
      }
    }
  }

  if (MODE == 2) {
#pragma unroll
    for (int m = 0; m < 4; ++m)
#pragma unroll
      for (int n = 0; n < 4; ++n) {
        const int gr = row0 + wr * 64 + m * 16 + g * 4;
        const int col = col0 + wc * 64 + n * 16 + c;
        const int bb = gr / NKV;
        const int kv = gr - bb * NKV;           // 4-pack cannot cross batch (784%4==0, gr%4==0)
        f16x4 pk;
#pragma unroll
        for (int r = 0; r < 4; ++r) pk[r] = (f16)(acc[m][n][r] * scale);
        *(f16x4*)(Ch + ((size_t)bb * 384 + col) * NKV + kv) = pk;
      }
  } else {
#pragma unroll
    for (int m = 0; m < 4; ++m)
#pragma unroll
      for (int n = 0; n < 4; ++n)
#pragma unroll
        for (int r = 0; r < 4; ++r) {
          const size_t row = row0 + wr * 64 + m * 16 + g * 4 + r;
          const size_t col = col0 + wc * 64 + n * 16 + c;
          if (MODE == 1) Ch[row * 384 + col] = (f16)(acc[m][n][r] * scale);
          else           Cf[row * 384 + col] = acc[m][n][r] * scale;
        }
  }
}

// fused q/k/v pointwise GEMMs: 882 flat blocks = q(196x3) + k(49x3) + v(49x3)
__global__ __launch_bounds__(256) void gemm_qkv(
    const f16* __restrict__ qdw, const f16* __restrict__ wqt, f16* __restrict__ qf, float qscale,
    const f16* __restrict__ kdw, const f16* __restrict__ wkt, f16* __restrict__ kf,
    const f16* __restrict__ vdw, const f16* __restrict__ wvt, f16* __restrict__ vtp) {
  const int blk = blockIdx.x;
  if (blk < 588) {
    gemm_body<1>(qdw, wqt, nullptr, qf, qscale, (blk % 196) * 128, (blk / 196) * 128);
  } else if (blk < 735) {
    const int r = blk - 588;
    gemm_body<1>(kdw, wkt, nullptr, kf, 1.0f, (r % 49) * 128, (r / 49) * 128);
  } else {
    const int r = blk - 735;
    gemm_body<2>(vdw, wvt, nullptr, vtp, 1.0f, (r % 49) * 128, (r / 49) * 128);
  }
}

template <int MODE>
__global__ __launch_bounds__(256) void gemm_mfma(
    const f16* __restrict__ A, const f16* __restrict__ Bt,
    float* __restrict__ Cf, f16* __restrict__ Ch, float scale) {
  gemm_body<MODE>(A, Bt, Cf, Ch, scale, blockIdx.x * 128, blockIdx.y * 128);
}

// ------------- f16 MFMA flash attention: single-barrier double-buffer + T14 -------------
// grid = 2352; lb = (bid&7)*294 + (bid>>3): each XCD owns 6 complete (b,h) pairs.
// Per tile: {write staged regs -> buf[cur]; issue loads(t+1) -> regs; __syncthreads;
// compute from buf[cur]} -- ONE barrier/tile. Safety: a wave entering iter i's write
// passed barrier(i-1), which all waves reached only after their tile-(i-2) compute
// of buf[i&1] -> no writer overtakes a reader. 12 full tiles + specialized tail.
__global__ __launch_bounds__(256) void attn_mfma(
    const f16* __restrict__ qp, const f16* __restrict__ kp,
    const f16* __restrict__ vt, f16* __restrict__ op) {
  __shared__ f16 Ks[2][64 * 64];   // [buf][kv][d], chunk ch at ch^(kv&7)
  __shared__ f16 Vs[2][64 * 64];   // [buf][d][kv], chunk ch at ch^(d&7)
  __shared__ f16 Ps[4][16 * 64];   // per-wave [q][kv], ch^(q&7)
  const int bid0 = blockIdx.x;
  const int lb = (bid0 & 7) * 294 + (bid0 >> 3);   // bijective (2352 = 8*294)
  const int qt = lb % 49;
  const int bh = lb / 49;
  const int h = bh % NHD, b = bh / NHD;
  const int tid = threadIdx.x;
  const int wave = tid >> 6, lane = tid & 63;
  const int c = lane & 15, g = lane >> 4;

  const size_t qrow = (size_t)b * NQ + qt * 64 + wave * 16 + c;
  f16x8 qa[2];
  qa[0] = *(const f16x8*)(qp + qrow * 384 + h * 64 + g * 8);
  qa[1] = *(const f16x8*)(qp + qrow * 384 + h * 64 + 32 + g * 8);

  f16x8 vones;
#pragma unroll
  for (int j = 0; j < 8; ++j) vones[j] = (f16)1.0f;

  const int tid8 = tid >> 3, tch = tid & 7;
  const int lch = tch ^ (tid8 & 7);            // logical chunk fetched

  const f16* kbase = kp + ((size_t)b * NKV) * 384 + h * 64;
  const f16* vbase = vt + ((size_t)(b * 384 + h * 64)) * NKV;

  float mrun = -1e30f;                // for q = c (redundant across g)
  f32x4 o[4] = {};                    // O[q=g*4+r][d=dt*16+c]
  f32x4 osum = {};                    // lsum[q=g*4+r]
  f16* prow = &Ps[wave][0];

  // T14 staging registers + preload tile 0 (in-bounds at t0=0)
  f16x8 kr0, kr1, vr0, vr1;
  kr0 = *(const f16x8*)(kbase + (size_t)tid8 * 384 + lch * 8);
  kr1 = *(const f16x8*)(kbase + (size_t)(32 + tid8) * 384 + lch * 8);
  vr0 = *(const f16x8*)(vbase + (size_t)tid8 * NKV + lch * 8);
  vr1 = *(const f16x8*)(vbase + (size_t)(32 + tid8) * NKV + lch * 8);

  int cur = 0;
  for (int ti = 0; ti < 13; ++ti) {
    // write staged regs -> buf[cur] (tile ti); buf[cur] last read at tile ti-2,
    // protected by barrier(ti-1).
    f16* ksw = &Ks[cur][0];
    f16* vsw = &Vs[cur][0];
    *(f16x8*)(ksw + tid * 8) = kr0;
    *(f16x8*)(ksw + 2048 + tid * 8) = kr1;
    *(f16x8*)(vsw + tid * 8) = vr0;
    *(f16x8*)(vsw + 2048 + tid * 8) = vr1;
    // issue loads for tile ti+1 into regs (fly during this tile's compute)
    if (ti + 1 < 13) {
      const int t0n = (ti + 1) * 64;
      int kvA = t0n + tid8;        if (kvA > NKV - 1) kvA = NKV - 1;
      int kvB = t0n + 32 + tid8;   if (kvB > NKV - 1) kvB = NKV - 1;
      int colc = t0n + lch * 8;    if (colc > NKV - 8) colc = NKV - 8;
      kr0 = *(const f16x8*)(kbase + (size_t)kvA * 384 + lch * 8);
      kr1 = *(const f16x8*)(kbase + (size_t)kvB * 384 + lch * 8);
      vr0 = *(const f16x8*)(vbase + (size_t)tid8 * NKV + colc);
      vr1 = *(const f16x8*)(vbase + (size_t)(32 + tid8) * NKV + colc);
    }
    __syncthreads();                  // buf[cur] writes visible; ONE barrier/tile
    const f16* ksb = &Ks[cur][0];
    const f16* vsb = &Vs[cur][0];

    if (ti < 12) {
      // -------- full tile --------
      f32x4 s[4] = {};
      __builtin_amdgcn_s_setprio(1);
#pragma unroll
      for (int kh = 0; kh < 2; ++kh) {
#pragma unroll
        for (int ct = 0; ct < 4; ++ct) {
          const int row = ct * 16 + c;
          const int sch = (kh * 4 + g) ^ (row & 7);
          f16x8 kb = *(const f16x8*)(ksb + row * 64 + sch * 8);
          s[ct] = __builtin_amdgcn_mfma_f32_16x16x32_f16(kb, qa[kh], s[ct], 0, 0, 0);
        }
      }
      __builtin_amdgcn_s_setprio(0);

      float mt = s[0][0];
#pragma unroll
      for (int ct = 0; ct < 4; ++ct)
#pragma unroll
        for (int r = 0; r < 4; ++r) mt = fmaxf(mt, s[ct][r]);
      mt = fmaxf(mt, __shfl_xor(mt, 16));
      mt = fmaxf(mt, __shfl_xor(mt, 32));

      if (__ballot(mt > mrun + 8.0f)) {   // defer-max: P bounded by 2^8
        const float mnew = fmaxf(mrun, mt);
        const float corr = fast_exp2(mrun - mnew);
        mrun = mnew;
#pragma unroll
        for (int r = 0; r < 4; ++r) {
          const float co = __shfl(corr, g * 4 + r);
#pragma unroll
          for (int dt = 0; dt < 4; ++dt) o[dt][r] *= co;
          osum[r] *= co;
        }
      }

#pragma unroll
      for (int ct = 0; ct < 4; ++ct) {
        const float p0 = fast_exp2(s[ct][0] - mrun);
        const float p1 = fast_exp2(s[ct][1] - mrun);
        const float p2 = fast_exp2(s[ct][2] - mrun);
        const float p3 = fast_exp2(s[ct][3] - mrun);
        const int sch = (ct * 2 + (g >> 1)) ^ (c & 7);
        *(f16x4*)(prow + c * 64 + sch * 8 + (g & 1) * 4) = pack4(p0, p1, p2, p3);
      }

      __builtin_amdgcn_s_setprio(1);
#pragma unroll
      for (int ks = 0; ks < 2; ++ks) {
        const int sp = (ks * 4 + g) ^ (c & 7);
        f16x8 pa = *(const f16x8*)(prow + c * 64 + sp * 8);
#pragma unroll
        for (int dt = 0; dt < 4; ++dt) {
          const int d = dt * 16 + c;
          f16x8 vb = *(const f16x8*)(vsb + d * 64 + sp * 8);
          o[dt] = __builtin_amdgcn_mfma_f32_16x16x32_f16(pa, vb, o[dt], 0, 0, 0);
        }
        osum = __builtin_amdgcn_mfma_f32_16x16x32_f16(pa, vones, osum, 0, 0, 0);
      }
      __builtin_amdgcn_s_setprio(0);
    } else {
      // -------- tail tile: t0 = 768, only 16 valid KV rows --------
      f32x4 s0 = {};
      __builtin_amdgcn_s_setprio(1);
#pragma unroll
      for (int kh = 0; kh < 2; ++kh) {
        const int sch = (kh * 4 + g) ^ (c & 7);
        f16x8 kb = *(const f16x8*)(ksb + c * 64 + sch * 8);
        s0 = __builtin_amdgcn_mfma_f32_16x16x32_f16(kb, qa[kh], s0, 0, 0, 0);
      }
      __builtin_amdgcn_s_setprio(0);

      float mt = fmaxf(fmaxf(s0[0], s0[1]), fmaxf(s0[2], s0[3]));
      mt = fmaxf(mt, __shfl_xor(mt, 16));
      mt = fmaxf(mt, __shfl_xor(mt, 32));
      if (__ballot(mt > mrun + 8.0f)) {
        const float mnew = fmaxf(mrun, mt);
        const float corr = fast_exp2(mrun - mnew);
        mrun = mnew;
#pragma unroll
        for (int r = 0; r < 4; ++r) {
          const float co = __shfl(corr, g * 4 + r);
#pragma unroll
          for (int dt = 0; dt < 4; ++dt) o[dt][r] *= co;
          osum[r] *= co;
        }
      }

      {
        const float p0 = fast_exp2(s0[0] - mrun);
        const float p1 = fast_exp2(s0[1] - mrun);
        const float p2 = fast_exp2(s0[2] - mrun);
        const float p3 = fast_exp2(s0[3] - mrun);
        const int sch0 = (0 + (g >> 1)) ^ (c & 7);
        *(f16x4*)(prow + c * 64 + sch0 * 8 + (g & 1) * 4) = pack4(p0, p1, p2, p3);
        const int sch1 = (2 + (g >> 1)) ^ (c & 7);
        f16x4 z = {};
        *(f16x4*)(prow + c * 64 + sch1 * 8 + (g & 1) * 4) = z;
      }

      __builtin_amdgcn_s_setprio(1);
      {
        const int sp = g ^ (c & 7);
        f16x8 pa = *(const f16x8*)(prow + c * 64 + sp * 8);
#pragma unroll
        for (int dt = 0; dt < 4; ++dt) {
          const int d = dt * 16 + c;
          f16x8 vb = *(const f16x8*)(vsb + d * 64 + sp * 8);
          o[dt] = __builtin_amdgcn_mfma_f32_16x16x32_f16(pa, vb, o[dt], 0, 0, 0);
        }
        osum = __builtin_amdgcn_mfma_f32_16x16x32_f16(pa, vones, osum, 0, 0, 0);
      }
      __builtin_amdgcn_s_setprio(0);
    }
    cur ^= 1;
  }

  // epilogue: osum already in q=g*4+r row layout -> no shuffles
  f16* obase = op + ((size_t)(b * NQ + qt * 64 + wave * 16)) * 384 + h * 64;
#pragma unroll
  for (int r = 0; r < 4; ++r) {
    const float iv = 1.0f / osum[r];
#pragma unroll
    for (int dt = 0; dt < 4; ++dt)
      obase[(size_t)(g * 4 + r) * 384 + dt * 16 + c] = (f16)(o[dt][r] * iv);
  }
}

extern "C" void kernel_launch(void* const* d_in, const int* in_sizes, int n_in,
                              void* d_out, int out_size, void* d_ws, size_t ws_size,
                              hipStream_t stream) {
  const float* inputs_q  = (const float*)d_in[0];
  const float* inputs_kv = (const float*)d_in[1];
  const float* out_kern  = (const float*)d_in[2];
  const float* q_dwk = (const float*)d_in[3];
  const float* q_bs  = (const float*)d_in[4];
  const float* q_bb  = (const float*)d_in[5];
  const float* q_bm  = (const float*)d_in[6];
  const float* q_bv  = (const float*)d_in[7];
  const float* q_pwk = (const float*)d_in[8];
  const float* k_dwk = (const float*)d_in[9];
  const float* k_bs  = (const float*)d_in[10];
  const float* k_bb  = (const float*)d_in[11];
  const float* k_bm  = (const float*)d_in[12];
  const float* k_bv  = (const float*)d_in[13];
  const float* k_pwk = (const float*)d_in[14];
  const float* v_dwk = (const float*)d_in[15];
  const float* v_bs  = (const float*)d_in[16];
  const float* v_bb  = (const float*)d_in[17];
  const float* v_bm  = (const float*)d_in[18];
  const float* v_bv  = (const float*)d_in[19];
  const float* v_pwk = (const float*)d_in[20];

  char* wsb = (char*)d_ws;
  f16* qdw = (f16*)(wsb + 0);             // 25088*384 f16
  f16* kdw = (f16*)(wsb + 19267584);      // 6272*384 f16
  f16* vdw = (f16*)(wsb + 24084480);      // 6272*384 f16
  f16* qf  = (f16*)(wsb + 28901376);      // 25088*384 f16
  f16* kf  = (f16*)(wsb + 48168960);      // 6272*384 f16
  f16* vtp = (f16*)(wsb + 57802752);      // 8*384*784 f16
  f16* of  = (f16*)(wsb + 62619648);      // 25088*384 f16
  f16* wqt = (f16*)(wsb + 81887232);      // 384*384 f16 x4
  f16* wkt = (f16*)(wsb + 82182144);
  f16* wvt = (f16*)(wsb + 82477056);
  f16* wot = (f16*)(wsb + 82771968);

  // 1. fused preprocess (XCD-chunked, high-ILP dw bodies)
  preprocess<<<4104, 256, 0, stream>>>(
      inputs_q, inputs_kv,
      q_dwk, q_bs, q_bb, q_bm, q_bv,
      k_dwk, k_bs, k_bb, k_bm, k_bv,
      v_dwk, v_bs, v_bb, v_bm, v_bv,
      q_pwk, k_pwk, v_pwk, out_kern, wqt, wkt, wvt, wot,
      qdw, kdw, vdw);
  // 2. fused q/k/v pointwise GEMMs (V written transposed; q folded with 1/8*log2e)
  gemm_qkv<<<882, 256, 0, stream>>>(qdw, wqt, qf, 0.125f * LOG2E,
                                    kdw, wkt, kf, vdw, wvt, vtp);
  // 3. MFMA attention (single-barrier dbuf, XCD-chunked, T14) -> f16 O
  attn_mfma<<<BB * NHD * 49, 256, 0, stream>>>(qf, kf, vtp, of);
  // 4. output projection (MFMA, fp32 out)
  gemm_mfma<0><<<dim3(196, 3), 256, 0, stream>>>(of, wot, (float*)d_out, nullptr, 1.0f);
}